// Round 1
// baseline (760.064 us; speedup 1.0000x reference)
//
#include <hip/hip_runtime.h>
#include <hip/hip_bf16.h>
#include <math.h>

// Problem dims (fixed)
#define BB 4
#define SS 1024
#define DD 512
#define HH 16
#define HD 32
#define NTOK (BB * SS)            // 4096
#define NELEM ((size_t)NTOK * DD) // 2M floats per [B,S,D] tensor
#define SCALE 0.17677669529663687f // 1/sqrt(32)

// ---------------------------------------------------------------------------
// Kernel 1: LayerNorm  x[4096,512] -> xn[4096,512]
// ---------------------------------------------------------------------------
__global__ __launch_bounds__(256) void ln_kernel(const float* __restrict__ x,
                                                 const float* __restrict__ g,
                                                 const float* __restrict__ bta,
                                                 float* __restrict__ xn) {
    int row = blockIdx.x;
    int tid = threadIdx.x;
    const float* xr = x + (size_t)row * DD;
    float2 v = *reinterpret_cast<const float2*>(&xr[tid * 2]);
    float s1 = v.x + v.y;
    float s2 = v.x * v.x + v.y * v.y;
    for (int off = 32; off > 0; off >>= 1) {
        s1 += __shfl_down(s1, off);
        s2 += __shfl_down(s2, off);
    }
    __shared__ float r1[4], r2[4];
    int w = tid >> 6;
    if ((tid & 63) == 0) { r1[w] = s1; r2[w] = s2; }
    __syncthreads();
    s1 = r1[0] + r1[1] + r1[2] + r1[3];
    s2 = r2[0] + r2[1] + r2[2] + r2[3];
    float mu = s1 * (1.0f / DD);
    float var = s2 * (1.0f / DD) - mu * mu;
    float rstd = rsqrtf(var + 1e-5f);
    float2 gg = *reinterpret_cast<const float2*>(&g[tid * 2]);
    float2 bb = *reinterpret_cast<const float2*>(&bta[tid * 2]);
    float2 o;
    o.x = (v.x - mu) * rstd * gg.x + bb.x;
    o.y = (v.y - mu) * rstd * gg.y + bb.y;
    *reinterpret_cast<float2*>(&xn[(size_t)row * DD + tid * 2]) = o;
}

// ---------------------------------------------------------------------------
// Kernel 2: GEMM  C[M,N] = A[M,K] @ W[K,N] + bias (+sigmoid) (+residual)
// BM=64 BN=64 BK=16, 256 threads, 4x4 per thread.
// ---------------------------------------------------------------------------
__global__ __launch_bounds__(256) void gemm_kernel(const float* __restrict__ A,
                                                   const float* __restrict__ W,
                                                   const float* __restrict__ bias,
                                                   const float* __restrict__ resid,
                                                   float* __restrict__ C,
                                                   int M, int N, int K, int act) {
    __shared__ __align__(16) float As[16][68]; // [k][m], stride 68 floats (272B = 17*16B)
    __shared__ __align__(16) float Bs[16][64]; // [k][n]
    int tid = threadIdx.x;
    int tx = tid & 15;  // n
    int ty = tid >> 4;  // m
    int bm = blockIdx.x * 64;
    int bn = blockIdx.y * 64;

    float acc[4][4] = {{0.f}};

    for (int k0 = 0; k0 < K; k0 += 16) {
        {   // A tile: 64 rows x 16 cols -> As[k][m] (transposed)
            int r = tid >> 2;
            int c4 = (tid & 3) * 4;
            float4 av = *reinterpret_cast<const float4*>(A + (size_t)(bm + r) * K + k0 + c4);
            As[c4 + 0][r] = av.x;
            As[c4 + 1][r] = av.y;
            As[c4 + 2][r] = av.z;
            As[c4 + 3][r] = av.w;
        }
        {   // B tile: 16 rows x 64 cols
            int r = tid >> 4;
            int c4 = (tid & 15) * 4;
            float4 wv = *reinterpret_cast<const float4*>(W + (size_t)(k0 + r) * N + bn + c4);
            *reinterpret_cast<float4*>(&Bs[r][c4]) = wv;
        }
        __syncthreads();
#pragma unroll
        for (int kk = 0; kk < 16; ++kk) {
            float4 a4 = *reinterpret_cast<const float4*>(&As[kk][ty * 4]);
            float4 b4 = *reinterpret_cast<const float4*>(&Bs[kk][tx * 4]);
            acc[0][0] += a4.x * b4.x; acc[0][1] += a4.x * b4.y; acc[0][2] += a4.x * b4.z; acc[0][3] += a4.x * b4.w;
            acc[1][0] += a4.y * b4.x; acc[1][1] += a4.y * b4.y; acc[1][2] += a4.y * b4.z; acc[1][3] += a4.y * b4.w;
            acc[2][0] += a4.z * b4.x; acc[2][1] += a4.z * b4.y; acc[2][2] += a4.z * b4.z; acc[2][3] += a4.z * b4.w;
            acc[3][0] += a4.w * b4.x; acc[3][1] += a4.w * b4.y; acc[3][2] += a4.w * b4.z; acc[3][3] += a4.w * b4.w;
        }
        __syncthreads();
    }

    float4 b4 = *reinterpret_cast<const float4*>(&bias[bn + tx * 4]);
#pragma unroll
    for (int i = 0; i < 4; ++i) {
        int row = bm + ty * 4 + i;
        int col = bn + tx * 4;
        float4 o;
        o.x = acc[i][0] + b4.x;
        o.y = acc[i][1] + b4.y;
        o.z = acc[i][2] + b4.z;
        o.w = acc[i][3] + b4.w;
        if (act == 1) {
            o.x = 1.0f / (1.0f + expf(-o.x));
            o.y = 1.0f / (1.0f + expf(-o.y));
            o.z = 1.0f / (1.0f + expf(-o.z));
            o.w = 1.0f / (1.0f + expf(-o.w));
        }
        if (resid) {
            float4 r4 = *reinterpret_cast<const float4*>(&resid[(size_t)row * N + col]);
            o.x += r4.x; o.y += r4.y; o.z += r4.z; o.w += r4.w;
        }
        *reinterpret_cast<float4*>(&C[(size_t)row * N + col]) = o;
    }
}

// ---------------------------------------------------------------------------
// Kernel 3a: anchor softmax partial stats over s-chunks of 256
// grid (D/64, B, S/256), block (64,4)
// ---------------------------------------------------------------------------
__global__ __launch_bounds__(256) void anchor_partial(const float* __restrict__ fa,
                                                      float* __restrict__ pmax,
                                                      float* __restrict__ psum) {
    int tx = threadIdx.x;      // 0..63 channel
    int ty = threadIdx.y;      // 0..3
    int c = blockIdx.x * 64 + tx;
    int b = blockIdx.y;
    int sc = blockIdx.z;
    const float* base = fa + ((size_t)(b * SS + sc * 256)) * DD + c;
    float m = -1e30f;
    for (int i = ty; i < 256; i += 4) m = fmaxf(m, base[(size_t)i * DD]);
    __shared__ float red[4][64];
    red[ty][tx] = m;
    __syncthreads();
    float cm = fmaxf(fmaxf(red[0][tx], red[1][tx]), fmaxf(red[2][tx], red[3][tx]));
    float s = 0.f;
    for (int i = ty; i < 256; i += 4) s += expf(base[(size_t)i * DD] - cm);
    __syncthreads();
    red[ty][tx] = s;
    __syncthreads();
    if (ty == 0) {
        float tot = red[0][tx] + red[1][tx] + red[2][tx] + red[3][tx];
        int o = (b * 4 + sc) * DD + c;
        pmax[o] = cm;
        psum[o] = tot;
    }
}

// Kernel 3b: merge 4 chunk stats per (b,c) -> (max, 1/Z)
__global__ __launch_bounds__(256) void anchor_merge(const float* __restrict__ pmax,
                                                    const float* __restrict__ psum,
                                                    float2* __restrict__ smscale) {
    int idx = blockIdx.x * 256 + threadIdx.x; // 0..2047
    int b = idx >> 9;
    int c = idx & 511;
    float M = -1e30f;
#pragma unroll
    for (int j = 0; j < 4; ++j) M = fmaxf(M, pmax[(b * 4 + j) * DD + c]);
    float Z = 0.f;
#pragma unroll
    for (int j = 0; j < 4; ++j) Z += psum[(b * 4 + j) * DD + c] * expf(pmax[(b * 4 + j) * DD + c] - M);
    smscale[idx] = make_float2(M, 1.0f / Z);
}

// Kernel 3c: kw = k * exp(fa - M) * invZ   (elementwise, float4)
__global__ __launch_bounds__(256) void kweight(const float* __restrict__ fa,
                                               const float* __restrict__ kin,
                                               const float2* __restrict__ smscale,
                                               float* __restrict__ kw) {
    size_t i4 = (size_t)blockIdx.x * 256 + threadIdx.x; // 0..524287
    size_t f = i4 * 4;
    int b = (int)(f >> 19);
    int c = (int)(f & 511);
    float4 fv = *reinterpret_cast<const float4*>(&fa[f]);
    float4 kv = *reinterpret_cast<const float4*>(&kin[f]);
    float2 s0 = smscale[b * DD + c + 0];
    float2 s1 = smscale[b * DD + c + 1];
    float2 s2 = smscale[b * DD + c + 2];
    float2 s3 = smscale[b * DD + c + 3];
    float4 o;
    o.x = kv.x * expf(fv.x - s0.x) * s0.y;
    o.y = kv.y * expf(fv.y - s1.x) * s1.y;
    o.z = kv.z * expf(fv.z - s2.x) * s2.y;
    o.w = kv.w * expf(fv.w - s3.x) * s3.y;
    *reinterpret_cast<float4*>(&kw[f]) = o;
}

// ---------------------------------------------------------------------------
// Kernel 4: fused attention. scores->softmax(h)->PV per t, no materialization.
// grid (S/32, B, 2 t-halves), block 256 (4 waves).
// Wave covers 8 s (2 per thread); thread owns head h = lane&15.
// ---------------------------------------------------------------------------
#define TT 8
__global__ __launch_bounds__(256) void attn_kernel(const float* __restrict__ q,
                                                   const float* __restrict__ kw,
                                                   const float* __restrict__ v,
                                                   float* __restrict__ part0,
                                                   float* __restrict__ part1) {
    int stile = blockIdx.x;
    int b = blockIdx.y;
    int half = blockIdx.z;
    int tid = threadIdx.x;
    int w = tid >> 6;
    int lane = tid & 63;
    int h = lane & 15;
    int sg = lane >> 4;           // 0..3
    int s0g = stile * 32 + w * 8 + sg * 2; // this thread's two s: s0g, s0g+1

    __shared__ __align__(16) float kw_lds[TT * 576];
    __shared__ __align__(16) float v_lds[TT * 576];

    float q0[32], q1[32], a0[32], a1[32];
    const float* qb = q + ((size_t)(b * SS + s0g)) * DD + h * HD;
#pragma unroll
    for (int d4 = 0; d4 < 8; ++d4) {
        float4 t0 = *reinterpret_cast<const float4*>(qb + d4 * 4);
        float4 t1 = *reinterpret_cast<const float4*>(qb + DD + d4 * 4);
        q0[d4 * 4 + 0] = t0.x; q0[d4 * 4 + 1] = t0.y; q0[d4 * 4 + 2] = t0.z; q0[d4 * 4 + 3] = t0.w;
        q1[d4 * 4 + 0] = t1.x; q1[d4 * 4 + 1] = t1.y; q1[d4 * 4 + 2] = t1.z; q1[d4 * 4 + 3] = t1.w;
        a0[d4 * 4 + 0] = 0.f; a0[d4 * 4 + 1] = 0.f; a0[d4 * 4 + 2] = 0.f; a0[d4 * 4 + 3] = 0.f;
        a1[d4 * 4 + 0] = 0.f; a1[d4 * 4 + 1] = 0.f; a1[d4 * 4 + 2] = 0.f; a1[d4 * 4 + 3] = 0.f;
    }

    int tstart = half * 512;
    for (int t0 = tstart; t0 < tstart + 512; t0 += TT) {
        // stage kw & v tiles: TT t-rows of 512 floats, padded layout [t][h*36+d]
#pragma unroll
        for (int j = 0; j < 4; ++j) {
            int gidx = j * 256 + tid;        // 0..1023
            int t = gidx >> 7;               // 0..7
            int c = (gidx & 127) * 4;        // 0..508
            int dst = t * 576 + (c >> 5) * 36 + (c & 31);
            size_t src = ((size_t)(b * SS + t0 + t)) * DD + c;
            *reinterpret_cast<float4*>(&kw_lds[dst]) = *reinterpret_cast<const float4*>(&kw[src]);
            *reinterpret_cast<float4*>(&v_lds[dst]) = *reinterpret_cast<const float4*>(&v[src]);
        }
        __syncthreads();
#pragma unroll
        for (int tt = 0; tt < TT; ++tt) {
            const float* kp = &kw_lds[tt * 576 + h * 36];
            float sc0 = 0.f, sc1 = 0.f;
#pragma unroll
            for (int d4 = 0; d4 < 8; ++d4) {
                float4 kv = *reinterpret_cast<const float4*>(kp + d4 * 4);
                sc0 += q0[d4 * 4 + 0] * kv.x + q0[d4 * 4 + 1] * kv.y + q0[d4 * 4 + 2] * kv.z + q0[d4 * 4 + 3] * kv.w;
                sc1 += q1[d4 * 4 + 0] * kv.x + q1[d4 * 4 + 1] * kv.y + q1[d4 * 4 + 2] * kv.z + q1[d4 * 4 + 3] * kv.w;
            }
            sc0 *= SCALE;
            sc1 *= SCALE;
            // softmax over the 16 heads (lanes sg*16 .. sg*16+15)
            float m0 = sc0, m1 = sc1;
#pragma unroll
            for (int off = 1; off < 16; off <<= 1) {
                m0 = fmaxf(m0, __shfl_xor(m0, off, 16));
                m1 = fmaxf(m1, __shfl_xor(m1, off, 16));
            }
            float e0 = expf(sc0 - m0), e1 = expf(sc1 - m1);
            float z0 = e0, z1 = e1;
#pragma unroll
            for (int off = 1; off < 16; off <<= 1) {
                z0 += __shfl_xor(z0, off, 16);
                z1 += __shfl_xor(z1, off, 16);
            }
            float p0 = e0 / z0, p1 = e1 / z1;
            const float* vp = &v_lds[tt * 576 + h * 36];
#pragma unroll
            for (int d4 = 0; d4 < 8; ++d4) {
                float4 vv = *reinterpret_cast<const float4*>(vp + d4 * 4);
                a0[d4 * 4 + 0] += p0 * vv.x; a0[d4 * 4 + 1] += p0 * vv.y;
                a0[d4 * 4 + 2] += p0 * vv.z; a0[d4 * 4 + 3] += p0 * vv.w;
                a1[d4 * 4 + 0] += p1 * vv.x; a1[d4 * 4 + 1] += p1 * vv.y;
                a1[d4 * 4 + 2] += p1 * vv.z; a1[d4 * 4 + 3] += p1 * vv.w;
            }
        }
        __syncthreads();
    }

    float* pout = (half == 0) ? part0 : part1;
    float* ob = pout + ((size_t)(b * SS + s0g)) * DD + h * HD;
#pragma unroll
    for (int d4 = 0; d4 < 8; ++d4) {
        *reinterpret_cast<float4*>(ob + d4 * 4) =
            make_float4(a0[d4 * 4], a0[d4 * 4 + 1], a0[d4 * 4 + 2], a0[d4 * 4 + 3]);
        *reinterpret_cast<float4*>(ob + DD + d4 * 4) =
            make_float4(a1[d4 * 4], a1[d4 * 4 + 1], a1[d4 * 4 + 2], a1[d4 * 4 + 3]);
    }
}

// Kernel 5: out_pre = (part0 + part1) * mg + hf
__global__ __launch_bounds__(256) void combine_kernel(const float* __restrict__ p0,
                                                      const float* __restrict__ p1,
                                                      const float* __restrict__ mg,
                                                      const float* __restrict__ hf,
                                                      float* __restrict__ outp) {
    size_t f = ((size_t)blockIdx.x * 256 + threadIdx.x) * 4;
    float4 a = *reinterpret_cast<const float4*>(&p0[f]);
    float4 bb = *reinterpret_cast<const float4*>(&p1[f]);
    float4 m = *reinterpret_cast<const float4*>(&mg[f]);
    float4 hh = *reinterpret_cast<const float4*>(&hf[f]);
    float4 o;
    o.x = (a.x + bb.x) * m.x + hh.x;
    o.y = (a.y + bb.y) * m.y + hh.y;
    o.z = (a.z + bb.z) * m.z + hh.z;
    o.w = (a.w + bb.w) * m.w + hh.w;
    *reinterpret_cast<float4*>(&outp[f]) = o;
}

// ---------------------------------------------------------------------------
extern "C" void kernel_launch(void* const* d_in, const int* in_sizes, int n_in,
                              void* d_out, int out_size, void* d_ws, size_t ws_size,
                              hipStream_t stream) {
    const float* x    = (const float*)d_in[0];
    const float* ln_g = (const float*)d_in[1];
    const float* ln_b = (const float*)d_in[2];
    const float* Wfa  = (const float*)d_in[3];  const float* bfa = (const float*)d_in[4];
    const float* Whp  = (const float*)d_in[5];  const float* bhp = (const float*)d_in[6];
    const float* Wmg  = (const float*)d_in[7];  const float* bmg = (const float*)d_in[8];
    const float* Wq   = (const float*)d_in[9];  const float* bq  = (const float*)d_in[10];
    const float* Wk   = (const float*)d_in[11]; const float* bk  = (const float*)d_in[12];
    const float* Wv   = (const float*)d_in[13]; const float* bv  = (const float*)d_in[14];
    const float* Wo   = (const float*)d_in[15]; const float* bo  = (const float*)d_in[16];
    float* out = (float*)d_out;
    float* ws = (float*)d_ws;

    float* xn = ws + 0 * NELEM;  // later reused as attention part0
    float* fa = ws + 1 * NELEM;  // later reused as out_pre
    float* hf = ws + 2 * NELEM;
    float* mg = ws + 3 * NELEM;
    float* q  = ws + 4 * NELEM;
    float* k  = ws + 5 * NELEM;  // later reused as attention part1
    float* v  = ws + 6 * NELEM;
    float* kw = ws + 7 * NELEM;
    float* pmax = ws + 8 * NELEM;            // 8192 floats
    float* psum = pmax + 8192;               // 8192 floats
    float2* smscale = (float2*)(psum + 8192); // 2048 float2

    // 1. LayerNorm
    ln_kernel<<<NTOK, 256, 0, stream>>>(x, ln_g, ln_b, xn);

    // 2. Six projections
    dim3 gg(NTOK / 64, DD / 64); // (64, 8)
    gemm_kernel<<<gg, 256, 0, stream>>>(xn, Wfa, bfa, nullptr, fa, NTOK, DD, DD, 0);
    gemm_kernel<<<gg, 256, 0, stream>>>(xn, Whp, bhp, nullptr, hf, NTOK, DD, DD, 0);
    gemm_kernel<<<gg, 256, 0, stream>>>(xn, Wmg, bmg, nullptr, mg, NTOK, DD, DD, 1);
    gemm_kernel<<<gg, 256, 0, stream>>>(xn, Wq,  bq,  nullptr, q,  NTOK, DD, DD, 0);
    gemm_kernel<<<gg, 256, 0, stream>>>(xn, Wk,  bk,  nullptr, k,  NTOK, DD, DD, 0);
    gemm_kernel<<<gg, 256, 0, stream>>>(xn, Wv,  bv,  nullptr, v,  NTOK, DD, DD, 0);

    // 3. anchor softmax over sequence axis -> kw = k * softmax(fa, axis=s)
    anchor_partial<<<dim3(DD / 64, BB, 4), dim3(64, 4), 0, stream>>>(fa, pmax, psum);
    anchor_merge<<<8, 256, 0, stream>>>(pmax, psum, smscale);
    kweight<<<(int)(NELEM / 4 / 256), 256, 0, stream>>>(fa, k, smscale, kw);

    // 4. fused attention: q,kw,v -> partial sums (t split in halves)
    attn_kernel<<<dim3(SS / 32, BB, 2), 256, 0, stream>>>(q, kw, v, xn /*part0*/, k /*part1*/);

    // 5. combine: out_pre = (p0+p1)*mg + hf   (into fa buffer)
    combine_kernel<<<(int)(NELEM / 4 / 256), 256, 0, stream>>>(xn, k, mg, hf, fa);

    // 6. output projection + residual
    gemm_kernel<<<gg, 256, 0, stream>>>(fa, Wo, bo, x, out, NTOK, DD, DD, 0);
}

// Round 2
// 290.759 us; speedup vs baseline: 2.6141x; 2.6141x over previous
//
#include <hip/hip_runtime.h>
#include <hip/hip_bf16.h>
#include <math.h>

#define BB 4
#define SS 1024
#define DD 512
#define HH 16
#define HD 32
#define NTOK (BB * SS)             // 4096
#define NELEM ((size_t)NTOK * DD)  // 2M elements per [B,S,D]
#define SCALE 0.17677669529663687f // 1/sqrt(32)
#define SCLOG2E 0.25505526082484745f // SCALE * log2(e)

typedef __attribute__((ext_vector_type(8))) __bf16 bf16x8;
typedef __attribute__((ext_vector_type(4))) __bf16 bf16x4;
typedef __attribute__((ext_vector_type(4))) float f32x4;
typedef __attribute__((ext_vector_type(4))) unsigned short us4;

// ---------------------------------------------------------------------------
// Kernel 1: LayerNorm  x[4096,512] f32 -> xn bf16
// ---------------------------------------------------------------------------
__global__ __launch_bounds__(256) void ln_kernel(const float* __restrict__ x,
                                                 const float* __restrict__ g,
                                                 const float* __restrict__ bta,
                                                 __bf16* __restrict__ xn) {
    int row = blockIdx.x;
    int tid = threadIdx.x;
    const float* xr = x + (size_t)row * DD;
    float2 v = *reinterpret_cast<const float2*>(&xr[tid * 2]);
    float s1 = v.x + v.y;
    float s2 = v.x * v.x + v.y * v.y;
    for (int off = 32; off > 0; off >>= 1) {
        s1 += __shfl_down(s1, off);
        s2 += __shfl_down(s2, off);
    }
    __shared__ float r1[4], r2[4];
    int w = tid >> 6;
    if ((tid & 63) == 0) { r1[w] = s1; r2[w] = s2; }
    __syncthreads();
    s1 = r1[0] + r1[1] + r1[2] + r1[3];
    s2 = r2[0] + r2[1] + r2[2] + r2[3];
    float mu = s1 * (1.0f / DD);
    float var = s2 * (1.0f / DD) - mu * mu;
    float rstd = rsqrtf(var + 1e-5f);
    float2 gg = *reinterpret_cast<const float2*>(&g[tid * 2]);
    float2 bb = *reinterpret_cast<const float2*>(&bta[tid * 2]);
    __bf16* xp = xn + (size_t)row * DD + tid * 2;
    xp[0] = (__bf16)((v.x - mu) * rstd * gg.x + bb.x);
    xp[1] = (__bf16)((v.y - mu) * rstd * gg.y + bb.y);
}

// ---------------------------------------------------------------------------
// Kernel 2: weight prep — Wt[z][n][k] = bf16(W_z[k][n]), z = 0..6
// grid (16,16,7), block 256, 32x32 tiles
// ---------------------------------------------------------------------------
struct W7 { const float* p[7]; };

__global__ __launch_bounds__(256) void wprep(W7 wp, __bf16* __restrict__ Wt) {
    int z = blockIdx.z;
    int kt = blockIdx.x, nt = blockIdx.y;
    const float* W = wp.p[z];
    __shared__ float lds[32][33];
    int tid = threadIdx.x;
    int r = tid >> 3, c4 = (tid & 7) * 4;
    float4 vv = *reinterpret_cast<const float4*>(W + (size_t)(kt * 32 + r) * DD + nt * 32 + c4);
    lds[r][c4 + 0] = vv.x; lds[r][c4 + 1] = vv.y;
    lds[r][c4 + 2] = vv.z; lds[r][c4 + 3] = vv.w;
    __syncthreads();
    __bf16* o = Wt + (size_t)z * DD * DD + (size_t)(nt * 32 + r) * DD + kt * 32 + c4;
    o[0] = (__bf16)lds[c4 + 0][r];
    o[1] = (__bf16)lds[c4 + 1][r];
    o[2] = (__bf16)lds[c4 + 2][r];
    o[3] = (__bf16)lds[c4 + 3][r];
}

// ---------------------------------------------------------------------------
// Kernel 3: bf16 MFMA GEMM, no-LDS (A and Wt are L2-resident).
// C[M,N] = A[M,K=512] @ W_z[K,N=512], W stored transposed [n][k] bf16.
// Block: 4 waves, wave tile 64m x 32n (4x2 frags). Block tile 128x64.
// mode: 0 = f32, 1 = f32+sigmoid, 2 = bf16. resid: optional f32 add.
// ---------------------------------------------------------------------------
struct GemmCfg { const float* bias[6]; void* out[6]; int mode[6]; };

__global__ __launch_bounds__(256) void mfma_gemm(const __bf16* __restrict__ A,
                                                 const __bf16* __restrict__ Wt0,
                                                 GemmCfg cfg,
                                                 const float* __restrict__ resid) {
    int z = blockIdx.z;
    const __bf16* W = Wt0 + (size_t)z * DD * DD;
    int tid = threadIdx.x;
    int l = tid & 63, wid = tid >> 6;
    int lr = l & 15, lg = l >> 4;
    int wm = wid >> 1, wn = wid & 1;
    int bm = blockIdx.x * 128 + wm * 64;
    int bn = blockIdx.y * 64 + wn * 32;

    f32x4 acc[4][2];
#pragma unroll
    for (int i = 0; i < 4; ++i)
#pragma unroll
        for (int j = 0; j < 2; ++j) acc[i][j] = (f32x4){0.f, 0.f, 0.f, 0.f};

    const __bf16* Ab = A + (size_t)(bm + lr) * DD + lg * 8;
    const __bf16* Bb = W + (size_t)(bn + lr) * DD + lg * 8;

#pragma unroll 4
    for (int k0 = 0; k0 < DD; k0 += 32) {
        bf16x8 af[4], wf[2];
#pragma unroll
        for (int mi = 0; mi < 4; ++mi)
            af[mi] = *reinterpret_cast<const bf16x8*>(Ab + (size_t)mi * 16 * DD + k0);
#pragma unroll
        for (int ni = 0; ni < 2; ++ni)
            wf[ni] = *reinterpret_cast<const bf16x8*>(Bb + (size_t)ni * 16 * DD + k0);
#pragma unroll
        for (int mi = 0; mi < 4; ++mi)
#pragma unroll
            for (int ni = 0; ni < 2; ++ni)
                acc[mi][ni] = __builtin_amdgcn_mfma_f32_16x16x32_bf16(af[mi], wf[ni], acc[mi][ni], 0, 0, 0);
    }

    int mode = cfg.mode[z];
    const float* bias = cfg.bias[z];
    float bv[2] = {bias[bn + lr], bias[bn + 16 + lr]};
#pragma unroll
    for (int mi = 0; mi < 4; ++mi) {
#pragma unroll
        for (int ni = 0; ni < 2; ++ni) {
#pragma unroll
            for (int r = 0; r < 4; ++r) {
                int row = bm + mi * 16 + lg * 4 + r;
                int col = bn + ni * 16 + lr;
                float val = acc[mi][ni][r] + bv[ni];
                if (mode == 1) val = 1.0f / (1.0f + expf(-val));
                if (resid) val += resid[(size_t)row * DD + col];
                if (mode == 2) ((__bf16*)cfg.out[z])[(size_t)row * DD + col] = (__bf16)val;
                else           ((float*)cfg.out[z])[(size_t)row * DD + col] = val;
            }
        }
    }
}

// ---------------------------------------------------------------------------
// Kernel 4a/4b: anchor softmax over sequence axis (per b, channel)
// ---------------------------------------------------------------------------
__global__ __launch_bounds__(256) void anchor_partial(const __bf16* __restrict__ fa,
                                                      float* __restrict__ pmax,
                                                      float* __restrict__ psum) {
    int tx = threadIdx.x;  // 0..63 channel
    int ty = threadIdx.y;  // 0..3
    int c = blockIdx.x * 64 + tx;
    int b = blockIdx.y;
    int sc = blockIdx.z;
    const __bf16* base = fa + ((size_t)(b * SS + sc * 256)) * DD + c;
    float m = -1e30f;
    for (int i = ty; i < 256; i += 4) m = fmaxf(m, (float)base[(size_t)i * DD]);
    __shared__ float red[4][64];
    red[ty][tx] = m;
    __syncthreads();
    float cm = fmaxf(fmaxf(red[0][tx], red[1][tx]), fmaxf(red[2][tx], red[3][tx]));
    float s = 0.f;
    for (int i = ty; i < 256; i += 4) s += expf((float)base[(size_t)i * DD] - cm);
    __syncthreads();
    red[ty][tx] = s;
    __syncthreads();
    if (ty == 0) {
        float tot = red[0][tx] + red[1][tx] + red[2][tx] + red[3][tx];
        int o = (b * 4 + sc) * DD + c;
        pmax[o] = cm;
        psum[o] = tot;
    }
}

__global__ __launch_bounds__(256) void anchor_merge(const float* __restrict__ pmax,
                                                    const float* __restrict__ psum,
                                                    float2* __restrict__ smscale) {
    int idx = blockIdx.x * 256 + threadIdx.x; // 0..2047
    int b = idx >> 9;
    int c = idx & 511;
    float M = -1e30f;
#pragma unroll
    for (int j = 0; j < 4; ++j) M = fmaxf(M, pmax[(b * 4 + j) * DD + c]);
    float Z = 0.f;
#pragma unroll
    for (int j = 0; j < 4; ++j) Z += psum[(b * 4 + j) * DD + c] * expf(pmax[(b * 4 + j) * DD + c] - M);
    smscale[idx] = make_float2(M, 1.0f / Z);
}

// Kernel 4c: kw = k * exp(fa - M) * invZ  (bf16 out)
__global__ __launch_bounds__(256) void kweight(const __bf16* __restrict__ fa,
                                               const __bf16* __restrict__ kin,
                                               const float2* __restrict__ sm,
                                               __bf16* __restrict__ kw) {
    size_t f = ((size_t)blockIdx.x * 256 + threadIdx.x) * 8;
    int b = (int)(f >> 19);
    int c = (int)(f & 511);
    const float2* smb = sm + b * DD + c;
#pragma unroll
    for (int j = 0; j < 8; ++j) {
        float2 s = smb[j];
        float val = (float)kin[f + j] * expf((float)fa[f + j] - s.x) * s.y;
        kw[f + j] = (__bf16)val;
    }
}

// ---------------------------------------------------------------------------
// Kernel 5: V transpose  v[b][t][h*32+d] bf16 -> vt[((b*16+h)*32+d)][t] bf16
// grid (S/32, H, B), block 256, 32x32 tiles
// ---------------------------------------------------------------------------
__global__ __launch_bounds__(256) void vtrans(const __bf16* __restrict__ v,
                                              __bf16* __restrict__ vt) {
    int t0 = blockIdx.x * 32;
    int h = blockIdx.y;
    int b = blockIdx.z;
    __shared__ unsigned short lds[32][33];
    int tid = threadIdx.x;
    int r = tid >> 3, c4 = (tid & 7) * 4;
    const unsigned short* vp = (const unsigned short*)v + ((size_t)(b * SS + t0 + r)) * DD + h * 32 + c4;
    us4 val = *reinterpret_cast<const us4*>(vp);
    lds[r][c4 + 0] = val[0]; lds[r][c4 + 1] = val[1];
    lds[r][c4 + 2] = val[2]; lds[r][c4 + 3] = val[3];
    __syncthreads();
    // write: d = r, t4 = c4
    us4 o;
    o[0] = lds[c4 + 0][r]; o[1] = lds[c4 + 1][r];
    o[2] = lds[c4 + 2][r]; o[3] = lds[c4 + 3][r];
    unsigned short* op = (unsigned short*)vt + ((size_t)((b * 16 + h) * 32 + r)) * SS + t0 + c4;
    *reinterpret_cast<us4*>(op) = o;
}

// ---------------------------------------------------------------------------
// Kernel 6: MFMA attention. Swapped QK^T (mfma(K,Q)) makes head-softmax
// lane-local AND P lands directly in the PV A-fragment layout.
// grid 1024 = (64 s-tiles) x (4 b) x (4 t-splits), block 64 (1 wave).
// ---------------------------------------------------------------------------
#define TSPLIT 4
__global__ __launch_bounds__(64, 1) void attn_mfma(const __bf16* __restrict__ q,
                                                   const __bf16* __restrict__ kw,
                                                   const __bf16* __restrict__ vt,
                                                   float* __restrict__ p0,
                                                   float* __restrict__ p1,
                                                   float* __restrict__ p2,
                                                   float* __restrict__ p3) {
    int blk = blockIdx.x;
    int st = blk & 63;
    int b = (blk >> 6) & 3;
    int tp = blk >> 8;
    int l = threadIdx.x;
    int lg = l >> 4;   // lane group 0..3
    int lr = l & 15;

    int s0 = st * 16;
    // Preload Q fragments (B-operand of swapped QK): lane holds s-col = s0+lr
    bf16x8 qf[16];
    const __bf16* qbase = q + ((size_t)(b * SS + s0 + lr)) * DD + lg * 8;
#pragma unroll
    for (int h = 0; h < 16; ++h) qf[h] = *reinterpret_cast<const bf16x8*>(qbase + h * 32);

    f32x4 acc[16][2];
#pragma unroll
    for (int h = 0; h < 16; ++h) {
        acc[h][0] = (f32x4){0.f, 0.f, 0.f, 0.f};
        acc[h][1] = (f32x4){0.f, 0.f, 0.f, 0.f};
    }

    const __bf16* kwb = kw + (size_t)(b * SS) * DD;
    const __bf16* vtb = vt + (size_t)(b * 16) * 32 * SS;
    // permuted K-row indices so P lands in PV A-layout: t = 8*(m>>2)+(m&3)
    int trowA = 8 * (lr >> 2) + (lr & 3);
    int trowB = trowA + 4;

    int tbase0 = tp * (SS / TSPLIT);
    for (int tc = 0; tc < SS / TSPLIT; tc += 32) {
        int tbase = tbase0 + tc;
        // ---- sub-chunk A: t = tbase + 8*lg + r (per lane, reg r)
        f32x4 sc[16];
#pragma unroll
        for (int h = 0; h < 16; ++h) {
            bf16x8 ka = *reinterpret_cast<const bf16x8*>(kwb + (size_t)(tbase + trowA) * DD + h * 32 + lg * 8);
            f32x4 z = (f32x4){0.f, 0.f, 0.f, 0.f};
            sc[h] = __builtin_amdgcn_mfma_f32_16x16x32_bf16(ka, qf[h], z, 0, 0, 0);
        }
        bf16x4 pA[16];
#pragma unroll
        for (int r = 0; r < 4; ++r) {
            float m = sc[0][r];
#pragma unroll
            for (int h = 1; h < 16; ++h) m = fmaxf(m, sc[h][r]);
            float e[16]; float zs = 0.f;
#pragma unroll
            for (int h = 0; h < 16; ++h) { e[h] = exp2f((sc[h][r] - m) * SCLOG2E); zs += e[h]; }
            float inv = 1.0f / zs;
#pragma unroll
            for (int h = 0; h < 16; ++h) pA[h][r] = (__bf16)(e[h] * inv);
        }
        // ---- sub-chunk B: t = tbase + 8*lg + 4 + r
#pragma unroll
        for (int h = 0; h < 16; ++h) {
            bf16x8 ka = *reinterpret_cast<const bf16x8*>(kwb + (size_t)(tbase + trowB) * DD + h * 32 + lg * 8);
            f32x4 z = (f32x4){0.f, 0.f, 0.f, 0.f};
            sc[h] = __builtin_amdgcn_mfma_f32_16x16x32_bf16(ka, qf[h], z, 0, 0, 0);
        }
        bf16x4 pB[16];
#pragma unroll
        for (int r = 0; r < 4; ++r) {
            float m = sc[0][r];
#pragma unroll
            for (int h = 1; h < 16; ++h) m = fmaxf(m, sc[h][r]);
            float e[16]; float zs = 0.f;
#pragma unroll
            for (int h = 0; h < 16; ++h) { e[h] = exp2f((sc[h][r] - m) * SCLOG2E); zs += e[h]; }
            float inv = 1.0f / zs;
#pragma unroll
            for (int h = 0; h < 16; ++h) pB[h][r] = (__bf16)(e[h] * inv);
        }
        // ---- PV: A = P (k-slots = t = tbase + 8*lg + j), B = V^T rows
#pragma unroll
        for (int h = 0; h < 16; ++h) {
            bf16x8 p = __builtin_shufflevector(pA[h], pB[h], 0, 1, 2, 3, 4, 5, 6, 7);
#pragma unroll
            for (int dh = 0; dh < 2; ++dh) {
                bf16x8 vf = *reinterpret_cast<const bf16x8*>(
                    vtb + (size_t)(h * 32 + dh * 16 + lr) * SS + tbase + lg * 8);
                acc[h][dh] = __builtin_amdgcn_mfma_f32_16x16x32_bf16(p, vf, acc[h][dh], 0, 0, 0);
            }
        }
    }

    float* pp = (tp == 0) ? p0 : ((tp == 1) ? p1 : ((tp == 2) ? p2 : p3));
    float* pb = pp + ((size_t)(b * SS + s0)) * DD;
#pragma unroll
    for (int h = 0; h < 16; ++h)
#pragma unroll
        for (int dh = 0; dh < 2; ++dh)
#pragma unroll
            for (int r = 0; r < 4; ++r)
                pb[(size_t)(lg * 4 + r) * DD + h * 32 + dh * 16 + lr] = acc[h][dh][r];
}

// ---------------------------------------------------------------------------
// Kernel 7: combine  comb = (p0+p1+p2+p3)*mg + hf  -> bf16
// ---------------------------------------------------------------------------
__global__ __launch_bounds__(256) void combine_kernel(const float* __restrict__ p0,
                                                      const float* __restrict__ p1,
                                                      const float* __restrict__ p2,
                                                      const float* __restrict__ p3,
                                                      const float* __restrict__ mg,
                                                      const float* __restrict__ hf,
                                                      __bf16* __restrict__ comb) {
    size_t f = ((size_t)blockIdx.x * 256 + threadIdx.x) * 8;
#pragma unroll
    for (int j = 0; j < 8; j += 4) {
        float4 a = *reinterpret_cast<const float4*>(p0 + f + j);
        float4 b1 = *reinterpret_cast<const float4*>(p1 + f + j);
        float4 c = *reinterpret_cast<const float4*>(p2 + f + j);
        float4 d = *reinterpret_cast<const float4*>(p3 + f + j);
        float4 m = *reinterpret_cast<const float4*>(mg + f + j);
        float4 hh = *reinterpret_cast<const float4*>(hf + f + j);
        comb[f + j + 0] = (__bf16)((a.x + b1.x + c.x + d.x) * m.x + hh.x);
        comb[f + j + 1] = (__bf16)((a.y + b1.y + c.y + d.y) * m.y + hh.y);
        comb[f + j + 2] = (__bf16)((a.z + b1.z + c.z + d.z) * m.z + hh.z);
        comb[f + j + 3] = (__bf16)((a.w + b1.w + c.w + d.w) * m.w + hh.w);
    }
}

// ---------------------------------------------------------------------------
extern "C" void kernel_launch(void* const* d_in, const int* in_sizes, int n_in,
                              void* d_out, int out_size, void* d_ws, size_t ws_size,
                              hipStream_t stream) {
    const float* x    = (const float*)d_in[0];
    const float* ln_g = (const float*)d_in[1];
    const float* ln_b = (const float*)d_in[2];
    const float* Wfa  = (const float*)d_in[3];  const float* bfa = (const float*)d_in[4];
    const float* Whp  = (const float*)d_in[5];  const float* bhp = (const float*)d_in[6];
    const float* Wmg  = (const float*)d_in[7];  const float* bmg = (const float*)d_in[8];
    const float* Wq   = (const float*)d_in[9];  const float* bq  = (const float*)d_in[10];
    const float* Wk   = (const float*)d_in[11]; const float* bk  = (const float*)d_in[12];
    const float* Wv   = (const float*)d_in[13]; const float* bv  = (const float*)d_in[14];
    const float* Wo   = (const float*)d_in[15]; const float* bo  = (const float*)d_in[16];
    float* out = (float*)d_out;

    char* w8 = (char*)d_ws;
    // Memory map (total 64 MB, proven ws >= 64.08 MB last round):
    __bf16* Wt   = (__bf16*)(w8 + ((size_t) 0 << 20));  // 3.67 MB
    __bf16* xn   = (__bf16*)(w8 + ((size_t) 4 << 20));  // 4 MB
    __bf16* fa   = (__bf16*)(w8 + ((size_t) 8 << 20));  // 4 MB
    float*  hf   = (float*) (w8 + ((size_t)12 << 20));  // 8 MB
    float*  mg   = (float*) (w8 + ((size_t)20 << 20));  // 8 MB
    __bf16* q    = (__bf16*)(w8 + ((size_t)28 << 20));  // 4 MB
    __bf16* k    = (__bf16*)(w8 + ((size_t)32 << 20));  // 4 MB
    __bf16* v    = (__bf16*)(w8 + ((size_t)36 << 20));  // 4 MB
    __bf16* kw   = (__bf16*)(w8 + ((size_t)40 << 20));  // 4 MB
    __bf16* vt   = (__bf16*)(w8 + ((size_t)44 << 20));  // 4 MB
    float* part0 = (float*) (w8 + ((size_t)48 << 20));  // 8 MB
    float* part1 = (float*) (w8 + ((size_t)56 << 20));  // 8 MB (ends 64 MB)
    float* part2 = (float*) (w8 + ((size_t) 4 << 20));  // reuse xn+fa (dead by attn)
    float* part3 = (float*) (w8 + ((size_t)32 << 20));  // reuse k+v (dead by attn)
    // anchor stats live only [anchor_partial .. kweight], placed in part0 region
    float* pmax  = (float*) (w8 + ((size_t)48 << 20));
    float* psum  = pmax + 16 * DD;
    float2* smsc = (float2*)(psum + 16 * DD);
    __bf16* comb = (__bf16*)(w8 + ((size_t)40 << 20));  // reuse kw (dead after attn)

    // 1. LayerNorm -> xn bf16
    ln_kernel<<<NTOK, 256, 0, stream>>>(x, ln_g, ln_b, xn);

    // 2. Weight transpose+cast (7 matrices)
    W7 wp; wp.p[0]=Wfa; wp.p[1]=Whp; wp.p[2]=Wmg; wp.p[3]=Wq; wp.p[4]=Wk; wp.p[5]=Wv; wp.p[6]=Wo;
    wprep<<<dim3(16, 16, 7), 256, 0, stream>>>(wp, Wt);

    // 3. Fused 6-projection MFMA GEMM
    GemmCfg cfg;
    cfg.bias[0]=bfa; cfg.out[0]=fa; cfg.mode[0]=2;   // fa bf16
    cfg.bias[1]=bhp; cfg.out[1]=hf; cfg.mode[1]=0;   // hf f32
    cfg.bias[2]=bmg; cfg.out[2]=mg; cfg.mode[2]=1;   // mg f32 sigmoid
    cfg.bias[3]=bq;  cfg.out[3]=q;  cfg.mode[3]=2;   // q bf16
    cfg.bias[4]=bk;  cfg.out[4]=k;  cfg.mode[4]=2;   // k bf16
    cfg.bias[5]=bv;  cfg.out[5]=v;  cfg.mode[5]=2;   // v bf16
    mfma_gemm<<<dim3(32, 8, 6), 256, 0, stream>>>(xn, Wt, cfg, nullptr);

    // 4. anchor softmax over sequence axis
    anchor_partial<<<dim3(8, 4, 4), dim3(64, 4), 0, stream>>>(fa, pmax, psum);
    anchor_merge<<<8, 256, 0, stream>>>(pmax, psum, smsc);
    kweight<<<1024, 256, 0, stream>>>(fa, k, smsc, kw);

    // 5. V transpose for PV fragments
    vtrans<<<dim3(32, 16, 4), 256, 0, stream>>>(v, vt);

    // 6. MFMA attention -> 4 partials
    attn_mfma<<<1024, 64, 0, stream>>>(q, kw, vt, part0, part1, part2, part3);

    // 7. combine -> comb bf16
    combine_kernel<<<1024, 256, 0, stream>>>(part0, part1, part2, part3, mg, hf, comb);

    // 8. output projection + residual (Wt slot 6)
    GemmCfg cfg2;
    for (int i = 0; i < 6; ++i) { cfg2.bias[i]=bo; cfg2.out[i]=out; cfg2.mode[i]=0; }
    mfma_gemm<<<dim3(32, 8, 1), 256, 0, stream>>>(comb, Wt + (size_t)6 * DD * DD, cfg2, x);
}

// Round 4
// 274.367 us; speedup vs baseline: 2.7702x; 1.0597x over previous
//
#include <hip/hip_runtime.h>
#include <hip/hip_bf16.h>
#include <math.h>

#define BB 4
#define SS 1024
#define DD 512
#define HH 16
#define HD 32
#define NTOK (BB * SS)             // 4096
#define NELEM ((size_t)NTOK * DD)  // 2M elements per [B,S,D]
#define SCALE 0.17677669529663687f // 1/sqrt(32)
#define SCLOG2E 0.25505526082484745f // SCALE * log2(e)

typedef __attribute__((ext_vector_type(8))) __bf16 bf16x8;
typedef __attribute__((ext_vector_type(4))) __bf16 bf16x4;
typedef __attribute__((ext_vector_type(4))) float f32x4;
typedef __attribute__((ext_vector_type(4))) unsigned short us4;

// ---------------------------------------------------------------------------
// Kernel 1: LayerNorm  x[4096,512] f32 -> xn bf16
// ---------------------------------------------------------------------------
__global__ __launch_bounds__(256) void ln_kernel(const float* __restrict__ x,
                                                 const float* __restrict__ g,
                                                 const float* __restrict__ bta,
                                                 __bf16* __restrict__ xn) {
    int row = blockIdx.x;
    int tid = threadIdx.x;
    const float* xr = x + (size_t)row * DD;
    float2 v = *reinterpret_cast<const float2*>(&xr[tid * 2]);
    float s1 = v.x + v.y;
    float s2 = v.x * v.x + v.y * v.y;
    for (int off = 32; off > 0; off >>= 1) {
        s1 += __shfl_down(s1, off);
        s2 += __shfl_down(s2, off);
    }
    __shared__ float r1[4], r2[4];
    int w = tid >> 6;
    if ((tid & 63) == 0) { r1[w] = s1; r2[w] = s2; }
    __syncthreads();
    s1 = r1[0] + r1[1] + r1[2] + r1[3];
    s2 = r2[0] + r2[1] + r2[2] + r2[3];
    float mu = s1 * (1.0f / DD);
    float var = s2 * (1.0f / DD) - mu * mu;
    float rstd = rsqrtf(var + 1e-5f);
    float2 gg = *reinterpret_cast<const float2*>(&g[tid * 2]);
    float2 bb = *reinterpret_cast<const float2*>(&bta[tid * 2]);
    __bf16* xp = xn + (size_t)row * DD + tid * 2;
    xp[0] = (__bf16)((v.x - mu) * rstd * gg.x + bb.x);
    xp[1] = (__bf16)((v.y - mu) * rstd * gg.y + bb.y);
}

// ---------------------------------------------------------------------------
// Kernel 2: weight prep — Wt[z][n][k] = bf16(W_z[k][n]), z = 0..6
// ---------------------------------------------------------------------------
struct W7 { const float* p[7]; };

__global__ __launch_bounds__(256) void wprep(W7 wp, __bf16* __restrict__ Wt) {
    int z = blockIdx.z;
    int kt = blockIdx.x, nt = blockIdx.y;
    const float* W = wp.p[z];
    __shared__ float lds[32][33];
    int tid = threadIdx.x;
    int r = tid >> 3, c4 = (tid & 7) * 4;
    float4 vv = *reinterpret_cast<const float4*>(W + (size_t)(kt * 32 + r) * DD + nt * 32 + c4);
    lds[r][c4 + 0] = vv.x; lds[r][c4 + 1] = vv.y;
    lds[r][c4 + 2] = vv.z; lds[r][c4 + 3] = vv.w;
    __syncthreads();
    __bf16* o = Wt + (size_t)z * DD * DD + (size_t)(nt * 32 + r) * DD + kt * 32 + c4;
    o[0] = (__bf16)lds[c4 + 0][r];
    o[1] = (__bf16)lds[c4 + 1][r];
    o[2] = (__bf16)lds[c4 + 2][r];
    o[3] = (__bf16)lds[c4 + 3][r];
}

// ---------------------------------------------------------------------------
// Kernel 3: bf16 MFMA GEMM, no-LDS (A and Wt are L2-resident).
// mode: 0 = f32 (+resid), 1 = sigmoid->bf16, 2 = bf16
// ---------------------------------------------------------------------------
struct GemmCfg { const float* bias[6]; void* out[6]; int mode[6]; };

__global__ __launch_bounds__(256) void mfma_gemm(const __bf16* __restrict__ A,
                                                 const __bf16* __restrict__ Wt0,
                                                 GemmCfg cfg,
                                                 const float* __restrict__ resid) {
    int z = blockIdx.z;
    const __bf16* W = Wt0 + (size_t)z * DD * DD;
    int tid = threadIdx.x;
    int l = tid & 63, wid = tid >> 6;
    int lr = l & 15, lg = l >> 4;
    int wm = wid >> 1, wn = wid & 1;
    int bm = blockIdx.x * 128 + wm * 64;
    int bn = blockIdx.y * 64 + wn * 32;

    f32x4 acc[4][2];
#pragma unroll
    for (int i = 0; i < 4; ++i)
#pragma unroll
        for (int j = 0; j < 2; ++j) acc[i][j] = (f32x4){0.f, 0.f, 0.f, 0.f};

    const __bf16* Ab = A + (size_t)(bm + lr) * DD + lg * 8;
    const __bf16* Bb = W + (size_t)(bn + lr) * DD + lg * 8;

#pragma unroll 4
    for (int k0 = 0; k0 < DD; k0 += 32) {
        bf16x8 af[4], wf[2];
#pragma unroll
        for (int mi = 0; mi < 4; ++mi)
            af[mi] = *reinterpret_cast<const bf16x8*>(Ab + (size_t)mi * 16 * DD + k0);
#pragma unroll
        for (int ni = 0; ni < 2; ++ni)
            wf[ni] = *reinterpret_cast<const bf16x8*>(Bb + (size_t)ni * 16 * DD + k0);
#pragma unroll
        for (int mi = 0; mi < 4; ++mi)
#pragma unroll
            for (int ni = 0; ni < 2; ++ni)
                acc[mi][ni] = __builtin_amdgcn_mfma_f32_16x16x32_bf16(af[mi], wf[ni], acc[mi][ni], 0, 0, 0);
    }

    int mode = cfg.mode[z];
    const float* bias = cfg.bias[z];
    float bv[2] = {bias[bn + lr], bias[bn + 16 + lr]};
#pragma unroll
    for (int mi = 0; mi < 4; ++mi) {
#pragma unroll
        for (int ni = 0; ni < 2; ++ni) {
#pragma unroll
            for (int r = 0; r < 4; ++r) {
                int row = bm + mi * 16 + lg * 4 + r;
                int col = bn + ni * 16 + lr;
                float val = acc[mi][ni][r] + bv[ni];
                if (mode == 0) {
                    if (resid) val += resid[(size_t)row * DD + col];
                    ((float*)cfg.out[z])[(size_t)row * DD + col] = val;
                } else if (mode == 1) {
                    val = 1.0f / (1.0f + expf(-val));
                    ((__bf16*)cfg.out[z])[(size_t)row * DD + col] = (__bf16)val;
                } else {
                    ((__bf16*)cfg.out[z])[(size_t)row * DD + col] = (__bf16)val;
                }
            }
        }
    }
}

// ---------------------------------------------------------------------------
// Kernel 4a/4b: anchor softmax over sequence axis (per b, channel)
// ---------------------------------------------------------------------------
__global__ __launch_bounds__(256) void anchor_partial(const __bf16* __restrict__ fa,
                                                      float* __restrict__ pmax,
                                                      float* __restrict__ psum) {
    int tx = threadIdx.x;
    int ty = threadIdx.y;
    int c = blockIdx.x * 64 + tx;
    int b = blockIdx.y;
    int sc = blockIdx.z;
    const __bf16* base = fa + ((size_t)(b * SS + sc * 256)) * DD + c;
    float m = -1e30f;
    for (int i = ty; i < 256; i += 4) m = fmaxf(m, (float)base[(size_t)i * DD]);
    __shared__ float red[4][64];
    red[ty][tx] = m;
    __syncthreads();
    float cm = fmaxf(fmaxf(red[0][tx], red[1][tx]), fmaxf(red[2][tx], red[3][tx]));
    float s = 0.f;
    for (int i = ty; i < 256; i += 4) s += expf((float)base[(size_t)i * DD] - cm);
    __syncthreads();
    red[ty][tx] = s;
    __syncthreads();
    if (ty == 0) {
        float tot = red[0][tx] + red[1][tx] + red[2][tx] + red[3][tx];
        int o = (b * 4 + sc) * DD + c;
        pmax[o] = cm;
        psum[o] = tot;
    }
}

__global__ __launch_bounds__(256) void anchor_merge(const float* __restrict__ pmax,
                                                    const float* __restrict__ psum,
                                                    float2* __restrict__ smscale) {
    int idx = blockIdx.x * 256 + threadIdx.x;
    int b = idx >> 9;
    int c = idx & 511;
    float M = -1e30f;
#pragma unroll
    for (int j = 0; j < 4; ++j) M = fmaxf(M, pmax[(b * 4 + j) * DD + c]);
    float Z = 0.f;
#pragma unroll
    for (int j = 0; j < 4; ++j) Z += psum[(b * 4 + j) * DD + c] * expf(pmax[(b * 4 + j) * DD + c] - M);
    smscale[idx] = make_float2(M, 1.0f / Z);
}

// Kernel 4c: kw = k * exp(fa - M) * invZ  (vectorized bf16x8)
__global__ __launch_bounds__(256) void kweight(const __bf16* __restrict__ fa,
                                               const __bf16* __restrict__ kin,
                                               const float2* __restrict__ sm,
                                               __bf16* __restrict__ kw) {
    size_t f = ((size_t)blockIdx.x * 256 + threadIdx.x) * 8;
    int b = (int)(f >> 19);
    int c = (int)(f & 511);
    bf16x8 fv = *reinterpret_cast<const bf16x8*>(fa + f);
    bf16x8 kv = *reinterpret_cast<const bf16x8*>(kin + f);
    const float2* smb = sm + b * DD + c;
    bf16x8 o;
#pragma unroll
    for (int j = 0; j < 8; ++j) {
        float2 s = smb[j];
        o[j] = (__bf16)((float)kv[j] * expf((float)fv[j] - s.x) * s.y);
    }
    *reinterpret_cast<bf16x8*>(kw + f) = o;
}

// ---------------------------------------------------------------------------
// Kernel 5: V transpose  v[b][t][h*32+d] -> vt[((b*16+h)*32+d)][t]
// ---------------------------------------------------------------------------
__global__ __launch_bounds__(256) void vtrans(const __bf16* __restrict__ v,
                                              __bf16* __restrict__ vt) {
    int t0 = blockIdx.x * 32;
    int h = blockIdx.y;
    int b = blockIdx.z;
    __shared__ unsigned short lds[32][33];
    int tid = threadIdx.x;
    int r = tid >> 3, c4 = (tid & 7) * 4;
    const unsigned short* vp = (const unsigned short*)v + ((size_t)(b * SS + t0 + r)) * DD + h * 32 + c4;
    us4 val = *reinterpret_cast<const us4*>(vp);
    lds[r][c4 + 0] = val[0]; lds[r][c4 + 1] = val[1];
    lds[r][c4 + 2] = val[2]; lds[r][c4 + 3] = val[3];
    __syncthreads();
    us4 o;
    o[0] = lds[c4 + 0][r]; o[1] = lds[c4 + 1][r];
    o[2] = lds[c4 + 2][r]; o[3] = lds[c4 + 3][r];
    unsigned short* op = (unsigned short*)vt + ((size_t)((b * 16 + h) * 32 + r)) * SS + t0 + c4;
    *reinterpret_cast<us4*>(op) = o;
}

// ---------------------------------------------------------------------------
// Kernel 6: MFMA attention, TSPLIT=8 (2 waves/SIMD), bf16 partials.
// grid (64 s-tiles, 4 b, 8 t-splits), block 64 (1 wave).
// ---------------------------------------------------------------------------
#define TSPLIT 8
struct P8 { __bf16* p[8]; };

__global__ __launch_bounds__(64, 2) void attn_mfma(const __bf16* __restrict__ q,
                                                   const __bf16* __restrict__ kw,
                                                   const __bf16* __restrict__ vt,
                                                   P8 ps) {
    int st = blockIdx.x;
    int b = blockIdx.y;
    int tp = blockIdx.z;
    int l = threadIdx.x;
    int lg = l >> 4;
    int lr = l & 15;

    int s0 = st * 16;
    bf16x8 qf[16];
    const __bf16* qbase = q + ((size_t)(b * SS + s0 + lr)) * DD + lg * 8;
#pragma unroll
    for (int h = 0; h < 16; ++h) qf[h] = *reinterpret_cast<const bf16x8*>(qbase + h * 32);

    f32x4 acc[16][2];
#pragma unroll
    for (int h = 0; h < 16; ++h) {
        acc[h][0] = (f32x4){0.f, 0.f, 0.f, 0.f};
        acc[h][1] = (f32x4){0.f, 0.f, 0.f, 0.f};
    }

    const __bf16* kwb = kw + (size_t)(b * SS) * DD;
    const __bf16* vtb = vt + (size_t)(b * 16) * 32 * SS;
    int trowA = 8 * (lr >> 2) + (lr & 3);
    int trowB = trowA + 4;

    int tbase0 = tp * (SS / TSPLIT);
    for (int tc = 0; tc < SS / TSPLIT; tc += 32) {
        int tbase = tbase0 + tc;
        f32x4 sc[16];
        __builtin_amdgcn_s_setprio(1);
#pragma unroll
        for (int h = 0; h < 16; ++h) {
            bf16x8 ka = *reinterpret_cast<const bf16x8*>(kwb + (size_t)(tbase + trowA) * DD + h * 32 + lg * 8);
            f32x4 z = (f32x4){0.f, 0.f, 0.f, 0.f};
            sc[h] = __builtin_amdgcn_mfma_f32_16x16x32_bf16(ka, qf[h], z, 0, 0, 0);
        }
        __builtin_amdgcn_s_setprio(0);
        bf16x4 pA[16];
#pragma unroll
        for (int r = 0; r < 4; ++r) {
            float m = sc[0][r];
#pragma unroll
            for (int h = 1; h < 16; ++h) m = fmaxf(m, sc[h][r]);
            float e[16]; float zs = 0.f;
#pragma unroll
            for (int h = 0; h < 16; ++h) { e[h] = exp2f((sc[h][r] - m) * SCLOG2E); zs += e[h]; }
            float inv = 1.0f / zs;
#pragma unroll
            for (int h = 0; h < 16; ++h) pA[h][r] = (__bf16)(e[h] * inv);
        }
        __builtin_amdgcn_s_setprio(1);
#pragma unroll
        for (int h = 0; h < 16; ++h) {
            bf16x8 ka = *reinterpret_cast<const bf16x8*>(kwb + (size_t)(tbase + trowB) * DD + h * 32 + lg * 8);
            f32x4 z = (f32x4){0.f, 0.f, 0.f, 0.f};
            sc[h] = __builtin_amdgcn_mfma_f32_16x16x32_bf16(ka, qf[h], z, 0, 0, 0);
        }
        __builtin_amdgcn_s_setprio(0);
        bf16x4 pB[16];
#pragma unroll
        for (int r = 0; r < 4; ++r) {
            float m = sc[0][r];
#pragma unroll
            for (int h = 1; h < 16; ++h) m = fmaxf(m, sc[h][r]);
            float e[16]; float zs = 0.f;
#pragma unroll
            for (int h = 0; h < 16; ++h) { e[h] = exp2f((sc[h][r] - m) * SCLOG2E); zs += e[h]; }
            float inv = 1.0f / zs;
#pragma unroll
            for (int h = 0; h < 16; ++h) pB[h][r] = (__bf16)(e[h] * inv);
        }
        __builtin_amdgcn_s_setprio(1);
#pragma unroll
        for (int h = 0; h < 16; ++h) {
            bf16x8 p = __builtin_shufflevector(pA[h], pB[h], 0, 1, 2, 3, 4, 5, 6, 7);
#pragma unroll
            for (int dh = 0; dh < 2; ++dh) {
                bf16x8 vf = *reinterpret_cast<const bf16x8*>(
                    vtb + (size_t)(h * 32 + dh * 16 + lr) * SS + tbase + lg * 8);
                acc[h][dh] = __builtin_amdgcn_mfma_f32_16x16x32_bf16(p, vf, acc[h][dh], 0, 0, 0);
            }
        }
        __builtin_amdgcn_s_setprio(0);
    }

    __bf16* pb = ps.p[tp] + ((size_t)(b * SS + s0)) * DD;
#pragma unroll
    for (int h = 0; h < 16; ++h)
#pragma unroll
        for (int dh = 0; dh < 2; ++dh)
#pragma unroll
            for (int r = 0; r < 4; ++r)
                pb[(size_t)(lg * 4 + r) * DD + h * 32 + dh * 16 + lr] = (__bf16)acc[h][dh][r];
}

// ---------------------------------------------------------------------------
// Kernel 7: combine  comb = (sum of 8 partials)*mg + hf  -> bf16
// ---------------------------------------------------------------------------
struct P8c { const __bf16* p[8]; };

__global__ __launch_bounds__(256) void combine_kernel(P8c ps,
                                                      const __bf16* __restrict__ mg,
                                                      const __bf16* __restrict__ hf,
                                                      __bf16* __restrict__ comb) {
    size_t f = ((size_t)blockIdx.x * 256 + threadIdx.x) * 8;
    float accv[8] = {0.f, 0.f, 0.f, 0.f, 0.f, 0.f, 0.f, 0.f};
#pragma unroll
    for (int i = 0; i < 8; ++i) {
        bf16x8 v = *reinterpret_cast<const bf16x8*>(ps.p[i] + f);
#pragma unroll
        for (int j = 0; j < 8; ++j) accv[j] += (float)v[j];
    }
    bf16x8 m = *reinterpret_cast<const bf16x8*>(mg + f);
    bf16x8 hh = *reinterpret_cast<const bf16x8*>(hf + f);
    bf16x8 o;
#pragma unroll
    for (int j = 0; j < 8; ++j) o[j] = (__bf16)(accv[j] * (float)m[j] + (float)hh[j]);
    *reinterpret_cast<bf16x8*>(comb + f) = o;
}

// ---------------------------------------------------------------------------
extern "C" void kernel_launch(void* const* d_in, const int* in_sizes, int n_in,
                              void* d_out, int out_size, void* d_ws, size_t ws_size,
                              hipStream_t stream) {
    const float* x    = (const float*)d_in[0];
    const float* ln_g = (const float*)d_in[1];
    const float* ln_b = (const float*)d_in[2];
    const float* Wfa  = (const float*)d_in[3];  const float* bfa = (const float*)d_in[4];
    const float* Whp  = (const float*)d_in[5];  const float* bhp = (const float*)d_in[6];
    const float* Wmg  = (const float*)d_in[7];  const float* bmg = (const float*)d_in[8];
    const float* Wq   = (const float*)d_in[9];  const float* bq  = (const float*)d_in[10];
    const float* Wk   = (const float*)d_in[11]; const float* bk  = (const float*)d_in[12];
    const float* Wv   = (const float*)d_in[13]; const float* bv  = (const float*)d_in[14];
    const float* Wo   = (const float*)d_in[15]; const float* bo  = (const float*)d_in[16];
    float* out = (float*)d_out;

    char* w8 = (char*)d_ws;
    // Memory map (MB offsets). NOTE: every [B,S,D] bf16 tensor is 4 MB
    // (2M elems x 2B) — round-3 bug was hf/mg sized 2 MB.
    __bf16* Wt   = (__bf16*)(w8 + ((size_t) 0 << 20)); // 3.5 MB used
    __bf16* xn   = (__bf16*)(w8 + ((size_t) 4 << 20)); // [4,8)   dead after 6-gemm
    __bf16* fa   = (__bf16*)(w8 + ((size_t) 8 << 20)); // [8,12)  dead after kweight
    __bf16* hf   = (__bf16*)(w8 + ((size_t)12 << 20)); // [12,16)
    __bf16* mg   = (__bf16*)(w8 + ((size_t)16 << 20)); // [16,20)
    __bf16* q    = (__bf16*)(w8 + ((size_t)20 << 20)); // [20,24)
    __bf16* k    = (__bf16*)(w8 + ((size_t)24 << 20)); // [24,28) dead after kweight
    __bf16* v    = (__bf16*)(w8 + ((size_t)28 << 20)); // [28,32) dead after vtrans
    __bf16* kw   = (__bf16*)(w8 + ((size_t)32 << 20)); // [32,36)
    __bf16* vt   = (__bf16*)(w8 + ((size_t)36 << 20)); // [36,40)
    // 8 bf16 partials (4 MB each): reuse dead xn/fa/k/v + fresh [40,56)
    P8 ps;
    ps.p[0] = (__bf16*)(w8 + ((size_t) 4 << 20));
    ps.p[1] = (__bf16*)(w8 + ((size_t) 8 << 20));
    ps.p[2] = (__bf16*)(w8 + ((size_t)24 << 20));
    ps.p[3] = (__bf16*)(w8 + ((size_t)28 << 20));
    ps.p[4] = (__bf16*)(w8 + ((size_t)40 << 20));
    ps.p[5] = (__bf16*)(w8 + ((size_t)44 << 20));
    ps.p[6] = (__bf16*)(w8 + ((size_t)48 << 20));
    ps.p[7] = (__bf16*)(w8 + ((size_t)52 << 20));
    __bf16* comb = (__bf16*)(w8 + ((size_t)56 << 20)); // [56,60)
    float* pmax  = (float*) (w8 + ((size_t)60 << 20)); // stats ~80 KB
    float* psum  = pmax + 16 * DD;
    float2* smsc = (float2*)(psum + 16 * DD);

    // 1. LayerNorm -> xn bf16
    ln_kernel<<<NTOK, 256, 0, stream>>>(x, ln_g, ln_b, xn);

    // 2. Weight transpose+cast
    W7 wp; wp.p[0]=Wfa; wp.p[1]=Whp; wp.p[2]=Wmg; wp.p[3]=Wq; wp.p[4]=Wk; wp.p[5]=Wv; wp.p[6]=Wo;
    wprep<<<dim3(16, 16, 7), 256, 0, stream>>>(wp, Wt);

    // 3. Fused 6-projection MFMA GEMM
    GemmCfg cfg;
    cfg.bias[0]=bfa; cfg.out[0]=fa; cfg.mode[0]=2;
    cfg.bias[1]=bhp; cfg.out[1]=hf; cfg.mode[1]=2;
    cfg.bias[2]=bmg; cfg.out[2]=mg; cfg.mode[2]=1;
    cfg.bias[3]=bq;  cfg.out[3]=q;  cfg.mode[3]=2;
    cfg.bias[4]=bk;  cfg.out[4]=k;  cfg.mode[4]=2;
    cfg.bias[5]=bv;  cfg.out[5]=v;  cfg.mode[5]=2;
    mfma_gemm<<<dim3(32, 8, 6), 256, 0, stream>>>(xn, Wt, cfg, nullptr);

    // 4. anchor softmax over sequence axis
    anchor_partial<<<dim3(8, 4, 4), dim3(64, 4), 0, stream>>>(fa, pmax, psum);
    anchor_merge<<<8, 256, 0, stream>>>(pmax, psum, smsc);
    kweight<<<1024, 256, 0, stream>>>(fa, k, smsc, kw);

    // 5. V transpose
    vtrans<<<dim3(32, 16, 4), 256, 0, stream>>>(v, vt);

    // 6. MFMA attention -> 8 bf16 partials
    attn_mfma<<<dim3(64, 4, 8), 64, 0, stream>>>(q, kw, vt, ps);

    // 7. combine
    P8c pc;
    for (int i = 0; i < 8; ++i) pc.p[i] = ps.p[i];
    combine_kernel<<<1024, 256, 0, stream>>>(pc, mg, hf, comb);

    // 8. output projection + residual
    GemmCfg cfg2;
    for (int i = 0; i < 6; ++i) { cfg2.bias[i]=bo; cfg2.out[i]=out; cfg2.mode[i]=0; }
    mfma_gemm<<<dim3(32, 8, 1), 256, 0, stream>>>(comb, Wt + (size_t)6 * DD * DD, cfg2, x);
}

// Round 5
// 239.222 us; speedup vs baseline: 3.1772x; 1.1469x over previous
//
#include <hip/hip_runtime.h>
#include <hip/hip_bf16.h>
#include <math.h>

#define BB 4
#define SS 1024
#define DD 512
#define HH 16
#define HD 32
#define NTOK (BB * SS)             // 4096
#define NELEM ((size_t)NTOK * DD)  // 2M elements per [B,S,D]
#define SCALE 0.17677669529663687f // 1/sqrt(32)
#define SCLOG2E 0.25505526082484745f // SCALE * log2(e)

typedef __attribute__((ext_vector_type(8))) __bf16 bf16x8;
typedef __attribute__((ext_vector_type(4))) __bf16 bf16x4;
typedef __attribute__((ext_vector_type(4))) float f32x4;
typedef __attribute__((ext_vector_type(4))) unsigned short us4;

// ---------------------------------------------------------------------------
// Kernel 1: LayerNorm  x[4096,512] f32 -> xn bf16
// ---------------------------------------------------------------------------
__global__ __launch_bounds__(256) void ln_kernel(const float* __restrict__ x,
                                                 const float* __restrict__ g,
                                                 const float* __restrict__ bta,
                                                 __bf16* __restrict__ xn) {
    int row = blockIdx.x;
    int tid = threadIdx.x;
    const float* xr = x + (size_t)row * DD;
    float2 v = *reinterpret_cast<const float2*>(&xr[tid * 2]);
    float s1 = v.x + v.y;
    float s2 = v.x * v.x + v.y * v.y;
    for (int off = 32; off > 0; off >>= 1) {
        s1 += __shfl_down(s1, off);
        s2 += __shfl_down(s2, off);
    }
    __shared__ float r1[4], r2[4];
    int w = tid >> 6;
    if ((tid & 63) == 0) { r1[w] = s1; r2[w] = s2; }
    __syncthreads();
    s1 = r1[0] + r1[1] + r1[2] + r1[3];
    s2 = r2[0] + r2[1] + r2[2] + r2[3];
    float mu = s1 * (1.0f / DD);
    float var = s2 * (1.0f / DD) - mu * mu;
    float rstd = rsqrtf(var + 1e-5f);
    float2 gg = *reinterpret_cast<const float2*>(&g[tid * 2]);
    float2 bb = *reinterpret_cast<const float2*>(&bta[tid * 2]);
    __bf16* xp = xn + (size_t)row * DD + tid * 2;
    xp[0] = (__bf16)((v.x - mu) * rstd * gg.x + bb.x);
    xp[1] = (__bf16)((v.y - mu) * rstd * gg.y + bb.y);
}

// ---------------------------------------------------------------------------
// Kernel 2: weight prep — Wt[z][n][k] = bf16(W_z[k][n]), z = 0..6
// ---------------------------------------------------------------------------
struct W7 { const float* p[7]; };

__global__ __launch_bounds__(256) void wprep(W7 wp, __bf16* __restrict__ Wt) {
    int z = blockIdx.z;
    int kt = blockIdx.x, nt = blockIdx.y;
    const float* W = wp.p[z];
    __shared__ float lds[32][33];
    int tid = threadIdx.x;
    int r = tid >> 3, c4 = (tid & 7) * 4;
    float4 vv = *reinterpret_cast<const float4*>(W + (size_t)(kt * 32 + r) * DD + nt * 32 + c4);
    lds[r][c4 + 0] = vv.x; lds[r][c4 + 1] = vv.y;
    lds[r][c4 + 2] = vv.z; lds[r][c4 + 3] = vv.w;
    __syncthreads();
    __bf16* o = Wt + (size_t)z * DD * DD + (size_t)(nt * 32 + r) * DD + kt * 32 + c4;
    o[0] = (__bf16)lds[c4 + 0][r];
    o[1] = (__bf16)lds[c4 + 1][r];
    o[2] = (__bf16)lds[c4 + 2][r];
    o[3] = (__bf16)lds[c4 + 3][r];
}

// ---------------------------------------------------------------------------
// Kernel 3: bf16 MFMA GEMM, no-LDS (A and Wt are L2-resident).
// mode: 0 = f32 (+resid), 1 = sigmoid->bf16, 2 = bf16
// ---------------------------------------------------------------------------
struct GemmCfg { const float* bias[6]; void* out[6]; int mode[6]; };

__global__ __launch_bounds__(256) void mfma_gemm(const __bf16* __restrict__ A,
                                                 const __bf16* __restrict__ Wt0,
                                                 GemmCfg cfg,
                                                 const float* __restrict__ resid) {
    int z = blockIdx.z;
    const __bf16* W = Wt0 + (size_t)z * DD * DD;
    int tid = threadIdx.x;
    int l = tid & 63, wid = tid >> 6;
    int lr = l & 15, lg = l >> 4;
    int wm = wid >> 1, wn = wid & 1;
    int bm = blockIdx.x * 128 + wm * 64;
    int bn = blockIdx.y * 64 + wn * 32;

    f32x4 acc[4][2];
#pragma unroll
    for (int i = 0; i < 4; ++i)
#pragma unroll
        for (int j = 0; j < 2; ++j) acc[i][j] = (f32x4){0.f, 0.f, 0.f, 0.f};

    const __bf16* Ab = A + (size_t)(bm + lr) * DD + lg * 8;
    const __bf16* Bb = W + (size_t)(bn + lr) * DD + lg * 8;

#pragma unroll 4
    for (int k0 = 0; k0 < DD; k0 += 32) {
        bf16x8 af[4], wf[2];
#pragma unroll
        for (int mi = 0; mi < 4; ++mi)
            af[mi] = *reinterpret_cast<const bf16x8*>(Ab + (size_t)mi * 16 * DD + k0);
#pragma unroll
        for (int ni = 0; ni < 2; ++ni)
            wf[ni] = *reinterpret_cast<const bf16x8*>(Bb + (size_t)ni * 16 * DD + k0);
#pragma unroll
        for (int mi = 0; mi < 4; ++mi)
#pragma unroll
            for (int ni = 0; ni < 2; ++ni)
                acc[mi][ni] = __builtin_amdgcn_mfma_f32_16x16x32_bf16(af[mi], wf[ni], acc[mi][ni], 0, 0, 0);
    }

    int mode = cfg.mode[z];
    const float* bias = cfg.bias[z];
    float bv[2] = {bias[bn + lr], bias[bn + 16 + lr]};
#pragma unroll
    for (int mi = 0; mi < 4; ++mi) {
#pragma unroll
        for (int ni = 0; ni < 2; ++ni) {
#pragma unroll
            for (int r = 0; r < 4; ++r) {
                int row = bm + mi * 16 + lg * 4 + r;
                int col = bn + ni * 16 + lr;
                float val = acc[mi][ni][r] + bv[ni];
                if (mode == 0) {
                    if (resid) val += resid[(size_t)row * DD + col];
                    ((float*)cfg.out[z])[(size_t)row * DD + col] = val;
                } else if (mode == 1) {
                    val = 1.0f / (1.0f + expf(-val));
                    ((__bf16*)cfg.out[z])[(size_t)row * DD + col] = (__bf16)val;
                } else {
                    ((__bf16*)cfg.out[z])[(size_t)row * DD + col] = (__bf16)val;
                }
            }
        }
    }
}

// ---------------------------------------------------------------------------
// Kernel 4a/4b: anchor softmax over sequence axis (per b, channel)
// ---------------------------------------------------------------------------
__global__ __launch_bounds__(256) void anchor_partial(const __bf16* __restrict__ fa,
                                                      float* __restrict__ pmax,
                                                      float* __restrict__ psum) {
    int tx = threadIdx.x;
    int ty = threadIdx.y;
    int c = blockIdx.x * 64 + tx;
    int b = blockIdx.y;
    int sc = blockIdx.z;
    const __bf16* base = fa + ((size_t)(b * SS + sc * 256)) * DD + c;
    float m = -1e30f;
    for (int i = ty; i < 256; i += 4) m = fmaxf(m, (float)base[(size_t)i * DD]);
    __shared__ float red[4][64];
    red[ty][tx] = m;
    __syncthreads();
    float cm = fmaxf(fmaxf(red[0][tx], red[1][tx]), fmaxf(red[2][tx], red[3][tx]));
    float s = 0.f;
    for (int i = ty; i < 256; i += 4) s += expf((float)base[(size_t)i * DD] - cm);
    __syncthreads();
    red[ty][tx] = s;
    __syncthreads();
    if (ty == 0) {
        float tot = red[0][tx] + red[1][tx] + red[2][tx] + red[3][tx];
        int o = (b * 4 + sc) * DD + c;
        pmax[o] = cm;
        psum[o] = tot;
    }
}

__global__ __launch_bounds__(256) void anchor_merge(const float* __restrict__ pmax,
                                                    const float* __restrict__ psum,
                                                    float2* __restrict__ smscale) {
    int idx = blockIdx.x * 256 + threadIdx.x;
    int b = idx >> 9;
    int c = idx & 511;
    float M = -1e30f;
#pragma unroll
    for (int j = 0; j < 4; ++j) M = fmaxf(M, pmax[(b * 4 + j) * DD + c]);
    float Z = 0.f;
#pragma unroll
    for (int j = 0; j < 4; ++j) Z += psum[(b * 4 + j) * DD + c] * expf(pmax[(b * 4 + j) * DD + c] - M);
    smscale[idx] = make_float2(M, 1.0f / Z);
}

// Kernel 4c: kw = k * exp(fa - M) * invZ  (vectorized bf16x8)
__global__ __launch_bounds__(256) void kweight(const __bf16* __restrict__ fa,
                                               const __bf16* __restrict__ kin,
                                               const float2* __restrict__ sm,
                                               __bf16* __restrict__ kw) {
    size_t f = ((size_t)blockIdx.x * 256 + threadIdx.x) * 8;
    int b = (int)(f >> 19);
    int c = (int)(f & 511);
    bf16x8 fv = *reinterpret_cast<const bf16x8*>(fa + f);
    bf16x8 kv = *reinterpret_cast<const bf16x8*>(kin + f);
    const float2* smb = sm + b * DD + c;
    bf16x8 o;
#pragma unroll
    for (int j = 0; j < 8; ++j) {
        float2 s = smb[j];
        o[j] = (__bf16)((float)kv[j] * expf((float)fv[j] - s.x) * s.y);
    }
    *reinterpret_cast<bf16x8*>(kw + f) = o;
}

// ---------------------------------------------------------------------------
// Kernel 5: V transpose  v[b][t][h*32+d] -> vt[((b*16+h)*32+d)][t]
// ---------------------------------------------------------------------------
__global__ __launch_bounds__(256) void vtrans(const __bf16* __restrict__ v,
                                              __bf16* __restrict__ vt) {
    int t0 = blockIdx.x * 32;
    int h = blockIdx.y;
    int b = blockIdx.z;
    __shared__ unsigned short lds[32][33];
    int tid = threadIdx.x;
    int r = tid >> 3, c4 = (tid & 7) * 4;
    const unsigned short* vp = (const unsigned short*)v + ((size_t)(b * SS + t0 + r)) * DD + h * 32 + c4;
    us4 val = *reinterpret_cast<const us4*>(vp);
    lds[r][c4 + 0] = val[0]; lds[r][c4 + 1] = val[1];
    lds[r][c4 + 2] = val[2]; lds[r][c4 + 3] = val[3];
    __syncthreads();
    us4 o;
    o[0] = lds[c4 + 0][r]; o[1] = lds[c4 + 1][r];
    o[2] = lds[c4 + 2][r]; o[3] = lds[c4 + 3][r];
    unsigned short* op = (unsigned short*)vt + ((size_t)((b * 16 + h) * 32 + r)) * SS + t0 + c4;
    *reinterpret_cast<us4*>(op) = o;
}

// ---------------------------------------------------------------------------
// Kernel 6: MFMA attention, TSPLIT=8 (2048 waves -> 2 waves/SIMD).
// Round-4 lesson: __launch_bounds__(64,2) clamped VGPR to 128 -> huge spills
// (FETCH 186MB). Fix: (64,1) like round 2 (196 regs, no spill) + cut live
// set so allocation stays <=256: q fragments are RELOADED from L2 per batch
// (not resident), and loads are batched 4-wide ahead of each MFMA group to
// break the load->mfma latency serialization.
// ---------------------------------------------------------------------------
#define TSPLIT 8
struct P8 { __bf16* p[8]; };

__global__ __launch_bounds__(64, 1) void attn_mfma(const __bf16* __restrict__ q,
                                                   const __bf16* __restrict__ kw,
                                                   const __bf16* __restrict__ vt,
                                                   P8 ps) {
    int st = blockIdx.x;
    int b = blockIdx.y;
    int tp = blockIdx.z;
    int l = threadIdx.x;
    int lg = l >> 4;
    int lr = l & 15;
    int s0 = st * 16;

    const __bf16* qbase = q + ((size_t)(b * SS + s0 + lr)) * DD + lg * 8;

    f32x4 acc[16][2];
#pragma unroll
    for (int h = 0; h < 16; ++h) {
        acc[h][0] = (f32x4){0.f, 0.f, 0.f, 0.f};
        acc[h][1] = (f32x4){0.f, 0.f, 0.f, 0.f};
    }

    const __bf16* kwb = kw + (size_t)(b * SS) * DD;
    const __bf16* vtb = vt + (size_t)(b * 16) * 32 * SS;
    int trowA = 8 * (lr >> 2) + (lr & 3);
    int trowB = trowA + 4;

    int tbase0 = tp * (SS / TSPLIT);
    for (int tc = 0; tc < SS / TSPLIT; tc += 32) {
        int tbase = tbase0 + tc;
        f32x4 sc[16];
        const __bf16* krowA = kwb + (size_t)(tbase + trowA) * DD + lg * 8;
        const __bf16* krowB = kwb + (size_t)(tbase + trowB) * DD + lg * 8;

        // ---- QK sub-chunk A: batch 4 h (8 independent loads, then 4 mfma)
#pragma unroll
        for (int hb = 0; hb < 16; hb += 4) {
            bf16x8 ka[4], qv[4];
#pragma unroll
            for (int j = 0; j < 4; ++j) {
                ka[j] = *reinterpret_cast<const bf16x8*>(krowA + (hb + j) * 32);
                qv[j] = *reinterpret_cast<const bf16x8*>(qbase + (hb + j) * 32);
            }
            __builtin_amdgcn_s_setprio(1);
#pragma unroll
            for (int j = 0; j < 4; ++j) {
                f32x4 z = (f32x4){0.f, 0.f, 0.f, 0.f};
                sc[hb + j] = __builtin_amdgcn_mfma_f32_16x16x32_bf16(ka[j], qv[j], z, 0, 0, 0);
            }
            __builtin_amdgcn_s_setprio(0);
        }
        bf16x4 pA[16];
#pragma unroll
        for (int r = 0; r < 4; ++r) {
            float m = sc[0][r];
#pragma unroll
            for (int h = 1; h < 16; ++h) m = fmaxf(m, sc[h][r]);
            float e[16]; float zs = 0.f;
#pragma unroll
            for (int h = 0; h < 16; ++h) { e[h] = exp2f((sc[h][r] - m) * SCLOG2E); zs += e[h]; }
            float inv = 1.0f / zs;
#pragma unroll
            for (int h = 0; h < 16; ++h) pA[h][r] = (__bf16)(e[h] * inv);
        }

        // ---- QK sub-chunk B
#pragma unroll
        for (int hb = 0; hb < 16; hb += 4) {
            bf16x8 ka[4], qv[4];
#pragma unroll
            for (int j = 0; j < 4; ++j) {
                ka[j] = *reinterpret_cast<const bf16x8*>(krowB + (hb + j) * 32);
                qv[j] = *reinterpret_cast<const bf16x8*>(qbase + (hb + j) * 32);
            }
            __builtin_amdgcn_s_setprio(1);
#pragma unroll
            for (int j = 0; j < 4; ++j) {
                f32x4 z = (f32x4){0.f, 0.f, 0.f, 0.f};
                sc[hb + j] = __builtin_amdgcn_mfma_f32_16x16x32_bf16(ka[j], qv[j], z, 0, 0, 0);
            }
            __builtin_amdgcn_s_setprio(0);
        }
        bf16x4 pB[16];
#pragma unroll
        for (int r = 0; r < 4; ++r) {
            float m = sc[0][r];
#pragma unroll
            for (int h = 1; h < 16; ++h) m = fmaxf(m, sc[h][r]);
            float e[16]; float zs = 0.f;
#pragma unroll
            for (int h = 0; h < 16; ++h) { e[h] = exp2f((sc[h][r] - m) * SCLOG2E); zs += e[h]; }
            float inv = 1.0f / zs;
#pragma unroll
            for (int h = 0; h < 16; ++h) pB[h][r] = (__bf16)(e[h] * inv);
        }

        // ---- PV: batch 4 h (8 independent vf loads, then 8 mfma)
#pragma unroll
        for (int hb = 0; hb < 16; hb += 4) {
            bf16x8 vf[8];
#pragma unroll
            for (int j = 0; j < 4; ++j) {
                int h = hb + j;
                vf[2 * j + 0] = *reinterpret_cast<const bf16x8*>(
                    vtb + (size_t)(h * 32 + lr) * SS + tbase + lg * 8);
                vf[2 * j + 1] = *reinterpret_cast<const bf16x8*>(
                    vtb + (size_t)(h * 32 + 16 + lr) * SS + tbase + lg * 8);
            }
            __builtin_amdgcn_s_setprio(1);
#pragma unroll
            for (int j = 0; j < 4; ++j) {
                int h = hb + j;
                bf16x8 p = __builtin_shufflevector(pA[h], pB[h], 0, 1, 2, 3, 4, 5, 6, 7);
                acc[h][0] = __builtin_amdgcn_mfma_f32_16x16x32_bf16(p, vf[2 * j + 0], acc[h][0], 0, 0, 0);
                acc[h][1] = __builtin_amdgcn_mfma_f32_16x16x32_bf16(p, vf[2 * j + 1], acc[h][1], 0, 0, 0);
            }
            __builtin_amdgcn_s_setprio(0);
        }
    }

    __bf16* pb = ps.p[tp] + ((size_t)(b * SS + s0)) * DD;
#pragma unroll
    for (int h = 0; h < 16; ++h)
#pragma unroll
        for (int dh = 0; dh < 2; ++dh)
#pragma unroll
            for (int r = 0; r < 4; ++r)
                pb[(size_t)(lg * 4 + r) * DD + h * 32 + dh * 16 + lr] = (__bf16)acc[h][dh][r];
}

// ---------------------------------------------------------------------------
// Kernel 7: combine  comb = (sum of 8 partials)*mg + hf  -> bf16
// ---------------------------------------------------------------------------
struct P8c { const __bf16* p[8]; };

__global__ __launch_bounds__(256) void combine_kernel(P8c ps,
                                                      const __bf16* __restrict__ mg,
                                                      const __bf16* __restrict__ hf,
                                                      __bf16* __restrict__ comb) {
    size_t f = ((size_t)blockIdx.x * 256 + threadIdx.x) * 8;
    float accv[8] = {0.f, 0.f, 0.f, 0.f, 0.f, 0.f, 0.f, 0.f};
#pragma unroll
    for (int i = 0; i < 8; ++i) {
        bf16x8 v = *reinterpret_cast<const bf16x8*>(ps.p[i] + f);
#pragma unroll
        for (int j = 0; j < 8; ++j) accv[j] += (float)v[j];
    }
    bf16x8 m = *reinterpret_cast<const bf16x8*>(mg + f);
    bf16x8 hh = *reinterpret_cast<const bf16x8*>(hf + f);
    bf16x8 o;
#pragma unroll
    for (int j = 0; j < 8; ++j) o[j] = (__bf16)(accv[j] * (float)m[j] + (float)hh[j]);
    *reinterpret_cast<bf16x8*>(comb + f) = o;
}

// ---------------------------------------------------------------------------
extern "C" void kernel_launch(void* const* d_in, const int* in_sizes, int n_in,
                              void* d_out, int out_size, void* d_ws, size_t ws_size,
                              hipStream_t stream) {
    const float* x    = (const float*)d_in[0];
    const float* ln_g = (const float*)d_in[1];
    const float* ln_b = (const float*)d_in[2];
    const float* Wfa  = (const float*)d_in[3];  const float* bfa = (const float*)d_in[4];
    const float* Whp  = (const float*)d_in[5];  const float* bhp = (const float*)d_in[6];
    const float* Wmg  = (const float*)d_in[7];  const float* bmg = (const float*)d_in[8];
    const float* Wq   = (const float*)d_in[9];  const float* bq  = (const float*)d_in[10];
    const float* Wk   = (const float*)d_in[11]; const float* bk  = (const float*)d_in[12];
    const float* Wv   = (const float*)d_in[13]; const float* bv  = (const float*)d_in[14];
    const float* Wo   = (const float*)d_in[15]; const float* bo  = (const float*)d_in[16];
    float* out = (float*)d_out;

    char* w8 = (char*)d_ws;
    // Memory map (MB offsets). Every [B,S,D] bf16 tensor is 4 MB.
    __bf16* Wt   = (__bf16*)(w8 + ((size_t) 0 << 20)); // 3.5 MB used
    __bf16* xn   = (__bf16*)(w8 + ((size_t) 4 << 20)); // [4,8)   dead after 6-gemm
    __bf16* fa   = (__bf16*)(w8 + ((size_t) 8 << 20)); // [8,12)  dead after kweight
    __bf16* hf   = (__bf16*)(w8 + ((size_t)12 << 20)); // [12,16)
    __bf16* mg   = (__bf16*)(w8 + ((size_t)16 << 20)); // [16,20)
    __bf16* q    = (__bf16*)(w8 + ((size_t)20 << 20)); // [20,24)
    __bf16* k    = (__bf16*)(w8 + ((size_t)24 << 20)); // [24,28) dead after kweight
    __bf16* v    = (__bf16*)(w8 + ((size_t)28 << 20)); // [28,32) dead after vtrans
    __bf16* kw   = (__bf16*)(w8 + ((size_t)32 << 20)); // [32,36)
    __bf16* vt   = (__bf16*)(w8 + ((size_t)36 << 20)); // [36,40)
    // 8 bf16 partials (4 MB each): reuse dead xn/fa/k/v + fresh [40,56)
    P8 ps;
    ps.p[0] = (__bf16*)(w8 + ((size_t) 4 << 20));
    ps.p[1] = (__bf16*)(w8 + ((size_t) 8 << 20));
    ps.p[2] = (__bf16*)(w8 + ((size_t)24 << 20));
    ps.p[3] = (__bf16*)(w8 + ((size_t)28 << 20));
    ps.p[4] = (__bf16*)(w8 + ((size_t)40 << 20));
    ps.p[5] = (__bf16*)(w8 + ((size_t)44 << 20));
    ps.p[6] = (__bf16*)(w8 + ((size_t)48 << 20));
    ps.p[7] = (__bf16*)(w8 + ((size_t)52 << 20));
    __bf16* comb = (__bf16*)(w8 + ((size_t)56 << 20)); // [56,60)
    float* pmax  = (float*) (w8 + ((size_t)60 << 20)); // stats ~80 KB
    float* psum  = pmax + 16 * DD;
    float2* smsc = (float2*)(psum + 16 * DD);

    // 1. LayerNorm -> xn bf16
    ln_kernel<<<NTOK, 256, 0, stream>>>(x, ln_g, ln_b, xn);

    // 2. Weight transpose+cast
    W7 wp; wp.p[0]=Wfa; wp.p[1]=Whp; wp.p[2]=Wmg; wp.p[3]=Wq; wp.p[4]=Wk; wp.p[5]=Wv; wp.p[6]=Wo;
    wprep<<<dim3(16, 16, 7), 256, 0, stream>>>(wp, Wt);

    // 3. Fused 6-projection MFMA GEMM
    GemmCfg cfg;
    cfg.bias[0]=bfa; cfg.out[0]=fa; cfg.mode[0]=2;
    cfg.bias[1]=bhp; cfg.out[1]=hf; cfg.mode[1]=2;
    cfg.bias[2]=bmg; cfg.out[2]=mg; cfg.mode[2]=1;
    cfg.bias[3]=bq;  cfg.out[3]=q;  cfg.mode[3]=2;
    cfg.bias[4]=bk;  cfg.out[4]=k;  cfg.mode[4]=2;
    cfg.bias[5]=bv;  cfg.out[5]=v;  cfg.mode[5]=2;
    mfma_gemm<<<dim3(32, 8, 6), 256, 0, stream>>>(xn, Wt, cfg, nullptr);

    // 4. anchor softmax over sequence axis
    anchor_partial<<<dim3(8, 4, 4), dim3(64, 4), 0, stream>>>(fa, pmax, psum);
    anchor_merge<<<8, 256, 0, stream>>>(pmax, psum, smsc);
    kweight<<<1024, 256, 0, stream>>>(fa, k, smsc, kw);

    // 5. V transpose
    vtrans<<<dim3(32, 16, 4), 256, 0, stream>>>(v, vt);

    // 6. MFMA attention -> 8 bf16 partials
    attn_mfma<<<dim3(64, 4, 8), 64, 0, stream>>>(q, kw, vt, ps);

    // 7. combine
    P8c pc;
    for (int i = 0; i < 8; ++i) pc.p[i] = ps.p[i];
    combine_kernel<<<1024, 256, 0, stream>>>(pc, mg, hf, comb);

    // 8. output projection + residual
    GemmCfg cfg2;
    for (int i = 0; i < 6; ++i) { cfg2.bias[i]=bo; cfg2.out[i]=out; cfg2.mode[i]=0; }
    mfma_gemm<<<dim3(32, 8, 1), 256, 0, stream>>>(comb, Wt + (size_t)6 * DD * DD, cfg2, x);
}

// Round 6
// 238.174 us; speedup vs baseline: 3.1912x; 1.0044x over previous
//
#include <hip/hip_runtime.h>
#include <hip/hip_bf16.h>
#include <math.h>

#define BB 4
#define SS 1024
#define DD 512
#define HH 16
#define HD 32
#define NTOK (BB * SS)             // 4096
#define NELEM ((size_t)NTOK * DD)  // 2M elements per [B,S,D]
#define SCALE 0.17677669529663687f // 1/sqrt(32)
#define SCLOG2E 0.25505526082484745f // SCALE * log2(e)

typedef __attribute__((ext_vector_type(8))) __bf16 bf16x8;
typedef __attribute__((ext_vector_type(4))) __bf16 bf16x4;
typedef __attribute__((ext_vector_type(4))) float f32x4;
typedef __attribute__((ext_vector_type(4))) unsigned short us4;

__device__ __forceinline__ void gload16(const void* g, void* l) {
    __builtin_amdgcn_global_load_lds(
        (const __attribute__((address_space(1))) void*)g,
        (__attribute__((address_space(3))) void*)l, 16, 0, 0);
}

// ---------------------------------------------------------------------------
// Kernel 1: LayerNorm  x[4096,512] f32 -> xn bf16
// ---------------------------------------------------------------------------
__global__ __launch_bounds__(256) void ln_kernel(const float* __restrict__ x,
                                                 const float* __restrict__ g,
                                                 const float* __restrict__ bta,
                                                 __bf16* __restrict__ xn) {
    int row = blockIdx.x;
    int tid = threadIdx.x;
    const float* xr = x + (size_t)row * DD;
    float2 v = *reinterpret_cast<const float2*>(&xr[tid * 2]);
    float s1 = v.x + v.y;
    float s2 = v.x * v.x + v.y * v.y;
    for (int off = 32; off > 0; off >>= 1) {
        s1 += __shfl_down(s1, off);
        s2 += __shfl_down(s2, off);
    }
    __shared__ float r1[4], r2[4];
    int w = tid >> 6;
    if ((tid & 63) == 0) { r1[w] = s1; r2[w] = s2; }
    __syncthreads();
    s1 = r1[0] + r1[1] + r1[2] + r1[3];
    s2 = r2[0] + r2[1] + r2[2] + r2[3];
    float mu = s1 * (1.0f / DD);
    float var = s2 * (1.0f / DD) - mu * mu;
    float rstd = rsqrtf(var + 1e-5f);
    float2 gg = *reinterpret_cast<const float2*>(&g[tid * 2]);
    float2 bb = *reinterpret_cast<const float2*>(&bta[tid * 2]);
    __bf16* xp = xn + (size_t)row * DD + tid * 2;
    xp[0] = (__bf16)((v.x - mu) * rstd * gg.x + bb.x);
    xp[1] = (__bf16)((v.y - mu) * rstd * gg.y + bb.y);
}

// ---------------------------------------------------------------------------
// Kernel 2: weight prep — Wt[z][n][k] = bf16(W_z[k][n]), z = 0..6
// ---------------------------------------------------------------------------
struct W7 { const float* p[7]; };

__global__ __launch_bounds__(256) void wprep(W7 wp, __bf16* __restrict__ Wt) {
    int z = blockIdx.z;
    int kt = blockIdx.x, nt = blockIdx.y;
    const float* W = wp.p[z];
    __shared__ float lds[32][33];
    int tid = threadIdx.x;
    int r = tid >> 3, c4 = (tid & 7) * 4;
    float4 vv = *reinterpret_cast<const float4*>(W + (size_t)(kt * 32 + r) * DD + nt * 32 + c4);
    lds[r][c4 + 0] = vv.x; lds[r][c4 + 1] = vv.y;
    lds[r][c4 + 2] = vv.z; lds[r][c4 + 3] = vv.w;
    __syncthreads();
    __bf16* o = Wt + (size_t)z * DD * DD + (size_t)(nt * 32 + r) * DD + kt * 32 + c4;
    o[0] = (__bf16)lds[c4 + 0][r];
    o[1] = (__bf16)lds[c4 + 1][r];
    o[2] = (__bf16)lds[c4 + 2][r];
    o[3] = (__bf16)lds[c4 + 3][r];
}

// ---------------------------------------------------------------------------
// Kernel 3: bf16 MFMA GEMM, no-LDS (A and Wt are L2-resident).
// mode: 0 = f32 (+resid), 1 = sigmoid->bf16, 2 = bf16
// ---------------------------------------------------------------------------
struct GemmCfg { const float* bias[6]; void* out[6]; int mode[6]; };

__global__ __launch_bounds__(256) void mfma_gemm(const __bf16* __restrict__ A,
                                                 const __bf16* __restrict__ Wt0,
                                                 GemmCfg cfg,
                                                 const float* __restrict__ resid) {
    int z = blockIdx.z;
    const __bf16* W = Wt0 + (size_t)z * DD * DD;
    int tid = threadIdx.x;
    int l = tid & 63, wid = tid >> 6;
    int lr = l & 15, lg = l >> 4;
    int wm = wid >> 1, wn = wid & 1;
    int bm = blockIdx.x * 128 + wm * 64;
    int bn = blockIdx.y * 64 + wn * 32;

    f32x4 acc[4][2];
#pragma unroll
    for (int i = 0; i < 4; ++i)
#pragma unroll
        for (int j = 0; j < 2; ++j) acc[i][j] = (f32x4){0.f, 0.f, 0.f, 0.f};

    const __bf16* Ab = A + (size_t)(bm + lr) * DD + lg * 8;
    const __bf16* Bb = W + (size_t)(bn + lr) * DD + lg * 8;

#pragma unroll 4
    for (int k0 = 0; k0 < DD; k0 += 32) {
        bf16x8 af[4], wf[2];
#pragma unroll
        for (int mi = 0; mi < 4; ++mi)
            af[mi] = *reinterpret_cast<const bf16x8*>(Ab + (size_t)mi * 16 * DD + k0);
#pragma unroll
        for (int ni = 0; ni < 2; ++ni)
            wf[ni] = *reinterpret_cast<const bf16x8*>(Bb + (size_t)ni * 16 * DD + k0);
#pragma unroll
        for (int mi = 0; mi < 4; ++mi)
#pragma unroll
            for (int ni = 0; ni < 2; ++ni)
                acc[mi][ni] = __builtin_amdgcn_mfma_f32_16x16x32_bf16(af[mi], wf[ni], acc[mi][ni], 0, 0, 0);
    }

    int mode = cfg.mode[z];
    const float* bias = cfg.bias[z];
    float bv[2] = {bias[bn + lr], bias[bn + 16 + lr]};
#pragma unroll
    for (int mi = 0; mi < 4; ++mi) {
#pragma unroll
        for (int ni = 0; ni < 2; ++ni) {
#pragma unroll
            for (int r = 0; r < 4; ++r) {
                int row = bm + mi * 16 + lg * 4 + r;
                int col = bn + ni * 16 + lr;
                float val = acc[mi][ni][r] + bv[ni];
                if (mode == 0) {
                    if (resid) val += resid[(size_t)row * DD + col];
                    ((float*)cfg.out[z])[(size_t)row * DD + col] = val;
                } else if (mode == 1) {
                    val = 1.0f / (1.0f + expf(-val));
                    ((__bf16*)cfg.out[z])[(size_t)row * DD + col] = (__bf16)val;
                } else {
                    ((__bf16*)cfg.out[z])[(size_t)row * DD + col] = (__bf16)val;
                }
            }
        }
    }
}

// ---------------------------------------------------------------------------
// Kernel 4a/4b: anchor softmax over sequence axis (per b, channel)
// ---------------------------------------------------------------------------
__global__ __launch_bounds__(256) void anchor_partial(const __bf16* __restrict__ fa,
                                                      float* __restrict__ pmax,
                                                      float* __restrict__ psum) {
    int tx = threadIdx.x;
    int ty = threadIdx.y;
    int c = blockIdx.x * 64 + tx;
    int b = blockIdx.y;
    int sc = blockIdx.z;
    const __bf16* base = fa + ((size_t)(b * SS + sc * 256)) * DD + c;
    float m = -1e30f;
    for (int i = ty; i < 256; i += 4) m = fmaxf(m, (float)base[(size_t)i * DD]);
    __shared__ float red[4][64];
    red[ty][tx] = m;
    __syncthreads();
    float cm = fmaxf(fmaxf(red[0][tx], red[1][tx]), fmaxf(red[2][tx], red[3][tx]));
    float s = 0.f;
    for (int i = ty; i < 256; i += 4) s += expf((float)base[(size_t)i * DD] - cm);
    __syncthreads();
    red[ty][tx] = s;
    __syncthreads();
    if (ty == 0) {
        float tot = red[0][tx] + red[1][tx] + red[2][tx] + red[3][tx];
        int o = (b * 4 + sc) * DD + c;
        pmax[o] = cm;
        psum[o] = tot;
    }
}

__global__ __launch_bounds__(256) void anchor_merge(const float* __restrict__ pmax,
                                                    const float* __restrict__ psum,
                                                    float2* __restrict__ smscale) {
    int idx = blockIdx.x * 256 + threadIdx.x;
    int b = idx >> 9;
    int c = idx & 511;
    float M = -1e30f;
#pragma unroll
    for (int j = 0; j < 4; ++j) M = fmaxf(M, pmax[(b * 4 + j) * DD + c]);
    float Z = 0.f;
#pragma unroll
    for (int j = 0; j < 4; ++j) Z += psum[(b * 4 + j) * DD + c] * expf(pmax[(b * 4 + j) * DD + c] - M);
    smscale[idx] = make_float2(M, 1.0f / Z);
}

// Kernel 4c: kw = k * exp(fa - M) * invZ  (vectorized bf16x8)
__global__ __launch_bounds__(256) void kweight(const __bf16* __restrict__ fa,
                                               const __bf16* __restrict__ kin,
                                               const float2* __restrict__ sm,
                                               __bf16* __restrict__ kw) {
    size_t f = ((size_t)blockIdx.x * 256 + threadIdx.x) * 8;
    int b = (int)(f >> 19);
    int c = (int)(f & 511);
    bf16x8 fv = *reinterpret_cast<const bf16x8*>(fa + f);
    bf16x8 kv = *reinterpret_cast<const bf16x8*>(kin + f);
    const float2* smb = sm + b * DD + c;
    bf16x8 o;
#pragma unroll
    for (int j = 0; j < 8; ++j) {
        float2 s = smb[j];
        o[j] = (__bf16)((float)kv[j] * expf((float)fv[j] - s.x) * s.y);
    }
    *reinterpret_cast<bf16x8*>(kw + f) = o;
}

// ---------------------------------------------------------------------------
// Kernel 5: V transpose  v[b][t][h*32+d] -> vt[((b*16+h)*32+d)][t]
// ---------------------------------------------------------------------------
__global__ __launch_bounds__(256) void vtrans(const __bf16* __restrict__ v,
                                              __bf16* __restrict__ vt) {
    int t0 = blockIdx.x * 32;
    int h = blockIdx.y;
    int b = blockIdx.z;
    __shared__ unsigned short lds[32][33];
    int tid = threadIdx.x;
    int r = tid >> 3, c4 = (tid & 7) * 4;
    const unsigned short* vp = (const unsigned short*)v + ((size_t)(b * SS + t0 + r)) * DD + h * 32 + c4;
    us4 val = *reinterpret_cast<const us4*>(vp);
    lds[r][c4 + 0] = val[0]; lds[r][c4 + 1] = val[1];
    lds[r][c4 + 2] = val[2]; lds[r][c4 + 3] = val[3];
    __syncthreads();
    us4 o;
    o[0] = lds[c4 + 0][r]; o[1] = lds[c4 + 1][r];
    o[2] = lds[c4 + 2][r]; o[3] = lds[c4 + 3][r];
    unsigned short* op = (unsigned short*)vt + ((size_t)((b * 16 + h) * 32 + r)) * SS + t0 + c4;
    *reinterpret_cast<us4*>(op) = o;
}

// ---------------------------------------------------------------------------
// Kernel 6: MFMA attention, 4-wave blocks sharing LDS-staged kw/vt chunks.
// grid (16 s-groups, 4 b, 8 tp), block 256. Each wave owns 16 s-rows.
// LDS 64KB: kw chunk [32t][1024B] XOR-swizzled + vt chunk [4][512hd][8t].
// Swizzle applied via pre-swizzled GLOBAL source (global_load_lds writes
// linearly); read side XOR collapses to lr<<4 for the permuted t-rows.
// ---------------------------------------------------------------------------
struct P8 { __bf16* p[8]; };

__global__ __launch_bounds__(256, 2) void attn_mfma(const __bf16* __restrict__ q,
                                                    const __bf16* __restrict__ kw,
                                                    const __bf16* __restrict__ vt,
                                                    P8 ps) {
    __shared__ __align__(16) char smem[65536];
    int sg = blockIdx.x;
    int b = blockIdx.y;
    int tp = blockIdx.z;
    int tid = threadIdx.x;
    int wid = tid >> 6;
    int lane = tid & 63;
    int lg = lane >> 4;
    int lr = lane & 15;
    int s0 = (sg * 4 + wid) * 16;

    const __bf16* qbase = q + ((size_t)(b * SS + s0 + lr)) * DD + lg * 8;
    const char* kwb8 = (const char*)kw + (size_t)b * SS * DD * 2;
    const char* vtb8 = (const char*)vt + (size_t)b * 512 * SS * 2;

    f32x4 acc[16][2];
#pragma unroll
    for (int h = 0; h < 16; ++h) {
        acc[h][0] = (f32x4){0.f, 0.f, 0.f, 0.f};
        acc[h][1] = (f32x4){0.f, 0.f, 0.f, 0.f};
    }

    int trowA = 8 * (lr >> 2) + (lr & 3);
    int trowB = trowA + 4;
    int xsl = lr << 4; // read-side XOR for permuted t-rows (bits{0,1,3,4} == lr)

    for (int tc = 0; tc < 128; tc += 32) {
        int tbase = tp * 128 + tc;
        // ---- stage kw: 32 rows x 1024B, source pre-swizzled so linear LDS
        //      write lands swizzled: LDS[row][colb] = kw[row][colb ^ x(row)]
#pragma unroll
        for (int it = 0; it < 8; ++it) {
            int row = it * 4 + wid;                              // wave-uniform
            int colb = (lane * 16) ^ (((row & 3) << 4) | (((row >> 3) & 3) << 6));
            gload16(kwb8 + (size_t)(tbase + row) * 1024 + colb,
                    smem + it * 4096 + wid * 1024);
        }
        // ---- stage vt: [lgq][hd-row][8t] subtiled, linear (conflict-free)
#pragma unroll
        for (int it = 0; it < 8; ++it) {
            int blkid = it * 4 + wid;
            int lgq = blkid >> 3;                                // wave-uniform
            int row = (blkid & 7) * 64 + lane;                   // per-lane
            gload16(vtb8 + (size_t)row * 2048 + (size_t)(tbase + lgq * 8) * 2,
                    smem + 32768 + it * 4096 + wid * 1024);
        }
        asm volatile("s_waitcnt vmcnt(0)" ::: "memory");
        __syncthreads();

        f32x4 sc[16];
        // ---- QK sub-chunk A (t = 8*lg + r)
#pragma unroll
        for (int hb = 0; hb < 16; hb += 4) {
            bf16x8 ka[4], qv[4];
#pragma unroll
            for (int j = 0; j < 4; ++j) {
                int h = hb + j;
                ka[j] = *reinterpret_cast<const bf16x8*>(
                    smem + trowA * 1024 + ((h * 64 + lg * 16) ^ xsl));
                qv[j] = *reinterpret_cast<const bf16x8*>(qbase + h * 32);
            }
            __builtin_amdgcn_s_setprio(1);
#pragma unroll
            for (int j = 0; j < 4; ++j) {
                f32x4 z = (f32x4){0.f, 0.f, 0.f, 0.f};
                sc[hb + j] = __builtin_amdgcn_mfma_f32_16x16x32_bf16(ka[j], qv[j], z, 0, 0, 0);
            }
            __builtin_amdgcn_s_setprio(0);
        }
        bf16x4 pA[16];
#pragma unroll
        for (int r = 0; r < 4; ++r) {
            float e[16]; float zs = 0.f;
#pragma unroll
            for (int h = 0; h < 16; ++h) { e[h] = exp2f(sc[h][r] * SCLOG2E); zs += e[h]; }
            float inv = __builtin_amdgcn_rcpf(zs);
#pragma unroll
            for (int h = 0; h < 16; ++h) pA[h][r] = (__bf16)(e[h] * inv);
        }
        // ---- QK sub-chunk B (t = 8*lg + 4 + r)
#pragma unroll
        for (int hb = 0; hb < 16; hb += 4) {
            bf16x8 ka[4], qv[4];
#pragma unroll
            for (int j = 0; j < 4; ++j) {
                int h = hb + j;
                ka[j] = *reinterpret_cast<const bf16x8*>(
                    smem + trowB * 1024 + ((h * 64 + lg * 16) ^ xsl));
                qv[j] = *reinterpret_cast<const bf16x8*>(qbase + h * 32);
            }
            __builtin_amdgcn_s_setprio(1);
#pragma unroll
            for (int j = 0; j < 4; ++j) {
                f32x4 z = (f32x4){0.f, 0.f, 0.f, 0.f};
                sc[hb + j] = __builtin_amdgcn_mfma_f32_16x16x32_bf16(ka[j], qv[j], z, 0, 0, 0);
            }
            __builtin_amdgcn_s_setprio(0);
        }
        bf16x4 pB[16];
#pragma unroll
        for (int r = 0; r < 4; ++r) {
            float e[16]; float zs = 0.f;
#pragma unroll
            for (int h = 0; h < 16; ++h) { e[h] = exp2f(sc[h][r] * SCLOG2E); zs += e[h]; }
            float inv = __builtin_amdgcn_rcpf(zs);
#pragma unroll
            for (int h = 0; h < 16; ++h) pB[h][r] = (__bf16)(e[h] * inv);
        }
        // ---- PV from vt LDS: lane reads [lg][h*32+dh*16+lr][8t]
#pragma unroll
        for (int hb = 0; hb < 16; hb += 4) {
            bf16x8 vf[8];
#pragma unroll
            for (int j = 0; j < 4; ++j) {
                int h = hb + j;
                vf[2 * j + 0] = *reinterpret_cast<const bf16x8*>(
                    smem + 32768 + lg * 8192 + h * 512 + lr * 16);
                vf[2 * j + 1] = *reinterpret_cast<const bf16x8*>(
                    smem + 32768 + lg * 8192 + h * 512 + 256 + lr * 16);
            }
            __builtin_amdgcn_s_setprio(1);
#pragma unroll
            for (int j = 0; j < 4; ++j) {
                int h = hb + j;
                bf16x8 p = __builtin_shufflevector(pA[h], pB[h], 0, 1, 2, 3, 4, 5, 6, 7);
                acc[h][0] = __builtin_amdgcn_mfma_f32_16x16x32_bf16(p, vf[2 * j + 0], acc[h][0], 0, 0, 0);
                acc[h][1] = __builtin_amdgcn_mfma_f32_16x16x32_bf16(p, vf[2 * j + 1], acc[h][1], 0, 0, 0);
            }
            __builtin_amdgcn_s_setprio(0);
        }
        __syncthreads(); // protect LDS before next chunk's stage
    }

    __bf16* pb = ps.p[tp] + ((size_t)(b * SS + s0)) * DD;
#pragma unroll
    for (int h = 0; h < 16; ++h)
#pragma unroll
        for (int dh = 0; dh < 2; ++dh)
#pragma unroll
            for (int r = 0; r < 4; ++r)
                pb[(size_t)(lg * 4 + r) * DD + h * 32 + dh * 16 + lr] = (__bf16)acc[h][dh][r];
}

// ---------------------------------------------------------------------------
// Kernel 7: combine  comb = (sum of 8 partials)*mg + hf  -> bf16
// ---------------------------------------------------------------------------
struct P8c { const __bf16* p[8]; };

__global__ __launch_bounds__(256) void combine_kernel(P8c ps,
                                                      const __bf16* __restrict__ mg,
                                                      const __bf16* __restrict__ hf,
                                                      __bf16* __restrict__ comb) {
    size_t f = ((size_t)blockIdx.x * 256 + threadIdx.x) * 8;
    float accv[8] = {0.f, 0.f, 0.f, 0.f, 0.f, 0.f, 0.f, 0.f};
#pragma unroll
    for (int i = 0; i < 8; ++i) {
        bf16x8 v = *reinterpret_cast<const bf16x8*>(ps.p[i] + f);
#pragma unroll
        for (int j = 0; j < 8; ++j) accv[j] += (float)v[j];
    }
    bf16x8 m = *reinterpret_cast<const bf16x8*>(mg + f);
    bf16x8 hh = *reinterpret_cast<const bf16x8*>(hf + f);
    bf16x8 o;
#pragma unroll
    for (int j = 0; j < 8; ++j) o[j] = (__bf16)(accv[j] * (float)m[j] + (float)hh[j]);
    *reinterpret_cast<bf16x8*>(comb + f) = o;
}

// ---------------------------------------------------------------------------
extern "C" void kernel_launch(void* const* d_in, const int* in_sizes, int n_in,
                              void* d_out, int out_size, void* d_ws, size_t ws_size,
                              hipStream_t stream) {
    const float* x    = (const float*)d_in[0];
    const float* ln_g = (const float*)d_in[1];
    const float* ln_b = (const float*)d_in[2];
    const float* Wfa  = (const float*)d_in[3];  const float* bfa = (const float*)d_in[4];
    const float* Whp  = (const float*)d_in[5];  const float* bhp = (const float*)d_in[6];
    const float* Wmg  = (const float*)d_in[7];  const float* bmg = (const float*)d_in[8];
    const float* Wq   = (const float*)d_in[9];  const float* bq  = (const float*)d_in[10];
    const float* Wk   = (const float*)d_in[11]; const float* bk  = (const float*)d_in[12];
    const float* Wv   = (const float*)d_in[13]; const float* bv  = (const float*)d_in[14];
    const float* Wo   = (const float*)d_in[15]; const float* bo  = (const float*)d_in[16];
    float* out = (float*)d_out;

    char* w8 = (char*)d_ws;
    // Memory map (MB offsets). Every [B,S,D] bf16 tensor is 4 MB.
    __bf16* Wt   = (__bf16*)(w8 + ((size_t) 0 << 20)); // 3.5 MB used
    __bf16* xn   = (__bf16*)(w8 + ((size_t) 4 << 20)); // [4,8)   dead after 6-gemm
    __bf16* fa   = (__bf16*)(w8 + ((size_t) 8 << 20)); // [8,12)  dead after kweight
    __bf16* hf   = (__bf16*)(w8 + ((size_t)12 << 20)); // [12,16)
    __bf16* mg   = (__bf16*)(w8 + ((size_t)16 << 20)); // [16,20)
    __bf16* q    = (__bf16*)(w8 + ((size_t)20 << 20)); // [20,24)
    __bf16* k    = (__bf16*)(w8 + ((size_t)24 << 20)); // [24,28) dead after kweight
    __bf16* v    = (__bf16*)(w8 + ((size_t)28 << 20)); // [28,32) dead after vtrans
    __bf16* kw   = (__bf16*)(w8 + ((size_t)32 << 20)); // [32,36)
    __bf16* vt   = (__bf16*)(w8 + ((size_t)36 << 20)); // [36,40)
    // 8 bf16 partials (4 MB each): reuse dead xn/fa/k/v + fresh [40,56)
    P8 ps;
    ps.p[0] = (__bf16*)(w8 + ((size_t) 4 << 20));
    ps.p[1] = (__bf16*)(w8 + ((size_t) 8 << 20));
    ps.p[2] = (__bf16*)(w8 + ((size_t)24 << 20));
    ps.p[3] = (__bf16*)(w8 + ((size_t)28 << 20));
    ps.p[4] = (__bf16*)(w8 + ((size_t)40 << 20));
    ps.p[5] = (__bf16*)(w8 + ((size_t)44 << 20));
    ps.p[6] = (__bf16*)(w8 + ((size_t)48 << 20));
    ps.p[7] = (__bf16*)(w8 + ((size_t)52 << 20));
    __bf16* comb = (__bf16*)(w8 + ((size_t)56 << 20)); // [56,60)
    float* pmax  = (float*) (w8 + ((size_t)60 << 20)); // stats ~80 KB
    float* psum  = pmax + 16 * DD;
    float2* smsc = (float2*)(psum + 16 * DD);

    // 1. LayerNorm -> xn bf16
    ln_kernel<<<NTOK, 256, 0, stream>>>(x, ln_g, ln_b, xn);

    // 2. Weight transpose+cast
    W7 wp; wp.p[0]=Wfa; wp.p[1]=Whp; wp.p[2]=Wmg; wp.p[3]=Wq; wp.p[4]=Wk; wp.p[5]=Wv; wp.p[6]=Wo;
    wprep<<<dim3(16, 16, 7), 256, 0, stream>>>(wp, Wt);

    // 3. Fused 6-projection MFMA GEMM
    GemmCfg cfg;
    cfg.bias[0]=bfa; cfg.out[0]=fa; cfg.mode[0]=2;
    cfg.bias[1]=bhp; cfg.out[1]=hf; cfg.mode[1]=2;
    cfg.bias[2]=bmg; cfg.out[2]=mg; cfg.mode[2]=1;
    cfg.bias[3]=bq;  cfg.out[3]=q;  cfg.mode[3]=2;
    cfg.bias[4]=bk;  cfg.out[4]=k;  cfg.mode[4]=2;
    cfg.bias[5]=bv;  cfg.out[5]=v;  cfg.mode[5]=2;
    mfma_gemm<<<dim3(32, 8, 6), 256, 0, stream>>>(xn, Wt, cfg, nullptr);

    // 4. anchor softmax over sequence axis
    anchor_partial<<<dim3(8, 4, 4), dim3(64, 4), 0, stream>>>(fa, pmax, psum);
    anchor_merge<<<8, 256, 0, stream>>>(pmax, psum, smsc);
    kweight<<<1024, 256, 0, stream>>>(fa, k, smsc, kw);

    // 5. V transpose
    vtrans<<<dim3(32, 16, 4), 256, 0, stream>>>(v, vt);

    // 6. MFMA attention -> 8 bf16 partials (4-wave LDS-shared blocks)
    attn_mfma<<<dim3(16, 4, 8), 256, 0, stream>>>(q, kw, vt, ps);

    // 7. combine
    P8c pc;
    for (int i = 0; i < 8; ++i) pc.p[i] = ps.p[i];
    combine_kernel<<<1024, 256, 0, stream>>>(pc, mg, hf, comb);

    // 8. output projection + residual
    GemmCfg cfg2;
    for (int i = 0; i < 6; ++i) { cfg2.bias[i]=bo; cfg2.out[i]=out; cfg2.mode[i]=0; }
    mfma_gemm<<<dim3(32, 8, 1), 256, 0, stream>>>(comb, Wt + (size_t)6 * DD * DD, cfg2, x);
}

// Round 7
// 233.128 us; speedup vs baseline: 3.2603x; 1.0216x over previous
//
#include <hip/hip_runtime.h>
#include <hip/hip_bf16.h>
#include <math.h>

#define BB 4
#define SS 1024
#define DD 512
#define HH 16
#define HD 32
#define NTOK (BB * SS)             // 4096
#define NELEM ((size_t)NTOK * DD)  // 2M elements per [B,S,D]
#define SCALE 0.17677669529663687f // 1/sqrt(32)
#define SCLOG2E 0.25505526082484745f // SCALE * log2(e)

typedef __attribute__((ext_vector_type(8))) __bf16 bf16x8;
typedef __attribute__((ext_vector_type(4))) __bf16 bf16x4;
typedef __attribute__((ext_vector_type(4))) float f32x4;
typedef __attribute__((ext_vector_type(4))) unsigned short us4;

__device__ __forceinline__ void gload16(const void* g, void* l) {
    __builtin_amdgcn_global_load_lds(
        (const __attribute__((address_space(1))) void*)g,
        (__attribute__((address_space(3))) void*)l, 16, 0, 0);
}

// ---------------------------------------------------------------------------
// Kernel 1: LayerNorm  x[4096,512] f32 -> xn bf16
// ---------------------------------------------------------------------------
__global__ __launch_bounds__(256) void ln_kernel(const float* __restrict__ x,
                                                 const float* __restrict__ g,
                                                 const float* __restrict__ bta,
                                                 __bf16* __restrict__ xn) {
    int row = blockIdx.x;
    int tid = threadIdx.x;
    const float* xr = x + (size_t)row * DD;
    float2 v = *reinterpret_cast<const float2*>(&xr[tid * 2]);
    float s1 = v.x + v.y;
    float s2 = v.x * v.x + v.y * v.y;
    for (int off = 32; off > 0; off >>= 1) {
        s1 += __shfl_down(s1, off);
        s2 += __shfl_down(s2, off);
    }
    __shared__ float r1[4], r2[4];
    int w = tid >> 6;
    if ((tid & 63) == 0) { r1[w] = s1; r2[w] = s2; }
    __syncthreads();
    s1 = r1[0] + r1[1] + r1[2] + r1[3];
    s2 = r2[0] + r2[1] + r2[2] + r2[3];
    float mu = s1 * (1.0f / DD);
    float var = s2 * (1.0f / DD) - mu * mu;
    float rstd = rsqrtf(var + 1e-5f);
    float2 gg = *reinterpret_cast<const float2*>(&g[tid * 2]);
    float2 bb = *reinterpret_cast<const float2*>(&bta[tid * 2]);
    __bf16* xp = xn + (size_t)row * DD + tid * 2;
    xp[0] = (__bf16)((v.x - mu) * rstd * gg.x + bb.x);
    xp[1] = (__bf16)((v.y - mu) * rstd * gg.y + bb.y);
}

// ---------------------------------------------------------------------------
// Kernel 2: weight prep — Wt[z][n][k] = bf16(W_z[k][n]), z = 0..6
// ---------------------------------------------------------------------------
struct W7 { const float* p[7]; };

__global__ __launch_bounds__(256) void wprep(W7 wp, __bf16* __restrict__ Wt) {
    int z = blockIdx.z;
    int kt = blockIdx.x, nt = blockIdx.y;
    const float* W = wp.p[z];
    __shared__ float lds[32][33];
    int tid = threadIdx.x;
    int r = tid >> 3, c4 = (tid & 7) * 4;
    float4 vv = *reinterpret_cast<const float4*>(W + (size_t)(kt * 32 + r) * DD + nt * 32 + c4);
    lds[r][c4 + 0] = vv.x; lds[r][c4 + 1] = vv.y;
    lds[r][c4 + 2] = vv.z; lds[r][c4 + 3] = vv.w;
    __syncthreads();
    __bf16* o = Wt + (size_t)z * DD * DD + (size_t)(nt * 32 + r) * DD + kt * 32 + c4;
    o[0] = (__bf16)lds[c4 + 0][r];
    o[1] = (__bf16)lds[c4 + 1][r];
    o[2] = (__bf16)lds[c4 + 2][r];
    o[3] = (__bf16)lds[c4 + 3][r];
}

// ---------------------------------------------------------------------------
// Kernel 3: bf16 MFMA GEMM, no-LDS (A and Wt are L2-resident).
// mode: 0 = f32 (+resid), 1 = sigmoid->bf16, 2 = bf16
// ---------------------------------------------------------------------------
struct GemmCfg { const float* bias[6]; void* out[6]; int mode[6]; };

__global__ __launch_bounds__(256) void mfma_gemm(const __bf16* __restrict__ A,
                                                 const __bf16* __restrict__ Wt0,
                                                 GemmCfg cfg,
                                                 const float* __restrict__ resid) {
    int z = blockIdx.z;
    const __bf16* W = Wt0 + (size_t)z * DD * DD;
    int tid = threadIdx.x;
    int l = tid & 63, wid = tid >> 6;
    int lr = l & 15, lg = l >> 4;
    int wm = wid >> 1, wn = wid & 1;
    int bm = blockIdx.x * 128 + wm * 64;
    int bn = blockIdx.y * 64 + wn * 32;

    f32x4 acc[4][2];
#pragma unroll
    for (int i = 0; i < 4; ++i)
#pragma unroll
        for (int j = 0; j < 2; ++j) acc[i][j] = (f32x4){0.f, 0.f, 0.f, 0.f};

    const __bf16* Ab = A + (size_t)(bm + lr) * DD + lg * 8;
    const __bf16* Bb = W + (size_t)(bn + lr) * DD + lg * 8;

#pragma unroll 4
    for (int k0 = 0; k0 < DD; k0 += 32) {
        bf16x8 af[4], wf[2];
#pragma unroll
        for (int mi = 0; mi < 4; ++mi)
            af[mi] = *reinterpret_cast<const bf16x8*>(Ab + (size_t)mi * 16 * DD + k0);
#pragma unroll
        for (int ni = 0; ni < 2; ++ni)
            wf[ni] = *reinterpret_cast<const bf16x8*>(Bb + (size_t)ni * 16 * DD + k0);
#pragma unroll
        for (int mi = 0; mi < 4; ++mi)
#pragma unroll
            for (int ni = 0; ni < 2; ++ni)
                acc[mi][ni] = __builtin_amdgcn_mfma_f32_16x16x32_bf16(af[mi], wf[ni], acc[mi][ni], 0, 0, 0);
    }

    int mode = cfg.mode[z];
    const float* bias = cfg.bias[z];
    float bv[2] = {bias[bn + lr], bias[bn + 16 + lr]};
#pragma unroll
    for (int mi = 0; mi < 4; ++mi) {
#pragma unroll
        for (int ni = 0; ni < 2; ++ni) {
#pragma unroll
            for (int r = 0; r < 4; ++r) {
                int row = bm + mi * 16 + lg * 4 + r;
                int col = bn + ni * 16 + lr;
                float val = acc[mi][ni][r] + bv[ni];
                if (mode == 0) {
                    if (resid) val += resid[(size_t)row * DD + col];
                    ((float*)cfg.out[z])[(size_t)row * DD + col] = val;
                } else if (mode == 1) {
                    val = 1.0f / (1.0f + expf(-val));
                    ((__bf16*)cfg.out[z])[(size_t)row * DD + col] = (__bf16)val;
                } else {
                    ((__bf16*)cfg.out[z])[(size_t)row * DD + col] = (__bf16)val;
                }
            }
        }
    }
}

// ---------------------------------------------------------------------------
// Kernel 4a/4b: anchor softmax over sequence axis (per b, channel)
// ---------------------------------------------------------------------------
__global__ __launch_bounds__(256) void anchor_partial(const __bf16* __restrict__ fa,
                                                      float* __restrict__ pmax,
                                                      float* __restrict__ psum) {
    int tx = threadIdx.x;
    int ty = threadIdx.y;
    int c = blockIdx.x * 64 + tx;
    int b = blockIdx.y;
    int sc = blockIdx.z;
    const __bf16* base = fa + ((size_t)(b * SS + sc * 256)) * DD + c;
    float m = -1e30f;
    for (int i = ty; i < 256; i += 4) m = fmaxf(m, (float)base[(size_t)i * DD]);
    __shared__ float red[4][64];
    red[ty][tx] = m;
    __syncthreads();
    float cm = fmaxf(fmaxf(red[0][tx], red[1][tx]), fmaxf(red[2][tx], red[3][tx]));
    float s = 0.f;
    for (int i = ty; i < 256; i += 4) s += expf((float)base[(size_t)i * DD] - cm);
    __syncthreads();
    red[ty][tx] = s;
    __syncthreads();
    if (ty == 0) {
        float tot = red[0][tx] + red[1][tx] + red[2][tx] + red[3][tx];
        int o = (b * 4 + sc) * DD + c;
        pmax[o] = cm;
        psum[o] = tot;
    }
}

__global__ __launch_bounds__(256) void anchor_merge(const float* __restrict__ pmax,
                                                    const float* __restrict__ psum,
                                                    float2* __restrict__ smscale) {
    int idx = blockIdx.x * 256 + threadIdx.x;
    int b = idx >> 9;
    int c = idx & 511;
    float M = -1e30f;
#pragma unroll
    for (int j = 0; j < 4; ++j) M = fmaxf(M, pmax[(b * 4 + j) * DD + c]);
    float Z = 0.f;
#pragma unroll
    for (int j = 0; j < 4; ++j) Z += psum[(b * 4 + j) * DD + c] * expf(pmax[(b * 4 + j) * DD + c] - M);
    smscale[idx] = make_float2(M, 1.0f / Z);
}

// Kernel 4c: kw = k * exp(fa - M) * invZ  (vectorized bf16x8)
__global__ __launch_bounds__(256) void kweight(const __bf16* __restrict__ fa,
                                               const __bf16* __restrict__ kin,
                                               const float2* __restrict__ sm,
                                               __bf16* __restrict__ kw) {
    size_t f = ((size_t)blockIdx.x * 256 + threadIdx.x) * 8;
    int b = (int)(f >> 19);
    int c = (int)(f & 511);
    bf16x8 fv = *reinterpret_cast<const bf16x8*>(fa + f);
    bf16x8 kv = *reinterpret_cast<const bf16x8*>(kin + f);
    const float2* smb = sm + b * DD + c;
    bf16x8 o;
#pragma unroll
    for (int j = 0; j < 8; ++j) {
        float2 s = smb[j];
        o[j] = (__bf16)((float)kv[j] * expf((float)fv[j] - s.x) * s.y);
    }
    *reinterpret_cast<bf16x8*>(kw + f) = o;
}

// ---------------------------------------------------------------------------
// Kernel 5: V transpose  v[b][t][h*32+d] -> vt[((b*16+h)*32+d)][t]
// ---------------------------------------------------------------------------
__global__ __launch_bounds__(256) void vtrans(const __bf16* __restrict__ v,
                                              __bf16* __restrict__ vt) {
    int t0 = blockIdx.x * 32;
    int h = blockIdx.y;
    int b = blockIdx.z;
    __shared__ unsigned short lds[32][33];
    int tid = threadIdx.x;
    int r = tid >> 3, c4 = (tid & 7) * 4;
    const unsigned short* vp = (const unsigned short*)v + ((size_t)(b * SS + t0 + r)) * DD + h * 32 + c4;
    us4 val = *reinterpret_cast<const us4*>(vp);
    lds[r][c4 + 0] = val[0]; lds[r][c4 + 1] = val[1];
    lds[r][c4 + 2] = val[2]; lds[r][c4 + 3] = val[3];
    __syncthreads();
    us4 o;
    o[0] = lds[c4 + 0][r]; o[1] = lds[c4 + 1][r];
    o[2] = lds[c4 + 2][r]; o[3] = lds[c4 + 3][r];
    unsigned short* op = (unsigned short*)vt + ((size_t)((b * 16 + h) * 32 + r)) * SS + t0 + c4;
    *reinterpret_cast<us4*>(op) = o;
}

// ---------------------------------------------------------------------------
// Kernel 6: MFMA attention, 4-wave blocks sharing LDS-staged kw/vt chunks.
// grid (16 s-groups, 4 b, 8 tp), block 256. Each wave owns 16 s-rows.
// LDS 64KB: kw chunk [32t][1024B] XOR-swizzled + vt chunk [4][512hd][8t].
// ROUND-7 FIX: __launch_bounds__(256) with NO min-waves arg. Rounds 4 & 6
// both proved a min-waves hint clamps VGPR (128) under this kernel's ~204
// live set -> massive scratch spills (FETCH/WRITE ~270 MB). Occupancy comes
// from structure: 64KB LDS -> 2 blocks/CU; ~204-240 VGPR -> 8 waves/CU.
// ---------------------------------------------------------------------------
struct P8 { __bf16* p[8]; };

__global__ __launch_bounds__(256) void attn_mfma(const __bf16* __restrict__ q,
                                                 const __bf16* __restrict__ kw,
                                                 const __bf16* __restrict__ vt,
                                                 P8 ps) {
    __shared__ __align__(16) char smem[65536];
    int sg = blockIdx.x;
    int b = blockIdx.y;
    int tp = blockIdx.z;
    int tid = threadIdx.x;
    int wid = tid >> 6;
    int lane = tid & 63;
    int lg = lane >> 4;
    int lr = lane & 15;
    int s0 = (sg * 4 + wid) * 16;

    const __bf16* qbase = q + ((size_t)(b * SS + s0 + lr)) * DD + lg * 8;
    const char* kwb8 = (const char*)kw + (size_t)b * SS * DD * 2;
    const char* vtb8 = (const char*)vt + (size_t)b * 512 * SS * 2;

    f32x4 acc[16][2];
#pragma unroll
    for (int h = 0; h < 16; ++h) {
        acc[h][0] = (f32x4){0.f, 0.f, 0.f, 0.f};
        acc[h][1] = (f32x4){0.f, 0.f, 0.f, 0.f};
    }

    int trowA = 8 * (lr >> 2) + (lr & 3);
    int trowB = trowA + 4;
    int xsl = lr << 4; // read-side XOR for permuted t-rows (bits{0,1,3,4} == lr)

    for (int tc = 0; tc < 128; tc += 32) {
        int tbase = tp * 128 + tc;
        // ---- stage kw: 32 rows x 1024B, source pre-swizzled so linear LDS
        //      write lands swizzled: LDS[row][colb] = kw[row][colb ^ x(row)]
#pragma unroll
        for (int it = 0; it < 8; ++it) {
            int row = it * 4 + wid;                              // wave-uniform
            int colb = (lane * 16) ^ (((row & 3) << 4) | (((row >> 3) & 3) << 6));
            gload16(kwb8 + (size_t)(tbase + row) * 1024 + colb,
                    smem + it * 4096 + wid * 1024);
        }
        // ---- stage vt: [lgq][hd-row][8t] subtiled, linear (conflict-free)
#pragma unroll
        for (int it = 0; it < 8; ++it) {
            int blkid = it * 4 + wid;
            int lgq = blkid >> 3;                                // wave-uniform
            int row = (blkid & 7) * 64 + lane;                   // per-lane
            gload16(vtb8 + (size_t)row * 2048 + (size_t)(tbase + lgq * 8) * 2,
                    smem + 32768 + it * 4096 + wid * 1024);
        }
        asm volatile("s_waitcnt vmcnt(0)" ::: "memory");
        __syncthreads();

        f32x4 sc[16];
        // ---- QK sub-chunk A (t = 8*lg + r)
#pragma unroll
        for (int hb = 0; hb < 16; hb += 4) {
            bf16x8 ka[4], qv[4];
#pragma unroll
            for (int j = 0; j < 4; ++j) {
                int h = hb + j;
                ka[j] = *reinterpret_cast<const bf16x8*>(
                    smem + trowA * 1024 + ((h * 64 + lg * 16) ^ xsl));
                qv[j] = *reinterpret_cast<const bf16x8*>(qbase + h * 32);
            }
            __builtin_amdgcn_s_setprio(1);
#pragma unroll
            for (int j = 0; j < 4; ++j) {
                f32x4 z = (f32x4){0.f, 0.f, 0.f, 0.f};
                sc[hb + j] = __builtin_amdgcn_mfma_f32_16x16x32_bf16(ka[j], qv[j], z, 0, 0, 0);
            }
            __builtin_amdgcn_s_setprio(0);
        }
        bf16x4 pA[16];
#pragma unroll
        for (int r = 0; r < 4; ++r) {
            float e[16]; float zs = 0.f;
#pragma unroll
            for (int h = 0; h < 16; ++h) { e[h] = exp2f(sc[h][r] * SCLOG2E); zs += e[h]; }
            float inv = __builtin_amdgcn_rcpf(zs);
#pragma unroll
            for (int h = 0; h < 16; ++h) pA[h][r] = (__bf16)(e[h] * inv);
        }
        // ---- QK sub-chunk B (t = 8*lg + 4 + r)
#pragma unroll
        for (int hb = 0; hb < 16; hb += 4) {
            bf16x8 ka[4], qv[4];
#pragma unroll
            for (int j = 0; j < 4; ++j) {
                int h = hb + j;
                ka[j] = *reinterpret_cast<const bf16x8*>(
                    smem + trowB * 1024 + ((h * 64 + lg * 16) ^ xsl));
                qv[j] = *reinterpret_cast<const bf16x8*>(qbase + h * 32);
            }
            __builtin_amdgcn_s_setprio(1);
#pragma unroll
            for (int j = 0; j < 4; ++j) {
                f32x4 z = (f32x4){0.f, 0.f, 0.f, 0.f};
                sc[hb + j] = __builtin_amdgcn_mfma_f32_16x16x32_bf16(ka[j], qv[j], z, 0, 0, 0);
            }
            __builtin_amdgcn_s_setprio(0);
        }
        bf16x4 pB[16];
#pragma unroll
        for (int r = 0; r < 4; ++r) {
            float e[16]; float zs = 0.f;
#pragma unroll
            for (int h = 0; h < 16; ++h) { e[h] = exp2f(sc[h][r] * SCLOG2E); zs += e[h]; }
            float inv = __builtin_amdgcn_rcpf(zs);
#pragma unroll
            for (int h = 0; h < 16; ++h) pB[h][r] = (__bf16)(e[h] * inv);
        }
        // ---- PV from vt LDS: lane reads [lg][h*32+dh*16+lr][8t]
#pragma unroll
        for (int hb = 0; hb < 16; hb += 4) {
            bf16x8 vf[8];
#pragma unroll
            for (int j = 0; j < 4; ++j) {
                int h = hb + j;
                vf[2 * j + 0] = *reinterpret_cast<const bf16x8*>(
                    smem + 32768 + lg * 8192 + h * 512 + lr * 16);
                vf[2 * j + 1] = *reinterpret_cast<const bf16x8*>(
                    smem + 32768 + lg * 8192 + h * 512 + 256 + lr * 16);
            }
            __builtin_amdgcn_s_setprio(1);
#pragma unroll
            for (int j = 0; j < 4; ++j) {
                int h = hb + j;
                bf16x8 p = __builtin_shufflevector(pA[h], pB[h], 0, 1, 2, 3, 4, 5, 6, 7);
                acc[h][0] = __builtin_amdgcn_mfma_f32_16x16x32_bf16(p, vf[2 * j + 0], acc[h][0], 0, 0, 0);
                acc[h][1] = __builtin_amdgcn_mfma_f32_16x16x32_bf16(p, vf[2 * j + 1], acc[h][1], 0, 0, 0);
            }
            __builtin_amdgcn_s_setprio(0);
        }
        __syncthreads(); // protect LDS before next chunk's stage
    }

    __bf16* pb = ps.p[tp] + ((size_t)(b * SS + s0)) * DD;
#pragma unroll
    for (int h = 0; h < 16; ++h)
#pragma unroll
        for (int dh = 0; dh < 2; ++dh)
#pragma unroll
            for (int r = 0; r < 4; ++r)
                pb[(size_t)(lg * 4 + r) * DD + h * 32 + dh * 16 + lr] = (__bf16)acc[h][dh][r];
}

// ---------------------------------------------------------------------------
// Kernel 7: combine  comb = (sum of 8 partials)*mg + hf  -> bf16
// ---------------------------------------------------------------------------
struct P8c { const __bf16* p[8]; };

__global__ __launch_bounds__(256) void combine_kernel(P8c ps,
                                                      const __bf16* __restrict__ mg,
                                                      const __bf16* __restrict__ hf,
                                                      __bf16* __restrict__ comb) {
    size_t f = ((size_t)blockIdx.x * 256 + threadIdx.x) * 8;
    float accv[8] = {0.f, 0.f, 0.f, 0.f, 0.f, 0.f, 0.f, 0.f};
#pragma unroll
    for (int i = 0; i < 8; ++i) {
        bf16x8 v = *reinterpret_cast<const bf16x8*>(ps.p[i] + f);
#pragma unroll
        for (int j = 0; j < 8; ++j) accv[j] += (float)v[j];
    }
    bf16x8 m = *reinterpret_cast<const bf16x8*>(mg + f);
    bf16x8 hh = *reinterpret_cast<const bf16x8*>(hf + f);
    bf16x8 o;
#pragma unroll
    for (int j = 0; j < 8; ++j) o[j] = (__bf16)(accv[j] * (float)m[j] + (float)hh[j]);
    *reinterpret_cast<bf16x8*>(comb + f) = o;
}

// ---------------------------------------------------------------------------
extern "C" void kernel_launch(void* const* d_in, const int* in_sizes, int n_in,
                              void* d_out, int out_size, void* d_ws, size_t ws_size,
                              hipStream_t stream) {
    const float* x    = (const float*)d_in[0];
    const float* ln_g = (const float*)d_in[1];
    const float* ln_b = (const float*)d_in[2];
    const float* Wfa  = (const float*)d_in[3];  const float* bfa = (const float*)d_in[4];
    const float* Whp  = (const float*)d_in[5];  const float* bhp = (const float*)d_in[6];
    const float* Wmg  = (const float*)d_in[7];  const float* bmg = (const float*)d_in[8];
    const float* Wq   = (const float*)d_in[9];  const float* bq  = (const float*)d_in[10];
    const float* Wk   = (const float*)d_in[11]; const float* bk  = (const float*)d_in[12];
    const float* Wv   = (const float*)d_in[13]; const float* bv  = (const float*)d_in[14];
    const float* Wo   = (const float*)d_in[15]; const float* bo  = (const float*)d_in[16];
    float* out = (float*)d_out;

    char* w8 = (char*)d_ws;
    // Memory map (MB offsets). Every [B,S,D] bf16 tensor is 4 MB.
    __bf16* Wt   = (__bf16*)(w8 + ((size_t) 0 << 20)); // 3.5 MB used
    __bf16* xn   = (__bf16*)(w8 + ((size_t) 4 << 20)); // [4,8)   dead after 6-gemm
    __bf16* fa   = (__bf16*)(w8 + ((size_t) 8 << 20)); // [8,12)  dead after kweight
    __bf16* hf   = (__bf16*)(w8 + ((size_t)12 << 20)); // [12,16)
    __bf16* mg   = (__bf16*)(w8 + ((size_t)16 << 20)); // [16,20)
    __bf16* q    = (__bf16*)(w8 + ((size_t)20 << 20)); // [20,24)
    __bf16* k    = (__bf16*)(w8 + ((size_t)24 << 20)); // [24,28) dead after kweight
    __bf16* v    = (__bf16*)(w8 + ((size_t)28 << 20)); // [28,32) dead after vtrans
    __bf16* kw   = (__bf16*)(w8 + ((size_t)32 << 20)); // [32,36)
    __bf16* vt   = (__bf16*)(w8 + ((size_t)36 << 20)); // [36,40)
    // 8 bf16 partials (4 MB each): reuse dead xn/fa/k/v + fresh [40,56)
    P8 ps;
    ps.p[0] = (__bf16*)(w8 + ((size_t) 4 << 20));
    ps.p[1] = (__bf16*)(w8 + ((size_t) 8 << 20));
    ps.p[2] = (__bf16*)(w8 + ((size_t)24 << 20));
    ps.p[3] = (__bf16*)(w8 + ((size_t)28 << 20));
    ps.p[4] = (__bf16*)(w8 + ((size_t)40 << 20));
    ps.p[5] = (__bf16*)(w8 + ((size_t)44 << 20));
    ps.p[6] = (__bf16*)(w8 + ((size_t)48 << 20));
    ps.p[7] = (__bf16*)(w8 + ((size_t)52 << 20));
    __bf16* comb = (__bf16*)(w8 + ((size_t)56 << 20)); // [56,60)
    float* pmax  = (float*) (w8 + ((size_t)60 << 20)); // stats ~80 KB
    float* psum  = pmax + 16 * DD;
    float2* smsc = (float2*)(psum + 16 * DD);

    // 1. LayerNorm -> xn bf16
    ln_kernel<<<NTOK, 256, 0, stream>>>(x, ln_g, ln_b, xn);

    // 2. Weight transpose+cast
    W7 wp; wp.p[0]=Wfa; wp.p[1]=Whp; wp.p[2]=Wmg; wp.p[3]=Wq; wp.p[4]=Wk; wp.p[5]=Wv; wp.p[6]=Wo;
    wprep<<<dim3(16, 16, 7), 256, 0, stream>>>(wp, Wt);

    // 3. Fused 6-projection MFMA GEMM
    GemmCfg cfg;
    cfg.bias[0]=bfa; cfg.out[0]=fa; cfg.mode[0]=2;
    cfg.bias[1]=bhp; cfg.out[1]=hf; cfg.mode[1]=2;
    cfg.bias[2]=bmg; cfg.out[2]=mg; cfg.mode[2]=1;
    cfg.bias[3]=bq;  cfg.out[3]=q;  cfg.mode[3]=2;
    cfg.bias[4]=bk;  cfg.out[4]=k;  cfg.mode[4]=2;
    cfg.bias[5]=bv;  cfg.out[5]=v;  cfg.mode[5]=2;
    mfma_gemm<<<dim3(32, 8, 6), 256, 0, stream>>>(xn, Wt, cfg, nullptr);

    // 4. anchor softmax over sequence axis
    anchor_partial<<<dim3(8, 4, 4), dim3(64, 4), 0, stream>>>(fa, pmax, psum);
    anchor_merge<<<8, 256, 0, stream>>>(pmax, psum, smsc);
    kweight<<<1024, 256, 0, stream>>>(fa, k, smsc, kw);

    // 5. V transpose
    vtrans<<<dim3(32, 16, 4), 256, 0, stream>>>(v, vt);

    // 6. MFMA attention -> 8 bf16 partials (4-wave LDS-shared blocks)
    attn_mfma<<<dim3(16, 4, 8), 256, 0, stream>>>(q, kw, vt, ps);

    // 7. combine
    P8c pc;
    for (int i = 0; i < 8; ++i) pc.p[i] = ps.p[i];
    combine_kernel<<<1024, 256, 0, stream>>>(pc, mg, hf, comb);

    // 8. output projection + residual
    GemmCfg cfg2;
    for (int i = 0; i < 6; ++i) { cfg2.bias[i]=bo; cfg2.out[i]=out; cfg2.mode[i]=0; }
    mfma_gemm<<<dim3(32, 8, 1), 256, 0, stream>>>(comb, Wt + (size_t)6 * DD * DD, cfg2, x);
}

// Round 9
// 201.130 us; speedup vs baseline: 3.7790x; 1.1591x over previous
//
#include <hip/hip_runtime.h>
#include <hip/hip_bf16.h>
#include <math.h>

#define BB 4
#define SS 1024
#define DD 512
#define HH 16
#define HD 32
#define NTOK (BB * SS)             // 4096
#define NELEM ((size_t)NTOK * DD)  // 2M elements per [B,S,D]
#define SCALE 0.17677669529663687f // 1/sqrt(32)
#define SCLOG2E 0.25505526082484745f // SCALE * log2(e)

typedef __attribute__((ext_vector_type(8))) __bf16 bf16x8;
typedef __attribute__((ext_vector_type(4))) __bf16 bf16x4;
typedef __attribute__((ext_vector_type(4))) float f32x4;
typedef __attribute__((ext_vector_type(4))) unsigned short us4;

__device__ __forceinline__ void gload16(const void* g, void* l) {
    __builtin_amdgcn_global_load_lds(
        (const __attribute__((address_space(1))) void*)g,
        (__attribute__((address_space(3))) void*)l, 16, 0, 0);
}

// ---------------------------------------------------------------------------
// Kernel 1: LayerNorm  x[4096,512] f32 -> xn bf16
// ---------------------------------------------------------------------------
__global__ __launch_bounds__(256) void ln_kernel(const float* __restrict__ x,
                                                 const float* __restrict__ g,
                                                 const float* __restrict__ bta,
                                                 __bf16* __restrict__ xn) {
    int row = blockIdx.x;
    int tid = threadIdx.x;
    const float* xr = x + (size_t)row * DD;
    float2 v = *reinterpret_cast<const float2*>(&xr[tid * 2]);
    float s1 = v.x + v.y;
    float s2 = v.x * v.x + v.y * v.y;
    for (int off = 32; off > 0; off >>= 1) {
        s1 += __shfl_down(s1, off);
        s2 += __shfl_down(s2, off);
    }
    __shared__ float r1[4], r2[4];
    int w = tid >> 6;
    if ((tid & 63) == 0) { r1[w] = s1; r2[w] = s2; }
    __syncthreads();
    s1 = r1[0] + r1[1] + r1[2] + r1[3];
    s2 = r2[0] + r2[1] + r2[2] + r2[3];
    float mu = s1 * (1.0f / DD);
    float var = s2 * (1.0f / DD) - mu * mu;
    float rstd = rsqrtf(var + 1e-5f);
    float2 gg = *reinterpret_cast<const float2*>(&g[tid * 2]);
    float2 bb = *reinterpret_cast<const float2*>(&bta[tid * 2]);
    __bf16* xp = xn + (size_t)row * DD + tid * 2;
    xp[0] = (__bf16)((v.x - mu) * rstd * gg.x + bb.x);
    xp[1] = (__bf16)((v.y - mu) * rstd * gg.y + bb.y);
}

// ---------------------------------------------------------------------------
// Kernel 2: weight prep — Wt[z][n][k] = bf16(W_z[k][n]), z = 0..6
// ---------------------------------------------------------------------------
struct W7 { const float* p[7]; };

__global__ __launch_bounds__(256) void wprep(W7 wp, __bf16* __restrict__ Wt) {
    int z = blockIdx.z;
    int kt = blockIdx.x, nt = blockIdx.y;
    const float* W = wp.p[z];
    __shared__ float lds[32][33];
    int tid = threadIdx.x;
    int r = tid >> 3, c4 = (tid & 7) * 4;
    float4 vv = *reinterpret_cast<const float4*>(W + (size_t)(kt * 32 + r) * DD + nt * 32 + c4);
    lds[r][c4 + 0] = vv.x; lds[r][c4 + 1] = vv.y;
    lds[r][c4 + 2] = vv.z; lds[r][c4 + 3] = vv.w;
    __syncthreads();
    __bf16* o = Wt + (size_t)z * DD * DD + (size_t)(nt * 32 + r) * DD + kt * 32 + c4;
    o[0] = (__bf16)lds[c4 + 0][r];
    o[1] = (__bf16)lds[c4 + 1][r];
    o[2] = (__bf16)lds[c4 + 2][r];
    o[3] = (__bf16)lds[c4 + 3][r];
}

// ---------------------------------------------------------------------------
// Kernel 3: bf16 MFMA GEMM, no-LDS (A and Wt are L2-resident).
// mode: 0 = f32 (+resid), 1 = sigmoid->bf16, 2 = bf16
// ---------------------------------------------------------------------------
struct GemmCfg { const float* bias[6]; void* out[6]; int mode[6]; };

__global__ __launch_bounds__(256) void mfma_gemm(const __bf16* __restrict__ A,
                                                 const __bf16* __restrict__ Wt0,
                                                 GemmCfg cfg,
                                                 const float* __restrict__ resid) {
    int z = blockIdx.z;
    const __bf16* W = Wt0 + (size_t)z * DD * DD;
    int tid = threadIdx.x;
    int l = tid & 63, wid = tid >> 6;
    int lr = l & 15, lg = l >> 4;
    int wm = wid >> 1, wn = wid & 1;
    int bm = blockIdx.x * 128 + wm * 64;
    int bn = blockIdx.y * 64 + wn * 32;

    f32x4 acc[4][2];
#pragma unroll
    for (int i = 0; i < 4; ++i)
#pragma unroll
        for (int j = 0; j < 2; ++j) acc[i][j] = (f32x4){0.f, 0.f, 0.f, 0.f};

    const __bf16* Ab = A + (size_t)(bm + lr) * DD + lg * 8;
    const __bf16* Bb = W + (size_t)(bn + lr) * DD + lg * 8;

#pragma unroll 4
    for (int k0 = 0; k0 < DD; k0 += 32) {
        bf16x8 af[4], wf[2];
#pragma unroll
        for (int mi = 0; mi < 4; ++mi)
            af[mi] = *reinterpret_cast<const bf16x8*>(Ab + (size_t)mi * 16 * DD + k0);
#pragma unroll
        for (int ni = 0; ni < 2; ++ni)
            wf[ni] = *reinterpret_cast<const bf16x8*>(Bb + (size_t)ni * 16 * DD + k0);
#pragma unroll
        for (int mi = 0; mi < 4; ++mi)
#pragma unroll
            for (int ni = 0; ni < 2; ++ni)
                acc[mi][ni] = __builtin_amdgcn_mfma_f32_16x16x32_bf16(af[mi], wf[ni], acc[mi][ni], 0, 0, 0);
    }

    int mode = cfg.mode[z];
    const float* bias = cfg.bias[z];
    float bv[2] = {bias[bn + lr], bias[bn + 16 + lr]};
#pragma unroll
    for (int mi = 0; mi < 4; ++mi) {
#pragma unroll
        for (int ni = 0; ni < 2; ++ni) {
#pragma unroll
            for (int r = 0; r < 4; ++r) {
                int row = bm + mi * 16 + lg * 4 + r;
                int col = bn + ni * 16 + lr;
                float val = acc[mi][ni][r] + bv[ni];
                if (mode == 0) {
                    if (resid) val += resid[(size_t)row * DD + col];
                    ((float*)cfg.out[z])[(size_t)row * DD + col] = val;
                } else if (mode == 1) {
                    val = 1.0f / (1.0f + expf(-val));
                    ((__bf16*)cfg.out[z])[(size_t)row * DD + col] = (__bf16)val;
                } else {
                    ((__bf16*)cfg.out[z])[(size_t)row * DD + col] = (__bf16)val;
                }
            }
        }
    }
}

// ---------------------------------------------------------------------------
// Kernel 4a/4b: anchor softmax over sequence axis (per b, channel)
// ---------------------------------------------------------------------------
__global__ __launch_bounds__(256) void anchor_partial(const __bf16* __restrict__ fa,
                                                      float* __restrict__ pmax,
                                                      float* __restrict__ psum) {
    int tx = threadIdx.x;
    int ty = threadIdx.y;
    int c = blockIdx.x * 64 + tx;
    int b = blockIdx.y;
    int sc = blockIdx.z;
    const __bf16* base = fa + ((size_t)(b * SS + sc * 256)) * DD + c;
    float m = -1e30f;
    for (int i = ty; i < 256; i += 4) m = fmaxf(m, (float)base[(size_t)i * DD]);
    __shared__ float red[4][64];
    red[ty][tx] = m;
    __syncthreads();
    float cm = fmaxf(fmaxf(red[0][tx], red[1][tx]), fmaxf(red[2][tx], red[3][tx]));
    float s = 0.f;
    for (int i = ty; i < 256; i += 4) s += expf((float)base[(size_t)i * DD] - cm);
    __syncthreads();
    red[ty][tx] = s;
    __syncthreads();
    if (ty == 0) {
        float tot = red[0][tx] + red[1][tx] + red[2][tx] + red[3][tx];
        int o = (b * 4 + sc) * DD + c;
        pmax[o] = cm;
        psum[o] = tot;
    }
}

__global__ __launch_bounds__(256) void anchor_merge(const float* __restrict__ pmax,
                                                    const float* __restrict__ psum,
                                                    float2* __restrict__ smscale) {
    int idx = blockIdx.x * 256 + threadIdx.x;
    int b = idx >> 9;
    int c = idx & 511;
    float M = -1e30f;
#pragma unroll
    for (int j = 0; j < 4; ++j) M = fmaxf(M, pmax[(b * 4 + j) * DD + c]);
    float Z = 0.f;
#pragma unroll
    for (int j = 0; j < 4; ++j) Z += psum[(b * 4 + j) * DD + c] * expf(pmax[(b * 4 + j) * DD + c] - M);
    smscale[idx] = make_float2(M, 1.0f / Z);
}

// Kernel 4c: kw = k * exp(fa - M) * invZ  (vectorized bf16x8)
__global__ __launch_bounds__(256) void kweight(const __bf16* __restrict__ fa,
                                               const __bf16* __restrict__ kin,
                                               const float2* __restrict__ sm,
                                               __bf16* __restrict__ kw) {
    size_t f = ((size_t)blockIdx.x * 256 + threadIdx.x) * 8;
    int b = (int)(f >> 19);
    int c = (int)(f & 511);
    bf16x8 fv = *reinterpret_cast<const bf16x8*>(fa + f);
    bf16x8 kv = *reinterpret_cast<const bf16x8*>(kin + f);
    const float2* smb = sm + b * DD + c;
    bf16x8 o;
#pragma unroll
    for (int j = 0; j < 8; ++j) {
        float2 s = smb[j];
        o[j] = (__bf16)((float)kv[j] * expf((float)fv[j] - s.x) * s.y);
    }
    *reinterpret_cast<bf16x8*>(kw + f) = o;
}

// ---------------------------------------------------------------------------
// Kernel 5: V transpose into TILED layout:
//   vt2[b][t/8][drow=h*32+d (512)][t%8]   (8KB per (b,t/8) slice)
// Round-7 lesson: the old [b][drow][t] layout made attn's vt staging a
// 2KB-strided gather (64 lines per gload16). Tiled layout makes each chunk
// slice contiguous -> staging is 64-lane-contiguous 1KB lines.
// ---------------------------------------------------------------------------
__global__ __launch_bounds__(256) void vtrans(const __bf16* __restrict__ v,
                                              __bf16* __restrict__ vt) {
    int t0 = blockIdx.x * 32;
    int h = blockIdx.y;
    int b = blockIdx.z;
    __shared__ unsigned short lds[32][33];
    int tid = threadIdx.x;
    int r = tid >> 3, c4 = (tid & 7) * 4;
    const unsigned short* vp = (const unsigned short*)v + ((size_t)(b * SS + t0 + r)) * DD + h * 32 + c4;
    us4 val = *reinterpret_cast<const us4*>(vp);
    lds[r][c4 + 0] = val[0]; lds[r][c4 + 1] = val[1];
    lds[r][c4 + 2] = val[2]; lds[r][c4 + 3] = val[3];
    __syncthreads();
    us4 o;
    o[0] = lds[c4 + 0][r]; o[1] = lds[c4 + 1][r];
    o[2] = lds[c4 + 2][r]; o[3] = lds[c4 + 3][r];  // o[j] = v[t0+c4+j][h*32+r]
    // tiled index: ((b*128 + (t0+c4)/8)*512 + h*32 + r)*8 + (c4&7)
    unsigned short* op = (unsigned short*)vt +
        ((size_t)(b * 128 + ((t0 + c4) >> 3)) * 512 + h * 32 + r) * 8 + (c4 & 7);
    *reinterpret_cast<us4*>(op) = o;
}

// ---------------------------------------------------------------------------
// Kernel 6: MFMA attention, 4-wave blocks sharing LDS-staged kw/vt chunks.
// grid (16 s-groups, 4 b, 8 tp), block 256. Each wave owns 16 s-rows.
// LDS 64KB: kw chunk [32t][1024B] XOR-swizzled + vt chunk [4][512dr][8t].
// NO min-waves hint (rounds 4/6: hint clamps VGPR -> spills). qf resident.
// ---------------------------------------------------------------------------
struct P8 { __bf16* p[8]; };

__global__ __launch_bounds__(256) void attn_mfma(const __bf16* __restrict__ q,
                                                 const __bf16* __restrict__ kw,
                                                 const __bf16* __restrict__ vt,
                                                 P8 ps) {
    __shared__ __align__(16) char smem[65536];
    int sg = blockIdx.x;
    int b = blockIdx.y;
    int tp = blockIdx.z;
    int tid = threadIdx.x;
    int wid = tid >> 6;
    int lane = tid & 63;
    int lg = lane >> 4;
    int lr = lane & 15;
    int s0 = (sg * 4 + wid) * 16;

    const __bf16* qbase = q + ((size_t)(b * SS + s0 + lr)) * DD + lg * 8;
    const char* kwb8 = (const char*)kw + (size_t)b * SS * DD * 2;
    const char* vtb8 = (const char*)vt + (size_t)b * 128 * 8192;

    // Q fragments resident (64 VGPR, loaded once)
    bf16x8 qf[16];
#pragma unroll
    for (int h = 0; h < 16; ++h) qf[h] = *reinterpret_cast<const bf16x8*>(qbase + h * 32);

    f32x4 acc[16][2];
#pragma unroll
    for (int h = 0; h < 16; ++h) {
        acc[h][0] = (f32x4){0.f, 0.f, 0.f, 0.f};
        acc[h][1] = (f32x4){0.f, 0.f, 0.f, 0.f};
    }

    int trowA = 8 * (lr >> 2) + (lr & 3);
    int trowB = trowA + 4;
    int xsl = lr << 4; // read-side XOR for permuted t-rows (bits{0,1,3,4} == lr)

    for (int tc = 0; tc < 128; tc += 32) {
        int tbase = tp * 128 + tc;
        // ---- stage kw: 32 rows x 1024B, source pre-swizzled (linear LDS dst)
#pragma unroll
        for (int it = 0; it < 8; ++it) {
            int row = it * 4 + wid;                              // wave-uniform
            int colb = (lane * 16) ^ (((row & 3) << 4) | (((row >> 3) & 3) << 6));
            gload16(kwb8 + (size_t)(tbase + row) * 1024 + colb,
                    smem + it * 4096 + wid * 1024);
        }
        // ---- stage vt (tiled layout): contiguous 1KB per gload16
#pragma unroll
        for (int it = 0; it < 8; ++it) {
            int blkid = it * 4 + wid;
            int lgq = blkid >> 3;                                // wave-uniform
            gload16(vtb8 + (size_t)((tbase >> 3) + lgq) * 8192 + (blkid & 7) * 1024 + lane * 16,
                    smem + 32768 + it * 4096 + wid * 1024);
        }
        asm volatile("s_waitcnt vmcnt(0)" ::: "memory");
        __syncthreads();

        f32x4 sc[16];
        // ---- QK sub-chunk A (t = 8*lg + r)
#pragma unroll
        for (int hb = 0; hb < 16; hb += 4) {
            bf16x8 ka[4];
#pragma unroll
            for (int j = 0; j < 4; ++j) {
                int h = hb + j;
                ka[j] = *reinterpret_cast<const bf16x8*>(
                    smem + trowA * 1024 + ((h * 64 + lg * 16) ^ xsl));
            }
            __builtin_amdgcn_s_setprio(1);
#pragma unroll
            for (int j = 0; j < 4; ++j) {
                f32x4 z = (f32x4){0.f, 0.f, 0.f, 0.f};
                sc[hb + j] = __builtin_amdgcn_mfma_f32_16x16x32_bf16(ka[j], qf[hb + j], z, 0, 0, 0);
            }
            __builtin_amdgcn_s_setprio(0);
        }
        bf16x4 pA[16];
#pragma unroll
        for (int r = 0; r < 4; ++r) {
            float e[16]; float zs = 0.f;
#pragma unroll
            for (int h = 0; h < 16; ++h) { e[h] = exp2f(sc[h][r] * SCLOG2E); zs += e[h]; }
            float inv = __builtin_amdgcn_rcpf(zs);
#pragma unroll
            for (int h = 0; h < 16; ++h) pA[h][r] = (__bf16)(e[h] * inv);
        }
        // ---- QK sub-chunk B (t = 8*lg + 4 + r)
#pragma unroll
        for (int hb = 0; hb < 16; hb += 4) {
            bf16x8 ka[4];
#pragma unroll
            for (int j = 0; j < 4; ++j) {
                int h = hb + j;
                ka[j] = *reinterpret_cast<const bf16x8*>(
                    smem + trowB * 1024 + ((h * 64 + lg * 16) ^ xsl));
            }
            __builtin_amdgcn_s_setprio(1);
#pragma unroll
            for (int j = 0; j < 4; ++j) {
                f32x4 z = (f32x4){0.f, 0.f, 0.f, 0.f};
                sc[hb + j] = __builtin_amdgcn_mfma_f32_16x16x32_bf16(ka[j], qf[hb + j], z, 0, 0, 0);
            }
            __builtin_amdgcn_s_setprio(0);
        }
        bf16x4 pB[16];
#pragma unroll
        for (int r = 0; r < 4; ++r) {
            float e[16]; float zs = 0.f;
#pragma unroll
            for (int h = 0; h < 16; ++h) { e[h] = exp2f(sc[h][r] * SCLOG2E); zs += e[h]; }
            float inv = __builtin_amdgcn_rcpf(zs);
#pragma unroll
            for (int h = 0; h < 16; ++h) pB[h][r] = (__bf16)(e[h] * inv);
        }
        // ---- PV from vt LDS: lane reads [lg][h*32+dh*16+lr][8t]
#pragma unroll
        for (int hb = 0; hb < 16; hb += 4) {
            bf16x8 vf[8];
#pragma unroll
            for (int j = 0; j < 4; ++j) {
                int h = hb + j;
                vf[2 * j + 0] = *reinterpret_cast<const bf16x8*>(
                    smem + 32768 + lg * 8192 + h * 512 + lr * 16);
                vf[2 * j + 1] = *reinterpret_cast<const bf16x8*>(
                    smem + 32768 + lg * 8192 + h * 512 + 256 + lr * 16);
            }
            __builtin_amdgcn_s_setprio(1);
#pragma unroll
            for (int j = 0; j < 4; ++j) {
                int h = hb + j;
                bf16x8 p = __builtin_shufflevector(pA[h], pB[h], 0, 1, 2, 3, 4, 5, 6, 7);
                acc[h][0] = __builtin_amdgcn_mfma_f32_16x16x32_bf16(p, vf[2 * j + 0], acc[h][0], 0, 0, 0);
                acc[h][1] = __builtin_amdgcn_mfma_f32_16x16x32_bf16(p, vf[2 * j + 1], acc[h][1], 0, 0, 0);
            }
            __builtin_amdgcn_s_setprio(0);
        }
        __syncthreads(); // protect LDS before next chunk's stage
    }

    __bf16* pb = ps.p[tp] + ((size_t)(b * SS + s0)) * DD;
#pragma unroll
    for (int h = 0; h < 16; ++h)
#pragma unroll
        for (int dh = 0; dh < 2; ++dh)
#pragma unroll
            for (int r = 0; r < 4; ++r)
                pb[(size_t)(lg * 4 + r) * DD + h * 32 + dh * 16 + lr] = (__bf16)acc[h][dh][r];
}

// ---------------------------------------------------------------------------
// Kernel 7: combine  comb = (sum of 8 partials)*mg + hf  -> bf16
// ---------------------------------------------------------------------------
struct P8c { const __bf16* p[8]; };

__global__ __launch_bounds__(256) void combine_kernel(P8c ps,
                                                      const __bf16* __restrict__ mg,
                                                      const __bf16* __restrict__ hf,
                                                      __bf16* __restrict__ comb) {
    size_t f = ((size_t)blockIdx.x * 256 + threadIdx.x) * 8;
    float accv[8] = {0.f, 0.f, 0.f, 0.f, 0.f, 0.f, 0.f, 0.f};
#pragma unroll
    for (int i = 0; i < 8; ++i) {
        bf16x8 v = *reinterpret_cast<const bf16x8*>(ps.p[i] + f);
#pragma unroll
        for (int j = 0; j < 8; ++j) accv[j] += (float)v[j];
    }
    bf16x8 m = *reinterpret_cast<const bf16x8*>(mg + f);
    bf16x8 hh = *reinterpret_cast<const bf16x8*>(hf + f);
    bf16x8 o;
#pragma unroll
    for (int j = 0; j < 8; ++j) o[j] = (__bf16)(accv[j] * (float)m[j] + (float)hh[j]);
    *reinterpret_cast<bf16x8*>(comb + f) = o;
}

// ---------------------------------------------------------------------------
extern "C" void kernel_launch(void* const* d_in, const int* in_sizes, int n_in,
                              void* d_out, int out_size, void* d_ws, size_t ws_size,
                              hipStream_t stream) {
    const float* x    = (const float*)d_in[0];
    const float* ln_g = (const float*)d_in[1];
    const float* ln_b = (const float*)d_in[2];
    const float* Wfa  = (const float*)d_in[3];  const float* bfa = (const float*)d_in[4];
    const float* Whp  = (const float*)d_in[5];  const float* bhp = (const float*)d_in[6];
    const float* Wmg  = (const float*)d_in[7];  const float* bmg = (const float*)d_in[8];
    const float* Wq   = (const float*)d_in[9];  const float* bq  = (const float*)d_in[10];
    const float* Wk   = (const float*)d_in[11]; const float* bk  = (const float*)d_in[12];
    const float* Wv   = (const float*)d_in[13]; const float* bv  = (const float*)d_in[14];
    const float* Wo   = (const float*)d_in[15]; const float* bo  = (const float*)d_in[16];
    float* out = (float*)d_out;

    char* w8 = (char*)d_ws;
    // Memory map (MB offsets). Every [B,S,D] bf16 tensor is 4 MB.
    __bf16* Wt   = (__bf16*)(w8 + ((size_t) 0 << 20)); // 3.5 MB used
    __bf16* xn   = (__bf16*)(w8 + ((size_t) 4 << 20)); // [4,8)   dead after 6-gemm
    __bf16* fa   = (__bf16*)(w8 + ((size_t) 8 << 20)); // [8,12)  dead after kweight
    __bf16* hf   = (__bf16*)(w8 + ((size_t)12 << 20)); // [12,16)
    __bf16* mg   = (__bf16*)(w8 + ((size_t)16 << 20)); // [16,20)
    __bf16* q    = (__bf16*)(w8 + ((size_t)20 << 20)); // [20,24)
    __bf16* k    = (__bf16*)(w8 + ((size_t)24 << 20)); // [24,28) dead after kweight
    __bf16* v    = (__bf16*)(w8 + ((size_t)28 << 20)); // [28,32) dead after vtrans
    __bf16* kw   = (__bf16*)(w8 + ((size_t)32 << 20)); // [32,36)
    __bf16* vt   = (__bf16*)(w8 + ((size_t)36 << 20)); // [36,40)
    // 8 bf16 partials (4 MB each): reuse dead xn/fa/k/v + fresh [40,56)
    P8 ps;
    ps.p[0] = (__bf16*)(w8 + ((size_t) 4 << 20));
    ps.p[1] = (__bf16*)(w8 + ((size_t) 8 << 20));
    ps.p[2] = (__bf16*)(w8 + ((size_t)24 << 20));
    ps.p[3] = (__bf16*)(w8 + ((size_t)28 << 20));
    ps.p[4] = (__bf16*)(w8 + ((size_t)40 << 20));
    ps.p[5] = (__bf16*)(w8 + ((size_t)44 << 20));
    ps.p[6] = (__bf16*)(w8 + ((size_t)48 << 20));
    ps.p[7] = (__bf16*)(w8 + ((size_t)52 << 20));
    __bf16* comb = (__bf16*)(w8 + ((size_t)56 << 20)); // [56,60)
    float* pmax  = (float*) (w8 + ((size_t)60 << 20)); // stats ~80 KB
    float* psum  = pmax + 16 * DD;
    float2* smsc = (float2*)(psum + 16 * DD);

    // 1. LayerNorm -> xn bf16
    ln_kernel<<<NTOK, 256, 0, stream>>>(x, ln_g, ln_b, xn);

    // 2. Weight transpose+cast
    W7 wp; wp.p[0]=Wfa; wp.p[1]=Whp; wp.p[2]=Wmg; wp.p[3]=Wq; wp.p[4]=Wk; wp.p[5]=Wv; wp.p[6]=Wo;
    wprep<<<dim3(16, 16, 7), 256, 0, stream>>>(wp, Wt);

    // 3. Fused 6-projection MFMA GEMM
    GemmCfg cfg;
    cfg.bias[0]=bfa; cfg.out[0]=fa; cfg.mode[0]=2;
    cfg.bias[1]=bhp; cfg.out[1]=hf; cfg.mode[1]=2;
    cfg.bias[2]=bmg; cfg.out[2]=mg; cfg.mode[2]=1;
    cfg.bias[3]=bq;  cfg.out[3]=q;  cfg.mode[3]=2;
    cfg.bias[4]=bk;  cfg.out[4]=k;  cfg.mode[4]=2;
    cfg.bias[5]=bv;  cfg.out[5]=v;  cfg.mode[5]=2;
    mfma_gemm<<<dim3(32, 8, 6), 256, 0, stream>>>(xn, Wt, cfg, nullptr);

    // 4. anchor softmax over sequence axis
    anchor_partial<<<dim3(8, 4, 4), dim3(64, 4), 0, stream>>>(fa, pmax, psum);
    anchor_merge<<<8, 256, 0, stream>>>(pmax, psum, smsc);
    kweight<<<1024, 256, 0, stream>>>(fa, k, smsc, kw);

    // 5. V transpose (tiled layout)
    vtrans<<<dim3(32, 16, 4), 256, 0, stream>>>(v, vt);

    // 6. MFMA attention -> 8 bf16 partials (4-wave LDS-shared blocks)
    attn_mfma<<<dim3(16, 4, 8), 256, 0, stream>>>(q, kw, vt, ps);

    // 7. combine
    P8c pc;
    for (int i = 0; i < 8; ++i) pc.p[i] = ps.p[i];
    combine_kernel<<<1024, 256, 0, stream>>>(pc, mg, hf, comb);

    // 8. output projection + residual
    GemmCfg cfg2;
    for (int i = 0; i < 6; ++i) { cfg2.bias[i]=bo; cfg2.out[i]=out; cfg2.mode[i]=0; }
    mfma_gemm<<<dim3(32, 8, 1), 256, 0, stream>>>(comb, Wt + (size_t)6 * DD * DD, cfg2, x);
}

// Round 10
// 148.758 us; speedup vs baseline: 5.1094x; 1.3521x over previous
//
#include <hip/hip_runtime.h>
#include <hip/hip_bf16.h>
#include <math.h>

#define BB 4
#define SS 1024
#define DD 512
#define HH 16
#define HD 32
#define NTOK (BB * SS)             // 4096
#define NELEM ((size_t)NTOK * DD)  // 2M elements per [B,S,D]
#define SCALE 0.17677669529663687f // 1/sqrt(32)
#define SCLOG2E 0.25505526082484745f // SCALE * log2(e)

typedef __attribute__((ext_vector_type(8))) __bf16 bf16x8;
typedef __attribute__((ext_vector_type(4))) __bf16 bf16x4;
typedef __attribute__((ext_vector_type(4))) float f32x4;
typedef __attribute__((ext_vector_type(4))) unsigned short us4;

__device__ __forceinline__ void gload16(const void* g, void* l) {
    __builtin_amdgcn_global_load_lds(
        (const __attribute__((address_space(1))) void*)g,
        (__attribute__((address_space(3))) void*)l, 16, 0, 0);
}

// ---------------------------------------------------------------------------
// Kernel 1: LayerNorm  x[4096,512] f32 -> xn bf16
// ---------------------------------------------------------------------------
__global__ __launch_bounds__(256) void ln_kernel(const float* __restrict__ x,
                                                 const float* __restrict__ g,
                                                 const float* __restrict__ bta,
                                                 __bf16* __restrict__ xn) {
    int row = blockIdx.x;
    int tid = threadIdx.x;
    const float* xr = x + (size_t)row * DD;
    float2 v = *reinterpret_cast<const float2*>(&xr[tid * 2]);
    float s1 = v.x + v.y;
    float s2 = v.x * v.x + v.y * v.y;
    for (int off = 32; off > 0; off >>= 1) {
        s1 += __shfl_down(s1, off);
        s2 += __shfl_down(s2, off);
    }
    __shared__ float r1[4], r2[4];
    int w = tid >> 6;
    if ((tid & 63) == 0) { r1[w] = s1; r2[w] = s2; }
    __syncthreads();
    s1 = r1[0] + r1[1] + r1[2] + r1[3];
    s2 = r2[0] + r2[1] + r2[2] + r2[3];
    float mu = s1 * (1.0f / DD);
    float var = s2 * (1.0f / DD) - mu * mu;
    float rstd = rsqrtf(var + 1e-5f);
    float2 gg = *reinterpret_cast<const float2*>(&g[tid * 2]);
    float2 bb = *reinterpret_cast<const float2*>(&bta[tid * 2]);
    __bf16* xp = xn + (size_t)row * DD + tid * 2;
    xp[0] = (__bf16)((v.x - mu) * rstd * gg.x + bb.x);
    xp[1] = (__bf16)((v.y - mu) * rstd * gg.y + bb.y);
}

// ---------------------------------------------------------------------------
// Kernel 2: weight prep — Wt[z][n][k] = bf16(W_z[k][n]), z = 0..6
// ---------------------------------------------------------------------------
struct W7 { const float* p[7]; };

__global__ __launch_bounds__(256) void wprep(W7 wp, __bf16* __restrict__ Wt) {
    int z = blockIdx.z;
    int kt = blockIdx.x, nt = blockIdx.y;
    const float* W = wp.p[z];
    __shared__ float lds[32][33];
    int tid = threadIdx.x;
    int r = tid >> 3, c4 = (tid & 7) * 4;
    float4 vv = *reinterpret_cast<const float4*>(W + (size_t)(kt * 32 + r) * DD + nt * 32 + c4);
    lds[r][c4 + 0] = vv.x; lds[r][c4 + 1] = vv.y;
    lds[r][c4 + 2] = vv.z; lds[r][c4 + 3] = vv.w;
    __syncthreads();
    __bf16* o = Wt + (size_t)z * DD * DD + (size_t)(nt * 32 + r) * DD + kt * 32 + c4;
    o[0] = (__bf16)lds[c4 + 0][r];
    o[1] = (__bf16)lds[c4 + 1][r];
    o[2] = (__bf16)lds[c4 + 2][r];
    o[3] = (__bf16)lds[c4 + 3][r];
}

// ---------------------------------------------------------------------------
// Kernel 3: bf16 MFMA GEMM, LDS-staged (m97-style, round-9 redesign).
// Round-9 lesson: no-LDS fragments-from-L2 made EVERY load a 16-line gather
// -> latency-bound at 123 TF (MfmaUtil 4.6%). Canonical fix: stage tiles in
// LDS with coalesced global_load_lds (pre-swizzled source, T2 XOR swizzle),
// conflict-free ds_read_b128 fragments.
// Tile: BM=128, BN=64, BK=64; 4 waves (2x2), wave tile 64x32 (4x2 frags).
// LDS 24KB: A[128 m][128B k-chunk] + B[64 n][128B], both XOR ((row&7)<<4).
// mode: 0 = f32 (+resid), 1 = sigmoid->bf16, 2 = bf16
// ---------------------------------------------------------------------------
struct GemmCfg { const float* bias[6]; void* out[6]; int mode[6]; };

__global__ __launch_bounds__(256) void mfma_gemm(const __bf16* __restrict__ A,
                                                 const __bf16* __restrict__ Wt0,
                                                 GemmCfg cfg,
                                                 const float* __restrict__ resid) {
    __shared__ __align__(16) char smem[24576]; // A 16KB @0, B 8KB @16384
    int z = blockIdx.z;
    const char* Ab8 = (const char*)A;                              // [4096][1024B]
    const char* Bb8 = (const char*)(Wt0 + (size_t)z * DD * DD);    // [512][1024B]
    int tid = threadIdx.x;
    int l = tid & 63, wid = tid >> 6;
    int lr = l & 15, lg = l >> 4;
    int wm = wid >> 1, wn = wid & 1;
    int bm = blockIdx.x * 128;
    int bn = blockIdx.y * 64;

    f32x4 acc[4][2];
#pragma unroll
    for (int i = 0; i < 4; ++i)
#pragma unroll
        for (int j = 0; j < 2; ++j) acc[i][j] = (f32x4){0.f, 0.f, 0.f, 0.f};

    for (int k0 = 0; k0 < DD; k0 += 64) {
        // ---- stage A-tile: 128 rows x 128B (k0..k0+64). Wave wid covers
        //      rows 32*wid..+32 in 4 insts of 8 rows. Source pre-swizzled.
#pragma unroll
        for (int i = 0; i < 4; ++i) {
            int r = wid * 32 + i * 8 + (l >> 3);
            int cb = ((l & 7) * 16) ^ ((r & 7) << 4);
            gload16(Ab8 + (size_t)(bm + r) * 1024 + k0 * 2 + cb,
                    smem + wid * 4096 + i * 1024);
        }
        // ---- stage B-tile: 64 rows x 128B. Wave covers 16 rows in 2 insts.
#pragma unroll
        for (int i = 0; i < 2; ++i) {
            int r = wid * 16 + i * 8 + (l >> 3);
            int cb = ((l & 7) * 16) ^ ((r & 7) << 4);
            gload16(Bb8 + (size_t)(bn + r) * 1024 + k0 * 2 + cb,
                    smem + 16384 + wid * 2048 + i * 1024);
        }
        asm volatile("s_waitcnt vmcnt(0)" ::: "memory");
        __syncthreads();

#pragma unroll
        for (int kk = 0; kk < 2; ++kk) {
            bf16x8 af[4], wf[2];
#pragma unroll
            for (int mi = 0; mi < 4; ++mi) {
                int m = wm * 64 + mi * 16 + lr;
                af[mi] = *reinterpret_cast<const bf16x8*>(
                    smem + m * 128 + ((kk * 64 + lg * 16) ^ ((m & 7) << 4)));
            }
#pragma unroll
            for (int ni = 0; ni < 2; ++ni) {
                int n = wn * 32 + ni * 16 + lr;
                wf[ni] = *reinterpret_cast<const bf16x8*>(
                    smem + 16384 + n * 128 + ((kk * 64 + lg * 16) ^ ((n & 7) << 4)));
            }
            __builtin_amdgcn_s_setprio(1);
#pragma unroll
            for (int mi = 0; mi < 4; ++mi)
#pragma unroll
                for (int ni = 0; ni < 2; ++ni)
                    acc[mi][ni] = __builtin_amdgcn_mfma_f32_16x16x32_bf16(af[mi], wf[ni], acc[mi][ni], 0, 0, 0);
            __builtin_amdgcn_s_setprio(0);
        }
        __syncthreads();
    }

    int bmw = bm + wm * 64;
    int bnw = bn + wn * 32;
    int mode = cfg.mode[z];
    const float* bias = cfg.bias[z];
    float bv[2] = {bias[bnw + lr], bias[bnw + 16 + lr]};
#pragma unroll
    for (int mi = 0; mi < 4; ++mi) {
#pragma unroll
        for (int ni = 0; ni < 2; ++ni) {
#pragma unroll
            for (int r = 0; r < 4; ++r) {
                int row = bmw + mi * 16 + lg * 4 + r;
                int col = bnw + ni * 16 + lr;
                float val = acc[mi][ni][r] + bv[ni];
                if (mode == 0) {
                    if (resid) val += resid[(size_t)row * DD + col];
                    ((float*)cfg.out[z])[(size_t)row * DD + col] = val;
                } else if (mode == 1) {
                    val = 1.0f / (1.0f + expf(-val));
                    ((__bf16*)cfg.out[z])[(size_t)row * DD + col] = (__bf16)val;
                } else {
                    ((__bf16*)cfg.out[z])[(size_t)row * DD + col] = (__bf16)val;
                }
            }
        }
    }
}

// ---------------------------------------------------------------------------
// Kernel 4a/4b: anchor softmax over sequence axis (per b, channel)
// ---------------------------------------------------------------------------
__global__ __launch_bounds__(256) void anchor_partial(const __bf16* __restrict__ fa,
                                                      float* __restrict__ pmax,
                                                      float* __restrict__ psum) {
    int tx = threadIdx.x;
    int ty = threadIdx.y;
    int c = blockIdx.x * 64 + tx;
    int b = blockIdx.y;
    int sc = blockIdx.z;
    const __bf16* base = fa + ((size_t)(b * SS + sc * 256)) * DD + c;
    float m = -1e30f;
    for (int i = ty; i < 256; i += 4) m = fmaxf(m, (float)base[(size_t)i * DD]);
    __shared__ float red[4][64];
    red[ty][tx] = m;
    __syncthreads();
    float cm = fmaxf(fmaxf(red[0][tx], red[1][tx]), fmaxf(red[2][tx], red[3][tx]));
    float s = 0.f;
    for (int i = ty; i < 256; i += 4) s += expf((float)base[(size_t)i * DD] - cm);
    __syncthreads();
    red[ty][tx] = s;
    __syncthreads();
    if (ty == 0) {
        float tot = red[0][tx] + red[1][tx] + red[2][tx] + red[3][tx];
        int o = (b * 4 + sc) * DD + c;
        pmax[o] = cm;
        psum[o] = tot;
    }
}

__global__ __launch_bounds__(256) void anchor_merge(const float* __restrict__ pmax,
                                                    const float* __restrict__ psum,
                                                    float2* __restrict__ smscale) {
    int idx = blockIdx.x * 256 + threadIdx.x;
    int b = idx >> 9;
    int c = idx & 511;
    float M = -1e30f;
#pragma unroll
    for (int j = 0; j < 4; ++j) M = fmaxf(M, pmax[(b * 4 + j) * DD + c]);
    float Z = 0.f;
#pragma unroll
    for (int j = 0; j < 4; ++j) Z += psum[(b * 4 + j) * DD + c] * expf(pmax[(b * 4 + j) * DD + c] - M);
    smscale[idx] = make_float2(M, 1.0f / Z);
}

// Kernel 4c: kw = k * exp(fa - M) * invZ  (vectorized bf16x8)
__global__ __launch_bounds__(256) void kweight(const __bf16* __restrict__ fa,
                                               const __bf16* __restrict__ kin,
                                               const float2* __restrict__ sm,
                                               __bf16* __restrict__ kw) {
    size_t f = ((size_t)blockIdx.x * 256 + threadIdx.x) * 8;
    int b = (int)(f >> 19);
    int c = (int)(f & 511);
    bf16x8 fv = *reinterpret_cast<const bf16x8*>(fa + f);
    bf16x8 kv = *reinterpret_cast<const bf16x8*>(kin + f);
    const float2* smb = sm + b * DD + c;
    bf16x8 o;
#pragma unroll
    for (int j = 0; j < 8; ++j) {
        float2 s = smb[j];
        o[j] = (__bf16)((float)kv[j] * expf((float)fv[j] - s.x) * s.y);
    }
    *reinterpret_cast<bf16x8*>(kw + f) = o;
}

// ---------------------------------------------------------------------------
// Kernel 5: V transpose into TILED layout:
//   vt2[b][t/8][drow=h*32+d (512)][t%8]   (8KB per (b,t/8) slice)
// ---------------------------------------------------------------------------
__global__ __launch_bounds__(256) void vtrans(const __bf16* __restrict__ v,
                                              __bf16* __restrict__ vt) {
    int t0 = blockIdx.x * 32;
    int h = blockIdx.y;
    int b = blockIdx.z;
    __shared__ unsigned short lds[32][33];
    int tid = threadIdx.x;
    int r = tid >> 3, c4 = (tid & 7) * 4;
    const unsigned short* vp = (const unsigned short*)v + ((size_t)(b * SS + t0 + r)) * DD + h * 32 + c4;
    us4 val = *reinterpret_cast<const us4*>(vp);
    lds[r][c4 + 0] = val[0]; lds[r][c4 + 1] = val[1];
    lds[r][c4 + 2] = val[2]; lds[r][c4 + 3] = val[3];
    __syncthreads();
    us4 o;
    o[0] = lds[c4 + 0][r]; o[1] = lds[c4 + 1][r];
    o[2] = lds[c4 + 2][r]; o[3] = lds[c4 + 3][r];  // o[j] = v[t0+c4+j][h*32+r]
    unsigned short* op = (unsigned short*)vt +
        ((size_t)(b * 128 + ((t0 + c4) >> 3)) * 512 + h * 32 + r) * 8 + (c4 & 7);
    *reinterpret_cast<us4*>(op) = o;
}

// ---------------------------------------------------------------------------
// Kernel 6: MFMA attention, 4-wave blocks sharing LDS-staged kw/vt chunks.
// grid (16 s-groups, 4 b, 8 tp), block 256. Each wave owns 16 s-rows.
// LDS 64KB: kw chunk [32t][1024B] XOR-swizzled + vt chunk [4][512dr][8t].
// NO min-waves hint (rounds 4/6: hint clamps VGPR -> spills). qf resident.
// ---------------------------------------------------------------------------
struct P8 { __bf16* p[8]; };

__global__ __launch_bounds__(256) void attn_mfma(const __bf16* __restrict__ q,
                                                 const __bf16* __restrict__ kw,
                                                 const __bf16* __restrict__ vt,
                                                 P8 ps) {
    __shared__ __align__(16) char smem[65536];
    int sg = blockIdx.x;
    int b = blockIdx.y;
    int tp = blockIdx.z;
    int tid = threadIdx.x;
    int wid = tid >> 6;
    int lane = tid & 63;
    int lg = lane >> 4;
    int lr = lane & 15;
    int s0 = (sg * 4 + wid) * 16;

    const __bf16* qbase = q + ((size_t)(b * SS + s0 + lr)) * DD + lg * 8;
    const char* kwb8 = (const char*)kw + (size_t)b * SS * DD * 2;
    const char* vtb8 = (const char*)vt + (size_t)b * 128 * 8192;

    bf16x8 qf[16];
#pragma unroll
    for (int h = 0; h < 16; ++h) qf[h] = *reinterpret_cast<const bf16x8*>(qbase + h * 32);

    f32x4 acc[16][2];
#pragma unroll
    for (int h = 0; h < 16; ++h) {
        acc[h][0] = (f32x4){0.f, 0.f, 0.f, 0.f};
        acc[h][1] = (f32x4){0.f, 0.f, 0.f, 0.f};
    }

    int trowA = 8 * (lr >> 2) + (lr & 3);
    int trowB = trowA + 4;
    int xsl = lr << 4;

    for (int tc = 0; tc < 128; tc += 32) {
        int tbase = tp * 128 + tc;
#pragma unroll
        for (int it = 0; it < 8; ++it) {
            int row = it * 4 + wid;
            int colb = (lane * 16) ^ (((row & 3) << 4) | (((row >> 3) & 3) << 6));
            gload16(kwb8 + (size_t)(tbase + row) * 1024 + colb,
                    smem + it * 4096 + wid * 1024);
        }
#pragma unroll
        for (int it = 0; it < 8; ++it) {
            int blkid = it * 4 + wid;
            int lgq = blkid >> 3;
            gload16(vtb8 + (size_t)((tbase >> 3) + lgq) * 8192 + (blkid & 7) * 1024 + lane * 16,
                    smem + 32768 + it * 4096 + wid * 1024);
        }
        asm volatile("s_waitcnt vmcnt(0)" ::: "memory");
        __syncthreads();

        f32x4 sc[16];
#pragma unroll
        for (int hb = 0; hb < 16; hb += 4) {
            bf16x8 ka[4];
#pragma unroll
            for (int j = 0; j < 4; ++j) {
                int h = hb + j;
                ka[j] = *reinterpret_cast<const bf16x8*>(
                    smem + trowA * 1024 + ((h * 64 + lg * 16) ^ xsl));
            }
            __builtin_amdgcn_s_setprio(1);
#pragma unroll
            for (int j = 0; j < 4; ++j) {
                f32x4 z = (f32x4){0.f, 0.f, 0.f, 0.f};
                sc[hb + j] = __builtin_amdgcn_mfma_f32_16x16x32_bf16(ka[j], qf[hb + j], z, 0, 0, 0);
            }
            __builtin_amdgcn_s_setprio(0);
        }
        bf16x4 pA[16];
#pragma unroll
        for (int r = 0; r < 4; ++r) {
            float e[16]; float zs = 0.f;
#pragma unroll
            for (int h = 0; h < 16; ++h) { e[h] = exp2f(sc[h][r] * SCLOG2E); zs += e[h]; }
            float inv = __builtin_amdgcn_rcpf(zs);
#pragma unroll
            for (int h = 0; h < 16; ++h) pA[h][r] = (__bf16)(e[h] * inv);
        }
#pragma unroll
        for (int hb = 0; hb < 16; hb += 4) {
            bf16x8 ka[4];
#pragma unroll
            for (int j = 0; j < 4; ++j) {
                int h = hb + j;
                ka[j] = *reinterpret_cast<const bf16x8*>(
                    smem + trowB * 1024 + ((h * 64 + lg * 16) ^ xsl));
            }
            __builtin_amdgcn_s_setprio(1);
#pragma unroll
            for (int j = 0; j < 4; ++j) {
                f32x4 z = (f32x4){0.f, 0.f, 0.f, 0.f};
                sc[hb + j] = __builtin_amdgcn_mfma_f32_16x16x32_bf16(ka[j], qf[hb + j], z, 0, 0, 0);
            }
            __builtin_amdgcn_s_setprio(0);
        }
        bf16x4 pB[16];
#pragma unroll
        for (int r = 0; r < 4; ++r) {
            float e[16]; float zs = 0.f;
#pragma unroll
            for (int h = 0; h < 16; ++h) { e[h] = exp2f(sc[h][r] * SCLOG2E); zs += e[h]; }
            float inv = __builtin_amdgcn_rcpf(zs);
#pragma unroll
            for (int h = 0; h < 16; ++h) pB[h][r] = (__bf16)(e[h] * inv);
        }
#pragma unroll
        for (int hb = 0; hb < 16; hb += 4) {
            bf16x8 vf[8];
#pragma unroll
            for (int j = 0; j < 4; ++j) {
                int h = hb + j;
                vf[2 * j + 0] = *reinterpret_cast<const bf16x8*>(
                    smem + 32768 + lg * 8192 + h * 512 + lr * 16);
                vf[2 * j + 1] = *reinterpret_cast<const bf16x8*>(
                    smem + 32768 + lg * 8192 + h * 512 + 256 + lr * 16);
            }
            __builtin_amdgcn_s_setprio(1);
#pragma unroll
            for (int j = 0; j < 4; ++j) {
                int h = hb + j;
                bf16x8 p = __builtin_shufflevector(pA[h], pB[h], 0, 1, 2, 3, 4, 5, 6, 7);
                acc[h][0] = __builtin_amdgcn_mfma_f32_16x16x32_bf16(p, vf[2 * j + 0], acc[h][0], 0, 0, 0);
                acc[h][1] = __builtin_amdgcn_mfma_f32_16x16x32_bf16(p, vf[2 * j + 1], acc[h][1], 0, 0, 0);
            }
            __builtin_amdgcn_s_setprio(0);
        }
        __syncthreads();
    }

    __bf16* pb = ps.p[tp] + ((size_t)(b * SS + s0)) * DD;
#pragma unroll
    for (int h = 0; h < 16; ++h)
#pragma unroll
        for (int dh = 0; dh < 2; ++dh)
#pragma unroll
            for (int r = 0; r < 4; ++r)
                pb[(size_t)(lg * 4 + r) * DD + h * 32 + dh * 16 + lr] = (__bf16)acc[h][dh][r];
}

// ---------------------------------------------------------------------------
// Kernel 7: combine  comb = (sum of 8 partials)*mg + hf  -> bf16
// ---------------------------------------------------------------------------
struct P8c { const __bf16* p[8]; };

__global__ __launch_bounds__(256) void combine_kernel(P8c ps,
                                                      const __bf16* __restrict__ mg,
                                                      const __bf16* __restrict__ hf,
                                                      __bf16* __restrict__ comb) {
    size_t f = ((size_t)blockIdx.x * 256 + threadIdx.x) * 8;
    float accv[8] = {0.f, 0.f, 0.f, 0.f, 0.f, 0.f, 0.f, 0.f};
#pragma unroll
    for (int i = 0; i < 8; ++i) {
        bf16x8 v = *reinterpret_cast<const bf16x8*>(ps.p[i] + f);
#pragma unroll
        for (int j = 0; j < 8; ++j) accv[j] += (float)v[j];
    }
    bf16x8 m = *reinterpret_cast<const bf16x8*>(mg + f);
    bf16x8 hh = *reinterpret_cast<const bf16x8*>(hf + f);
    bf16x8 o;
#pragma unroll
    for (int j = 0; j < 8; ++j) o[j] = (__bf16)(accv[j] * (float)m[j] + (float)hh[j]);
    *reinterpret_cast<bf16x8*>(comb + f) = o;
}

// ---------------------------------------------------------------------------
extern "C" void kernel_launch(void* const* d_in, const int* in_sizes, int n_in,
                              void* d_out, int out_size, void* d_ws, size_t ws_size,
                              hipStream_t stream) {
    const float* x    = (const float*)d_in[0];
    const float* ln_g = (const float*)d_in[1];
    const float* ln_b = (const float*)d_in[2];
    const float* Wfa  = (const float*)d_in[3];  const float* bfa = (const float*)d_in[4];
    const float* Whp  = (const float*)d_in[5];  const float* bhp = (const float*)d_in[6];
    const float* Wmg  = (const float*)d_in[7];  const float* bmg = (const float*)d_in[8];
    const float* Wq   = (const float*)d_in[9];  const float* bq  = (const float*)d_in[10];
    const float* Wk   = (const float*)d_in[11]; const float* bk  = (const float*)d_in[12];
    const float* Wv   = (const float*)d_in[13]; const float* bv  = (const float*)d_in[14];
    const float* Wo   = (const float*)d_in[15]; const float* bo  = (const float*)d_in[16];
    float* out = (float*)d_out;

    char* w8 = (char*)d_ws;
    // Memory map (MB offsets). Every [B,S,D] bf16 tensor is 4 MB.
    __bf16* Wt   = (__bf16*)(w8 + ((size_t) 0 << 20)); // 3.5 MB used
    __bf16* xn   = (__bf16*)(w8 + ((size_t) 4 << 20)); // [4,8)   dead after 6-gemm
    __bf16* fa   = (__bf16*)(w8 + ((size_t) 8 << 20)); // [8,12)  dead after kweight
    __bf16* hf   = (__bf16*)(w8 + ((size_t)12 << 20)); // [12,16)
    __bf16* mg   = (__bf16*)(w8 + ((size_t)16 << 20)); // [16,20)
    __bf16* q    = (__bf16*)(w8 + ((size_t)20 << 20)); // [20,24)
    __bf16* k    = (__bf16*)(w8 + ((size_t)24 << 20)); // [24,28) dead after kweight
    __bf16* v    = (__bf16*)(w8 + ((size_t)28 << 20)); // [28,32) dead after vtrans
    __bf16* kw   = (__bf16*)(w8 + ((size_t)32 << 20)); // [32,36)
    __bf16* vt   = (__bf16*)(w8 + ((size_t)36 << 20)); // [36,40)
    P8 ps;
    ps.p[0] = (__bf16*)(w8 + ((size_t) 4 << 20));
    ps.p[1] = (__bf16*)(w8 + ((size_t) 8 << 20));
    ps.p[2] = (__bf16*)(w8 + ((size_t)24 << 20));
    ps.p[3] = (__bf16*)(w8 + ((size_t)28 << 20));
    ps.p[4] = (__bf16*)(w8 + ((size_t)40 << 20));
    ps.p[5] = (__bf16*)(w8 + ((size_t)44 << 20));
    ps.p[6] = (__bf16*)(w8 + ((size_t)48 << 20));
    ps.p[7] = (__bf16*)(w8 + ((size_t)52 << 20));
    __bf16* comb = (__bf16*)(w8 + ((size_t)56 << 20)); // [56,60)
    float* pmax  = (float*) (w8 + ((size_t)60 << 20)); // stats ~80 KB
    float* psum  = pmax + 16 * DD;
    float2* smsc = (float2*)(psum + 16 * DD);

    // 1. LayerNorm -> xn bf16
    ln_kernel<<<NTOK, 256, 0, stream>>>(x, ln_g, ln_b, xn);

    // 2. Weight transpose+cast
    W7 wp; wp.p[0]=Wfa; wp.p[1]=Whp; wp.p[2]=Wmg; wp.p[3]=Wq; wp.p[4]=Wk; wp.p[5]=Wv; wp.p[6]=Wo;
    wprep<<<dim3(16, 16, 7), 256, 0, stream>>>(wp, Wt);

    // 3. Fused 6-projection MFMA GEMM (LDS-staged)
    GemmCfg cfg;
    cfg.bias[0]=bfa; cfg.out[0]=fa; cfg.mode[0]=2;
    cfg.bias[1]=bhp; cfg.out[1]=hf; cfg.mode[1]=2;
    cfg.bias[2]=bmg; cfg.out[2]=mg; cfg.mode[2]=1;
    cfg.bias[3]=bq;  cfg.out[3]=q;  cfg.mode[3]=2;
    cfg.bias[4]=bk;  cfg.out[4]=k;  cfg.mode[4]=2;
    cfg.bias[5]=bv;  cfg.out[5]=v;  cfg.mode[5]=2;
    mfma_gemm<<<dim3(32, 8, 6), 256, 0, stream>>>(xn, Wt, cfg, nullptr);

    // 4. anchor softmax over sequence axis
    anchor_partial<<<dim3(8, 4, 4), dim3(64, 4), 0, stream>>>(fa, pmax, psum);
    anchor_merge<<<8, 256, 0, stream>>>(pmax, psum, smsc);
    kweight<<<1024, 256, 0, stream>>>(fa, k, smsc, kw);

    // 5. V transpose (tiled layout)
    vtrans<<<dim3(32, 16, 4), 256, 0, stream>>>(v, vt);

    // 6. MFMA attention -> 8 bf16 partials (4-wave LDS-shared blocks)
    attn_mfma<<<dim3(16, 4, 8), 256, 0, stream>>>(q, kw, vt, ps);

    // 7. combine
    P8c pc;
    for (int i = 0; i < 8; ++i) pc.p[i] = ps.p[i];
    combine_kernel<<<1024, 256, 0, stream>>>(pc, mg, hf, comb);

    // 8. output projection + residual (LDS-staged GEMM)
    GemmCfg cfg2;
    for (int i = 0; i < 6; ++i) { cfg2.bias[i]=bo; cfg2.out[i]=out; cfg2.mode[i]=0; }
    mfma_gemm<<<dim3(32, 8, 1), 256, 0, stream>>>(comb, Wt + (size_t)6 * DD * DD, cfg2, x);
}